// Round 13
// baseline (2093.623 us; speedup 1.0000x reference)
//
#include <hip/hip_runtime.h>
#include <hip/hip_bf16.h>
#include <math.h>

#define B_   16
#define L_   2048
#define D_   128
#define H_   4
#define NL_  4
#define DK_  32
#define DFF_ 256
#define INTD_ 11
#define F_OUT 129
#define DM_  16
#define FMINV (-3.402823466e38f)
#define LOG2E 1.4426950408889634f

#define BL_  (B_*L_)      // 32768
#define SZ_X (BL_*D_)     // 4194304 floats

#define PSTR 72           // attn P-scratch stride

#define WT_Q 0
#define WT_K 16384
#define WT_V 32768
#define WT_O 49152
#define WT_1 65536
#define WT_2 98304
#define WT_TOT 131072

typedef __attribute__((ext_vector_type(8))) short bf16x8;
typedef __attribute__((ext_vector_type(4))) float f32x4;

#if __has_builtin(__builtin_amdgcn_exp2f)
#define EXP2F(x) __builtin_amdgcn_exp2f(x)
#else
#define EXP2F(x) __expf(0.69314718055994531f*(x))
#endif

static __device__ __forceinline__ short f2bf(float x) {
    union { __hip_bfloat16 h; short s; } u;
    u.h = __float2bfloat16(x);
    return u.s;
}
static __device__ __forceinline__ float bf2f(short s) {
    union { __hip_bfloat16 h; short t; } u;
    u.t = s;
    return __bfloat162float(u.h);
}
static __device__ __forceinline__ void split2(float v, short& h, short& l) {
    h = f2bf(v); l = f2bf(v - bf2f(h));
}
static __device__ __forceinline__ void split_trunc(float v, short& h, short& l) {
    unsigned u = __float_as_uint(v);
    h = (short)(u >> 16);
    float r = v - __uint_as_float(u & 0xffff0000u);
    l = (short)(__float_as_uint(r) >> 16);
}

// ---------------------------------------------------------------------------
// Mask compaction: pos[b,l] = compact index or -1; kcount[b]; cfm[b,j]=0/FMIN.
// ---------------------------------------------------------------------------
__global__ __launch_bounds__(256)
void compact_kernel(const int* __restrict__ mask, int* __restrict__ pos,
                    int* __restrict__ kcount, float* __restrict__ cfm)
{
    int b = blockIdx.x, t = threadIdx.x;
    int lane = t & 63, w = t >> 6;
    __shared__ int wsum[4];
    __shared__ int tot_s;
    int mv[8], loc[8], s = 0;
#pragma unroll
    for (int i = 0; i < 8; ++i) {
        mv[i] = mask[b*L_ + t*8 + i];
        loc[i] = s;
        s += mv[i];
    }
    int v = s;
#pragma unroll
    for (int d = 1; d < 64; d <<= 1) {
        int y = __shfl_up(v, d);
        if (lane >= d) v += y;
    }
    int excl = v - s;
    if (lane == 63) wsum[w] = v;
    __syncthreads();
    int wbase = 0;
    for (int i = 0; i < w; ++i) wbase += wsum[i];
    int base = wbase + excl;
#pragma unroll
    for (int i = 0; i < 8; ++i)
        pos[b*L_ + t*8 + i] = mv[i] ? (base + loc[i]) : -1;
    if (t == 255) { kcount[b] = base + s; tot_s = base + s; }
    __syncthreads();
    int tot = tot_s;
    for (int l = t; l < L_; l += 256) cfm[b*L_ + l] = (l < tot) ? 0.0f : FMINV;
}

// ---------------------------------------------------------------------------
// Embedding with compaction
// ---------------------------------------------------------------------------
__global__ __launch_bounds__(128)
void embed_kernel(const float* __restrict__ values, const float* __restrict__ times,
                  const int* __restrict__ variables, const int* __restrict__ pos,
                  const float* __restrict__ W1t, const float* __restrict__ b1t,
                  const float* __restrict__ W2t,
                  const float* __restrict__ W1v, const float* __restrict__ b1v,
                  const float* __restrict__ W2v,
                  const float* __restrict__ var_table, float* __restrict__ x)
{
    int bl = blockIdx.x;
    int p  = pos[bl];
    if (p < 0) return;
    int t  = threadIdx.x;
    __shared__ float th[INTD_], vh[INTD_];
    if (t < INTD_)                th[t]    = tanhf(times[bl]  * W1t[t]    + b1t[t]);
    if (t >= 64 && t < 64+INTD_)  vh[t-64] = tanhf(values[bl] * W1v[t-64] + b1v[t-64]);
    __syncthreads();
    int var = variables[bl];
    float acc = var_table[var*D_ + t];
#pragma unroll
    for (int i = 0; i < INTD_; ++i)
        acc += th[i]*W2t[i*D_ + t] + vh[i]*W2v[i*D_ + t];
    x[((size_t)((bl >> 11)*2048 + p))*D_ + t] = acc;
}

// zero compact x tail rows [Kb, ceil64(Kb)) once
__global__ __launch_bounds__(256)
void xtail_zero_kernel(const int* __restrict__ kcount, float* __restrict__ x)
{
    int b = blockIdx.x, t = threadIdx.x;
    int Kb = kcount[b];
    int end = (Kb + 63) & ~63;
    int tot = (end - Kb) * D_;
    for (int i = t; i < tot; i += 256)
        x[((size_t)(b*2048 + Kb))*D_ + i] = 0.0f;
}

// ---------------------------------------------------------------------------
// Weight pre-splits
// ---------------------------------------------------------------------------
__global__ __launch_bounds__(256)
void split_all_kernel(const float* __restrict__ Wq, const float* __restrict__ Wk,
                      const float* __restrict__ Wv, const float* __restrict__ Wo,
                      const float* __restrict__ W1, const float* __restrict__ W2,
                      short* __restrict__ hi, short* __restrict__ lo)
{
    int gidx = blockIdx.x*256 + threadIdx.x;
    int layer = gidx >> 17;
    int idx   = gidx & 131071;
    float v;
    if (idx < 49152) {
        int which = idx >> 14;
        int r = idx & 16383;
        int col = r >> 7, k = r & 127;
        int h = col >> 5, e = col & 31;
        const float* src = ((which == 0) ? Wq : (which == 1) ? Wk : Wv)
                           + (size_t)layer*H_*D_*DK_;
        v = src[(h*D_ + k)*DK_ + e];
    } else if (idx < 65536) {
        int r = idx - 49152;
        int col = r >> 7, k = r & 127;
        v = Wo[(size_t)layer*D_*D_ + k*D_ + col];
    } else if (idx < 98304) {
        int r = idx - 65536;
        int col = r >> 7, k = r & 127;
        v = W1[(size_t)layer*D_*DFF_ + k*DFF_ + col];
    } else {
        int r = idx - 98304;
        int col = r >> 8, k = r & 255;
        v = W2[(size_t)layer*DFF_*D_ + k*D_ + col];
    }
    short h2, l2; split2(v, h2, l2);
    hi[gidx] = h2; lo[gidx] = l2;
}

__global__ __launch_bounds__(256)
void split_nk_kernel(const float* __restrict__ W, short* __restrict__ hi,
                     short* __restrict__ lo, int N, int K)
{
    int idx = blockIdx.x*256 + threadIdx.x;
    int col = idx / K, k = idx - col*K;
    float v = W[k*N + col];
    short h2, l2; split2(v, h2, l2);
    hi[idx] = h2; lo[idx] = l2;
}

// ---------------------------------------------------------------------------
// MFMA GEMM on COMPACT rows (early-exit past ceil64(Kb)). 64-row blocks.
// EPI: 1=+resid 2=+bias,gelu 3=+bias,+resid 7=fusion att dot (+cfm)
// ---------------------------------------------------------------------------
template<int EPI>
__global__ __launch_bounds__(256)
void gemm_mfma(const float* __restrict__ A, const short* __restrict__ Whi,
               const short* __restrict__ Wlo, const float* __restrict__ bias,
               const float* __restrict__ resid, float* __restrict__ out,
               const float* __restrict__ cfm, const int* __restrict__ kcount,
               int N, int K)
{
    const int row0 = blockIdx.x * 64;
    const int bb = row0 >> 11;
    if ((row0 & 2047) >= ((kcount[bb] + 63) & ~63)) return;

    __shared__ short Ahi[64*136];
    __shared__ short Alo[64*136];
    __shared__ float part[64][16];
    const int t = threadIdx.x;
    const int w = t >> 6, lane = t & 63;
    const int m = lane & 15, qd = lane >> 4;
    const int col0 = blockIdx.y * 128;

    f32x4 acc[4][2];
#pragma unroll
    for (int r4 = 0; r4 < 4; ++r4)
#pragma unroll
        for (int j = 0; j < 2; ++j) acc[r4][j] = (f32x4){0,0,0,0};

    for (int kb = 0; kb < K; kb += 128) {
        if (kb) __syncthreads();
#pragma unroll
        for (int i = 0; i < 8; ++i) {
            int r = (t >> 5) + 8*i;
            int c = (t & 31) * 4;
            float4 av = *(const float4*)(A + (size_t)(row0 + r)*K + kb + c);
            short4 hi4, lo4;
            split2(av.x, hi4.x, lo4.x);
            split2(av.y, hi4.y, lo4.y);
            split2(av.z, hi4.z, lo4.z);
            split2(av.w, hi4.w, lo4.w);
            *(short4*)&Ahi[r*136 + c] = hi4;
            *(short4*)&Alo[r*136 + c] = lo4;
        }
        __syncthreads();

#pragma unroll
        for (int ks = 0; ks < 4; ++ks) {
            bf16x8 wh[2], wl[2];
#pragma unroll
            for (int j = 0; j < 2; ++j) {
                size_t wi = (size_t)(col0 + 32*w + 16*j + m)*K + kb + 32*ks + 8*qd;
                wh[j] = *(const bf16x8*)(Whi + wi);
                wl[j] = *(const bf16x8*)(Wlo + wi);
            }
#pragma unroll
            for (int r4 = 0; r4 < 4; ++r4) {
                bf16x8 ah = *(const bf16x8*)&Ahi[(16*r4 + m)*136 + 32*ks + 8*qd];
                bf16x8 al = *(const bf16x8*)&Alo[(16*r4 + m)*136 + 32*ks + 8*qd];
#pragma unroll
                for (int j = 0; j < 2; ++j) {
                    acc[r4][j] = __builtin_amdgcn_mfma_f32_16x16x32_bf16(wh[j], ah, acc[r4][j], 0, 0, 0);
                    acc[r4][j] = __builtin_amdgcn_mfma_f32_16x16x32_bf16(wh[j], al, acc[r4][j], 0, 0, 0);
                    acc[r4][j] = __builtin_amdgcn_mfma_f32_16x16x32_bf16(wl[j], ah, acc[r4][j], 0, 0, 0);
                }
            }
        }
    }

#pragma unroll
    for (int r4 = 0; r4 < 4; ++r4) {
        int row = row0 + 16*r4 + m;
        float dotp = 0.0f;
#pragma unroll
        for (int j = 0; j < 2; ++j) {
            int col = col0 + 32*w + 16*j + 4*qd;
            f32x4 v = acc[r4][j];
            if (EPI == 2 || EPI == 3 || EPI == 7) {
                float4 bv = *(const float4*)(bias + col);
                v[0] += bv.x; v[1] += bv.y; v[2] += bv.z; v[3] += bv.w;
            }
            if (EPI == 2) {
#pragma unroll
                for (int e = 0; e < 4; ++e)
                    v[e] = 0.5f * v[e] * (1.0f + erff(v[e] * 0.70710678118654752f));
            }
            if (EPI == 7) {
#pragma unroll
                for (int e = 0; e < 4; ++e) v[e] = tanhf(v[e]);
            }
            if (EPI == 1 || EPI == 3) {
                float4 rv = *(const float4*)(resid + (size_t)row*N + col);
                v[0] += rv.x; v[1] += rv.y; v[2] += rv.z; v[3] += rv.w;
            }
            if (EPI == 7) {
                float4 uv = *(const float4*)(resid + col);   // uf
                dotp += v[0]*uv.x + v[1]*uv.y + v[2]*uv.z + v[3]*uv.w;
            } else {
                float4 sv = {v[0], v[1], v[2], v[3]};
                *(float4*)(out + (size_t)row*N + col) = sv;
            }
        }
        if (EPI == 7) part[16*r4 + m][4*w + qd] = dotp;
    }
    if (EPI == 7) {
        __syncthreads();
        if (t < 64) {
            float s = 0.0f;
#pragma unroll
            for (int i = 0; i < 16; ++i) s += part[t][i];
            out[row0 + t] = s + cfm[row0 + t];
        }
    }
}

// ---------------------------------------------------------------------------
// Fused QKV GEMM on compact rows, one weight stream per block (grid.y=3):
// sec 0: Q fp32; sec 1: K hi/lo head-major; sec 2: V^T hi/lo.
// ---------------------------------------------------------------------------
__global__ __launch_bounds__(256)
void gemm_qkv_fused(const float* __restrict__ A, const short* __restrict__ Whi,
                    const short* __restrict__ Wlo, const int* __restrict__ kcount,
                    float* __restrict__ qout,
                    short* __restrict__ khi, short* __restrict__ klo,
                    short* __restrict__ vhiT, short* __restrict__ vloT)
{
    const int row0 = blockIdx.x * 64;
    const int bb = row0 >> 11;
    if ((row0 & 2047) >= ((kcount[bb] + 63) & ~63)) return;
    const int sec = blockIdx.y;

    __shared__ short Ahi[64*136];
    __shared__ short Alo[64*136];
    const int t = threadIdx.x;
    const int w = t >> 6, lane = t & 63;
    const int m = lane & 15, qd = lane >> 4;

#pragma unroll
    for (int i = 0; i < 8; ++i) {
        int r = (t >> 5) + 8*i;
        int c = (t & 31) * 4;
        float4 av = *(const float4*)(A + (size_t)(row0 + r)*D_ + c);
        short4 hi4, lo4;
        split2(av.x, hi4.x, lo4.x);
        split2(av.y, hi4.y, lo4.y);
        split2(av.z, hi4.z, lo4.z);
        split2(av.w, hi4.w, lo4.w);
        *(short4*)&Ahi[r*136 + c] = hi4;
        *(short4*)&Alo[r*136 + c] = lo4;
    }
    __syncthreads();

    const short* Wh = Whi + sec*16384;
    const short* Wl = Wlo + sec*16384;
    f32x4 acc[4][2];
#pragma unroll
    for (int r4 = 0; r4 < 4; ++r4)
#pragma unroll
        for (int j = 0; j < 2; ++j) acc[r4][j] = (f32x4){0,0,0,0};

#pragma unroll
    for (int ks = 0; ks < 4; ++ks) {
        bf16x8 wh[2], wl[2];
#pragma unroll
        for (int j = 0; j < 2; ++j) {
            size_t wi = (size_t)(32*w + 16*j + m)*D_ + 32*ks + 8*qd;
            wh[j] = *(const bf16x8*)(Wh + wi);
            wl[j] = *(const bf16x8*)(Wl + wi);
        }
#pragma unroll
        for (int r4 = 0; r4 < 4; ++r4) {
            bf16x8 ah = *(const bf16x8*)&Ahi[(16*r4 + m)*136 + 32*ks + 8*qd];
            bf16x8 al = *(const bf16x8*)&Alo[(16*r4 + m)*136 + 32*ks + 8*qd];
#pragma unroll
            for (int j = 0; j < 2; ++j) {
                acc[r4][j] = __builtin_amdgcn_mfma_f32_16x16x32_bf16(wh[j], ah, acc[r4][j], 0, 0, 0);
                acc[r4][j] = __builtin_amdgcn_mfma_f32_16x16x32_bf16(wh[j], al, acc[r4][j], 0, 0, 0);
                acc[r4][j] = __builtin_amdgcn_mfma_f32_16x16x32_bf16(wl[j], ah, acc[r4][j], 0, 0, 0);
            }
        }
    }

#pragma unroll
    for (int r4 = 0; r4 < 4; ++r4) {
        int row = row0 + 16*r4 + m;
        int l = row & 2047;
#pragma unroll
        for (int j = 0; j < 2; ++j) {
            int col = 32*w + 16*j + 4*qd;
            f32x4 v = acc[r4][j];
            if (sec == 0) {
                float4 sv = {v[0], v[1], v[2], v[3]};
                *(float4*)(qout + (size_t)row*D_ + col) = sv;
            } else if (sec == 1) {
                size_t idx = ((size_t)((bb*4 + w)*2048 + l))*32 + (col & 31);
                short4 hi4, lo4;
                split2(v[0], hi4.x, lo4.x);
                split2(v[1], hi4.y, lo4.y);
                split2(v[2], hi4.z, lo4.z);
                split2(v[3], hi4.w, lo4.w);
                *(short4*)(khi + idx) = hi4;
                *(short4*)(klo + idx) = lo4;
            } else {
                size_t basep = (size_t)(bb*4 + w)*32;
#pragma unroll
                for (int e = 0; e < 4; ++e) {
                    int d = 16*j + 4*qd + e;
                    short hh, ll; split2(v[e], hh, ll);
                    vhiT[(basep + d)*2048 + l] = hh;
                    vloT[(basep + d)*2048 + l] = ll;
                }
            }
        }
    }
}

// ---------------------------------------------------------------------------
// MFMA flash attention over compact rows, DEPTH-2 register prefetch:
// tile kt+2 issued after kt's post-write barrier -> LDS write of a tile waits
// on loads issued two full compute phases earlier.
// ---------------------------------------------------------------------------
__global__ __launch_bounds__(256)
void attn_mfma_kernel(const float* __restrict__ q,
                      const short* __restrict__ khi, const short* __restrict__ klo,
                      const short* __restrict__ vhiT, const short* __restrict__ vloT,
                      const int* __restrict__ kcount, const float* __restrict__ cfm,
                      float* __restrict__ o)
{
    __shared__ short KhiS[64*32];
    __shared__ short KloS[64*32];
    __shared__ short Vthi[32*72];
    __shared__ short Vtlo[32*72];
    __shared__ short Pshi[4][16*PSTR];
    __shared__ short Pslo[4][16*PSTR];
    __shared__ float kmf[64];
    __shared__ float al_ls[4][16];
    __shared__ float l_ls [4][16];

    const int t    = threadIdx.x;
    const int w    = t >> 6;
    const int lane = t & 63;
    const int m    = lane & 15;
    const int qd   = lane >> 4;
    const int qt = blockIdx.x, h = blockIdx.y, b = blockIdx.z;

    const int Kb = kcount[b];
    if (qt*64 >= Kb) return;
    const int nt = (Kb + 63) >> 6;

    const size_t hd = ((size_t)(b*4 + h))*2048*32;
    const int vd = t >> 3;
    const int vk = (t & 7) * 8;
    const size_t vbase = ((size_t)(b*4 + h)*32 + vd)*2048 + vk;

    const int qrow = qt*64 + 16*w + m;
    const float* qp = q + ((size_t)(b*L_ + qrow))*D_ + h*DK_ + 8*qd;
    float qf[8];
    *(float4*)&qf[0] = *(const float4*)qp;
    *(float4*)&qf[4] = *(const float4*)(qp + 4);
    bf16x8 qhi, qlo;
#pragma unroll
    for (int j = 0; j < 8; ++j) {
        float qs = qf[j] * LOG2E;
        short hs = f2bf(qs);
        qhi[j] = hs;
        qlo[j] = f2bf(qs - bf2f(hs));
    }

    // depth-2 prefetch register slots
    bf16x8 pkh[2], pkl[2], pvh[2], pvl[2];
    float4 pmask[2];
    pmask[0] = (float4){0,0,0,0};
    pmask[1] = (float4){0,0,0,0};
    {
        const size_t gk = hd + (size_t)t*8;
        pkh[0] = *(const bf16x8*)(khi + gk);
        pkl[0] = *(const bf16x8*)(klo + gk);
        pvh[0] = *(const bf16x8*)(vhiT + vbase);
        pvl[0] = *(const bf16x8*)(vloT + vbase);
        if (t < 16) pmask[0] = ((const float4*)(cfm + (size_t)b*L_))[t];
    }
    if (nt > 1) {
        const size_t gk = hd + (size_t)64*32 + t*8;
        pkh[1] = *(const bf16x8*)(khi + gk);
        pkl[1] = *(const bf16x8*)(klo + gk);
        pvh[1] = *(const bf16x8*)(vhiT + vbase + 64);
        pvl[1] = *(const bf16x8*)(vloT + vbase + 64);
        if (t < 16) pmask[1] = ((const float4*)(cfm + (size_t)b*L_ + 64))[t];
    }

    float m_old = -INFINITY, l_run = 0.0f;
    f32x4 o_acc[2] = {{0,0,0,0},{0,0,0,0}};

    for (int kt = 0; kt < nt; ++kt) {
        const int sl = kt & 1;
        __syncthreads();
        *(bf16x8*)&KhiS[t*8] = pkh[sl];
        *(bf16x8*)&KloS[t*8] = pkl[sl];
        *(bf16x8*)&Vthi[vd*72 + vk] = pvh[sl];
        *(bf16x8*)&Vtlo[vd*72 + vk] = pvl[sl];
        if (t < 16) ((float4*)kmf)[t] = pmask[sl];
        __syncthreads();
        if (kt + 2 < nt) {
            const size_t gk = hd + (size_t)(kt+2)*64*32 + t*8;
            pkh[sl] = *(const bf16x8*)(khi + gk);
            pkl[sl] = *(const bf16x8*)(klo + gk);
            pvh[sl] = *(const bf16x8*)(vhiT + vbase + (size_t)(kt+2)*64);
            pvl[sl] = *(const bf16x8*)(vloT + vbase + (size_t)(kt+2)*64);
            if (t < 16) pmask[sl] = ((const float4*)(cfm + (size_t)b*L_ + (size_t)(kt+2)*64))[t];
        }

        f32x4 sf[4];
#pragma unroll
        for (int k4 = 0; k4 < 4; ++k4) {
            bf16x8 ka = *(const bf16x8*)&KhiS[(16*k4 + m)*32 + 8*qd];
            bf16x8 kl = *(const bf16x8*)&KloS[(16*k4 + m)*32 + 8*qd];
            f32x4 c = {0,0,0,0};
            c = __builtin_amdgcn_mfma_f32_16x16x32_bf16(ka, qhi, c, 0, 0, 0);
            c = __builtin_amdgcn_mfma_f32_16x16x32_bf16(ka, qlo, c, 0, 0, 0);
            c = __builtin_amdgcn_mfma_f32_16x16x32_bf16(kl, qhi, c, 0, 0, 0);
            sf[k4] = c;
        }

        float sv[16];
#pragma unroll
        for (int k4 = 0; k4 < 4; ++k4) {
            float4 kmv = *(const float4*)&kmf[16*k4 + 4*qd];
            sv[4*k4+0] = sf[k4][0] + kmv.x;
            sv[4*k4+1] = sf[k4][1] + kmv.y;
            sv[4*k4+2] = sf[k4][2] + kmv.z;
            sv[4*k4+3] = sf[k4][3] + kmv.w;
        }

        float tmax = sv[0];
#pragma unroll
        for (int j = 1; j < 16; ++j) tmax = fmaxf(tmax, sv[j]);
        tmax = fmaxf(tmax, __shfl_xor(tmax, 16));
        tmax = fmaxf(tmax, __shfl_xor(tmax, 32));
        float mnew  = fmaxf(m_old, tmax);
        float alpha = EXP2F(m_old - mnew);
        float psum = 0.0f;
        short pbh[16], pbl[16];
#pragma unroll
        for (int j = 0; j < 16; ++j) {
            float p = EXP2F(sv[j] - mnew);
            psum += p;
            split_trunc(p, pbh[j], pbl[j]);
        }
        psum += __shfl_xor(psum, 16);
        psum += __shfl_xor(psum, 32);
        l_run = l_run * alpha + psum;
        m_old = mnew;

#pragma unroll
        for (int k4 = 0; k4 < 4; ++k4) {
            short4 s4h, s4l;
            s4h.x = pbh[4*k4+0]; s4h.y = pbh[4*k4+1]; s4h.z = pbh[4*k4+2]; s4h.w = pbh[4*k4+3];
            s4l.x = pbl[4*k4+0]; s4l.y = pbl[4*k4+1]; s4l.z = pbl[4*k4+2]; s4l.w = pbl[4*k4+3];
            *(short4*)&Pshi[w][m*PSTR + 16*k4 + 4*qd] = s4h;
            *(short4*)&Pslo[w][m*PSTR + 16*k4 + 4*qd] = s4l;
        }
        if (lane < 16) al_ls[w][lane] = alpha;

        {
            float4 alr = *(const float4*)&al_ls[w][4*qd];
            o_acc[0][0]*=alr.x; o_acc[0][1]*=alr.y; o_acc[0][2]*=alr.z; o_acc[0][3]*=alr.w;
            o_acc[1][0]*=alr.x; o_acc[1][1]*=alr.y; o_acc[1][2]*=alr.z; o_acc[1][3]*=alr.w;
        }
#pragma unroll
        for (int s = 0; s < 2; ++s) {
            bf16x8 pah = *(const bf16x8*)&Pshi[w][m*PSTR + 32*s + 8*qd];
            bf16x8 pal = *(const bf16x8*)&Pslo[w][m*PSTR + 32*s + 8*qd];
#pragma unroll
            for (int tp = 0; tp < 2; ++tp) {
                bf16x8 vh = *(const bf16x8*)&Vthi[(16*tp + m)*72 + 32*s + 8*qd];
                bf16x8 vl = *(const bf16x8*)&Vtlo[(16*tp + m)*72 + 32*s + 8*qd];
                o_acc[tp] = __builtin_amdgcn_mfma_f32_16x16x32_bf16(pah, vh, o_acc[tp], 0, 0, 0);
                o_acc[tp] = __builtin_amdgcn_mfma_f32_16x16x32_bf16(pah, vl, o_acc[tp], 0, 0, 0);
                o_acc[tp] = __builtin_amdgcn_mfma_f32_16x16x32_bf16(pal, vh, o_acc[tp], 0, 0, 0);
            }
        }
    }

    if (lane < 16) l_ls[w][lane] = l_run;
    float4 lr = *(const float4*)&l_ls[w][4*qd];
    float li[4] = {1.0f/lr.x, 1.0f/lr.y, 1.0f/lr.z, 1.0f/lr.w};
#pragma unroll
    for (int tp = 0; tp < 2; ++tp)
#pragma unroll
        for (int r = 0; r < 4; ++r)
            o[((size_t)(b*L_ + qt*64 + 16*w + 4*qd + r))*D_ + h*DK_ + 16*tp + m] =
                o_acc[tp][r] * li[r];
}

// ---------------------------------------------------------------------------
// Pooling
// ---------------------------------------------------------------------------
__global__ __launch_bounds__(256)
void pool_stats_kernel(const float* __restrict__ att, const int* __restrict__ kcount,
                       float* __restrict__ p)
{
    int b = blockIdx.x, t = threadIdx.x;
    int lim = (kcount[b] + 63) & ~63;
    __shared__ float red[4];
    __shared__ float a_s[L_];

    float m = -INFINITY;
    for (int l = t; l < L_; l += 256) {
        float a = (l < lim) ? att[b*L_ + l] : FMINV;
        a_s[l] = a;
        m = fmaxf(m, a);
    }
#pragma unroll
    for (int s = 1; s < 64; s <<= 1) m = fmaxf(m, __shfl_xor(m, s));
    if ((t & 63) == 0) red[t >> 6] = m;
    __syncthreads();
    m = fmaxf(fmaxf(red[0], red[1]), fmaxf(red[2], red[3]));
    __syncthreads();

    float s = 0.0f;
    for (int l = t; l < L_; l += 256) s += __expf(a_s[l] - m);
#pragma unroll
    for (int st = 1; st < 64; st <<= 1) s += __shfl_xor(s, st);
    if ((t & 63) == 0) red[t >> 6] = s;
    __syncthreads();
    s = red[0] + red[1] + red[2] + red[3];
    float inv = 1.0f / s;
    for (int l = t; l < L_; l += 256)
        p[b*L_ + l] = (l < lim) ? __expf(a_s[l] - m) * inv : 0.0f;
}

__global__ __launch_bounds__(128)
void pool_partial_kernel(const float* __restrict__ p, const float* __restrict__ x,
                         float* __restrict__ part)
{
    int c = blockIdx.x, b = blockIdx.y, d = threadIdx.x;
    const float* xb = x + ((size_t)(b*L_ + c*128))*D_ + d;
    const float* pb = p + b*L_ + c*128;
    float acc = 0.0f;
#pragma unroll 4
    for (int i = 0; i < 128; ++i) acc += pb[i] * xb[(size_t)i*D_];
    part[((size_t)b*16 + c)*D_ + d] = acc;
}

// ---------------------------------------------------------------------------
// Demographics MLP
// ---------------------------------------------------------------------------
__global__ __launch_bounds__(256)
void demo_kernel(const float* __restrict__ demog, const float* __restrict__ Wd1,
                 const float* __restrict__ bd1, const float* __restrict__ Wd2,
                 const float* __restrict__ bd2, float* __restrict__ demo_out)
{
    int t = threadIdx.x;
    __shared__ float dsm[B_][DM_];
    __shared__ float hs[B_][2*D_];
    if (t < B_*DM_) dsm[t >> 4][t & 15] = demog[t];
    __syncthreads();
    {
        int col = t;
#pragma unroll
        for (int r = 0; r < B_; ++r) {
            float acc = bd1[col];
#pragma unroll
            for (int kk = 0; kk < DM_; ++kk) acc += dsm[r][kk]*Wd1[kk*(2*D_)+col];
            hs[r][col] = tanhf(acc);
        }
    }
    __syncthreads();
    {
        int c  = t & (D_-1);
        int r0 = t >> 7;
        for (int r = r0; r < B_; r += 2) {
            float acc = bd2[c];
            for (int kk = 0; kk < 2*D_; ++kk) acc += hs[r][kk]*Wd2[kk*D_+c];
            demo_out[r*D_+c] = acc;
        }
    }
}

// ---------------------------------------------------------------------------
// Head
// ---------------------------------------------------------------------------
__global__ __launch_bounds__(256)
void head_kernel(const float* __restrict__ part, const float* __restrict__ demo,
                 const float* __restrict__ Wh, const float* __restrict__ bh,
                 float* __restrict__ out)
{
    int b = blockIdx.x, t = threadIdx.x;
    __shared__ float tss[128];
    if (t < 128) {
        float s = 0.0f;
#pragma unroll
        for (int c = 0; c < 16; ++c) s += part[((size_t)b*16 + c)*D_ + t];
        tss[t] = s;
    }
    __syncthreads();
    if (t >= F_OUT) return;
    float acc = bh[t];
    for (int k2 = 0; k2 < D_; ++k2) acc += tss[k2]         * Wh[k2*F_OUT + t];
    for (int k2 = 0; k2 < D_; ++k2) acc += demo[b*D_ + k2] * Wh[(D_+k2)*F_OUT + t];
    out[b*F_OUT + t] = acc;
}

// ---------------------------------------------------------------------------
extern "C" void kernel_launch(void* const* d_in, const int* in_sizes, int n_in,
                              void* d_out, int out_size, void* d_ws, size_t ws_size,
                              hipStream_t stream)
{
    (void)in_sizes; (void)n_in; (void)out_size; (void)ws_size;
    const float* values       = (const float*)d_in[0];
    const float* times        = (const float*)d_in[1];
    const int*   variables    = (const int*)  d_in[2];
    const int*   input_mask   = (const int*)  d_in[3];
    const float* demographics = (const float*)d_in[4];
    const float* W1t = (const float*)d_in[5];
    const float* b1t = (const float*)d_in[6];
    const float* W2t = (const float*)d_in[7];
    const float* W1v = (const float*)d_in[8];
    const float* b1v = (const float*)d_in[9];
    const float* W2v = (const float*)d_in[10];
    const float* var_table = (const float*)d_in[11];
    const float* Wq  = (const float*)d_in[12];
    const float* Wk  = (const float*)d_in[13];
    const float* Wv  = (const float*)d_in[14];
    const float* Wo  = (const float*)d_in[15];
    const float* W1  = (const float*)d_in[16];
    const float* b1  = (const float*)d_in[17];
    const float* W2  = (const float*)d_in[18];
    const float* b2  = (const float*)d_in[19];
    const float* Wf  = (const float*)d_in[20];
    const float* bfv = (const float*)d_in[21];
    const float* uf  = (const float*)d_in[22];
    const float* Wd1 = (const float*)d_in[23];
    const float* bd1 = (const float*)d_in[24];
    const float* Wd2 = (const float*)d_in[25];
    const float* bd2 = (const float*)d_in[26];
    const float* Wh  = (const float*)d_in[27];
    const float* bhv = (const float*)d_in[28];
    float* out = (float*)d_out;

    float* ws     = (float*)d_ws;
    float* x      = ws;                   // compact rows
    float* qb     = ws + (size_t)SZ_X;
    float* region = ws + (size_t)2*SZ_X;
    short* khi    = (short*)region;
    short* klo    = khi + (size_t)SZ_X;
    short* vhiT   = klo + (size_t)SZ_X;
    short* vloT   = vhiT + (size_t)SZ_X;
    float* hb     = region;               // alias (FFN hidden)
    float* attb   = ws + (size_t)4*SZ_X;  // BL_
    float* attp   = attb + BL_;           // BL_
    float* partb  = attp + BL_;           // B_*16*D_
    float* demob  = partb + B_*16*D_;     // B_*D_
    short* wt_hi  = (short*)(demob + B_*D_);
    short* wt_lo  = wt_hi + (size_t)NL_*WT_TOT;
    short* wfhi   = wt_lo + (size_t)NL_*WT_TOT;
    short* wflo   = wfhi + 16384;
    int*   posb   = (int*)(wflo + 16384);       // BL_
    int*   kcountb= posb + BL_;                 // B_
    float* cfmb   = (float*)(kcountb + B_);     // BL_

    compact_kernel<<<B_, 256, 0, stream>>>(input_mask, posb, kcountb, cfmb);
    embed_kernel<<<BL_, 128, 0, stream>>>(values, times, variables, posb,
                                          W1t, b1t, W2t, W1v, b1v, W2v,
                                          var_table, x);
    xtail_zero_kernel<<<B_, 256, 0, stream>>>(kcountb, x);
    demo_kernel<<<1, 256, 0, stream>>>(demographics, Wd1, bd1, Wd2, bd2, demob);
    split_nk_kernel<<<64, 256, 0, stream>>>(Wf, wfhi, wflo, D_, D_);
    split_all_kernel<<<NL_*512, 256, 0, stream>>>(Wq, Wk, Wv, Wo, W1, W2, wt_hi, wt_lo);

    for (int i = 0; i < NL_; ++i) {
        short* whL = wt_hi + (size_t)i*WT_TOT;
        short* wlL = wt_lo + (size_t)i*WT_TOT;
        gemm_qkv_fused<<<dim3(BL_/64, 3), 256, 0, stream>>>(x, whL, wlL, kcountb,
            qb, khi, klo, vhiT, vloT);
        attn_mfma_kernel<<<dim3(L_/64, H_, B_), 256, 0, stream>>>(qb, khi, klo, vhiT, vloT,
                                                                  kcountb, cfmb, qb);
        gemm_mfma<1><<<dim3(BL_/64, 1), 256, 0, stream>>>(qb, whL+WT_O, wlL+WT_O,
            nullptr, x, x, nullptr, kcountb, D_, D_);
        gemm_mfma<2><<<dim3(BL_/64, 2), 256, 0, stream>>>(x, whL+WT_1, wlL+WT_1,
            b1 + i*DFF_, nullptr, hb, nullptr, kcountb, DFF_, D_);
        gemm_mfma<3><<<dim3(BL_/64, 1), 256, 0, stream>>>(hb, whL+WT_2, wlL+WT_2,
            b2 + i*D_, x, x, nullptr, kcountb, D_, DFF_);
    }

    // fused fusion-attention on compact rows: att = tanh(x@Wf+bf).uf + cfm
    gemm_mfma<7><<<dim3(BL_/64, 1), 256, 0, stream>>>(x, wfhi, wflo,
        bfv, uf, attb, cfmb, kcountb, D_, D_);
    pool_stats_kernel<<<B_, 256, 0, stream>>>(attb, kcountb, attp);
    pool_partial_kernel<<<dim3(16, B_), 128, 0, stream>>>(attp, x, partb);
    head_kernel<<<B_, 256, 0, stream>>>(partb, demob, Wh, bhv, out);
}

// Round 14
// 849.752 us; speedup vs baseline: 2.4638x; 2.4638x over previous
//
#include <hip/hip_runtime.h>
#include <hip/hip_bf16.h>
#include <math.h>

#define B_   16
#define L_   2048
#define D_   128
#define H_   4
#define NL_  4
#define DK_  32
#define DFF_ 256
#define INTD_ 11
#define F_OUT 129
#define DM_  16
#define FMINV (-3.402823466e38f)
#define LOG2E 1.4426950408889634f

#define BL_  (B_*L_)      // 32768
#define SZ_X (BL_*D_)     // 4194304 floats

#define PSTR 72           // attn P-scratch stride

#define WT_Q 0
#define WT_K 16384
#define WT_V 32768
#define WT_O 49152
#define WT_1 65536
#define WT_2 98304
#define WT_TOT 131072

typedef __attribute__((ext_vector_type(8))) short bf16x8;
typedef __attribute__((ext_vector_type(4))) float f32x4;

#if __has_builtin(__builtin_amdgcn_exp2f)
#define EXP2F(x) __builtin_amdgcn_exp2f(x)
#else
#define EXP2F(x) __expf(0.69314718055994531f*(x))
#endif

static __device__ __forceinline__ short f2bf(float x) {
    union { __hip_bfloat16 h; short s; } u;
    u.h = __float2bfloat16(x);
    return u.s;
}
static __device__ __forceinline__ float bf2f(short s) {
    union { __hip_bfloat16 h; short t; } u;
    u.t = s;
    return __bfloat162float(u.h);
}
static __device__ __forceinline__ void split2(float v, short& h, short& l) {
    h = f2bf(v); l = f2bf(v - bf2f(h));
}
static __device__ __forceinline__ void split_trunc(float v, short& h, short& l) {
    unsigned u = __float_as_uint(v);
    h = (short)(u >> 16);
    float r = v - __uint_as_float(u & 0xffff0000u);
    l = (short)(__float_as_uint(r) >> 16);
}

// ---------------------------------------------------------------------------
// Mask compaction: pos[b,l] = compact index or -1; kcount[b]; cfm[b,j]=0/FMIN.
// ---------------------------------------------------------------------------
__global__ __launch_bounds__(256)
void compact_kernel(const int* __restrict__ mask, int* __restrict__ pos,
                    int* __restrict__ kcount, float* __restrict__ cfm)
{
    int b = blockIdx.x, t = threadIdx.x;
    int lane = t & 63, w = t >> 6;
    __shared__ int wsum[4];
    __shared__ int tot_s;
    int mv[8], loc[8], s = 0;
#pragma unroll
    for (int i = 0; i < 8; ++i) {
        mv[i] = mask[b*L_ + t*8 + i];
        loc[i] = s;
        s += mv[i];
    }
    int v = s;
#pragma unroll
    for (int d = 1; d < 64; d <<= 1) {
        int y = __shfl_up(v, d);
        if (lane >= d) v += y;
    }
    int excl = v - s;
    if (lane == 63) wsum[w] = v;
    __syncthreads();
    int wbase = 0;
    for (int i = 0; i < w; ++i) wbase += wsum[i];
    int base = wbase + excl;
#pragma unroll
    for (int i = 0; i < 8; ++i)
        pos[b*L_ + t*8 + i] = mv[i] ? (base + loc[i]) : -1;
    if (t == 255) { kcount[b] = base + s; tot_s = base + s; }
    __syncthreads();
    int tot = tot_s;
    for (int l = t; l < L_; l += 256) cfm[b*L_ + l] = (l < tot) ? 0.0f : FMINV;
}

// ---------------------------------------------------------------------------
// Embedding with compaction
// ---------------------------------------------------------------------------
__global__ __launch_bounds__(128)
void embed_kernel(const float* __restrict__ values, const float* __restrict__ times,
                  const int* __restrict__ variables, const int* __restrict__ pos,
                  const float* __restrict__ W1t, const float* __restrict__ b1t,
                  const float* __restrict__ W2t,
                  const float* __restrict__ W1v, const float* __restrict__ b1v,
                  const float* __restrict__ W2v,
                  const float* __restrict__ var_table, float* __restrict__ x)
{
    int bl = blockIdx.x;
    int p  = pos[bl];
    if (p < 0) return;
    int t  = threadIdx.x;
    __shared__ float th[INTD_], vh[INTD_];
    if (t < INTD_)                th[t]    = tanhf(times[bl]  * W1t[t]    + b1t[t]);
    if (t >= 64 && t < 64+INTD_)  vh[t-64] = tanhf(values[bl] * W1v[t-64] + b1v[t-64]);
    __syncthreads();
    int var = variables[bl];
    float acc = var_table[var*D_ + t];
#pragma unroll
    for (int i = 0; i < INTD_; ++i)
        acc += th[i]*W2t[i*D_ + t] + vh[i]*W2v[i*D_ + t];
    x[((size_t)((bl >> 11)*2048 + p))*D_ + t] = acc;
}

// zero compact x tail rows [Kb, ceil64(Kb)) once
__global__ __launch_bounds__(256)
void xtail_zero_kernel(const int* __restrict__ kcount, float* __restrict__ x)
{
    int b = blockIdx.x, t = threadIdx.x;
    int Kb = kcount[b];
    int end = (Kb + 63) & ~63;
    int tot = (end - Kb) * D_;
    for (int i = t; i < tot; i += 256)
        x[((size_t)(b*2048 + Kb))*D_ + i] = 0.0f;
}

// ---------------------------------------------------------------------------
// Weight pre-splits
// ---------------------------------------------------------------------------
__global__ __launch_bounds__(256)
void split_all_kernel(const float* __restrict__ Wq, const float* __restrict__ Wk,
                      const float* __restrict__ Wv, const float* __restrict__ Wo,
                      const float* __restrict__ W1, const float* __restrict__ W2,
                      short* __restrict__ hi, short* __restrict__ lo)
{
    int gidx = blockIdx.x*256 + threadIdx.x;
    int layer = gidx >> 17;
    int idx   = gidx & 131071;
    float v;
    if (idx < 49152) {
        int which = idx >> 14;
        int r = idx & 16383;
        int col = r >> 7, k = r & 127;
        int h = col >> 5, e = col & 31;
        const float* src = ((which == 0) ? Wq : (which == 1) ? Wk : Wv)
                           + (size_t)layer*H_*D_*DK_;
        v = src[(h*D_ + k)*DK_ + e];
    } else if (idx < 65536) {
        int r = idx - 49152;
        int col = r >> 7, k = r & 127;
        v = Wo[(size_t)layer*D_*D_ + k*D_ + col];
    } else if (idx < 98304) {
        int r = idx - 65536;
        int col = r >> 7, k = r & 127;
        v = W1[(size_t)layer*D_*DFF_ + k*DFF_ + col];
    } else {
        int r = idx - 98304;
        int col = r >> 8, k = r & 255;
        v = W2[(size_t)layer*DFF_*D_ + k*D_ + col];
    }
    short h2, l2; split2(v, h2, l2);
    hi[gidx] = h2; lo[gidx] = l2;
}

__global__ __launch_bounds__(256)
void split_nk_kernel(const float* __restrict__ W, short* __restrict__ hi,
                     short* __restrict__ lo, int N, int K)
{
    int idx = blockIdx.x*256 + threadIdx.x;
    int col = idx / K, k = idx - col*K;
    float v = W[k*N + col];
    short h2, l2; split2(v, h2, l2);
    hi[idx] = h2; lo[idx] = l2;
}

// ---------------------------------------------------------------------------
// MFMA GEMM on COMPACT rows (early-exit past ceil64(Kb)). 64-row blocks.
// EPI: 1=+resid 2=+bias,gelu 3=+bias,+resid 7=fusion att dot (+cfm)
// ---------------------------------------------------------------------------
template<int EPI>
__global__ __launch_bounds__(256)
void gemm_mfma(const float* __restrict__ A, const short* __restrict__ Whi,
               const short* __restrict__ Wlo, const float* __restrict__ bias,
               const float* __restrict__ resid, float* __restrict__ out,
               const float* __restrict__ cfm, const int* __restrict__ kcount,
               int N, int K)
{
    const int row0 = blockIdx.x * 64;
    const int bb = row0 >> 11;
    if ((row0 & 2047) >= ((kcount[bb] + 63) & ~63)) return;

    __shared__ short Ahi[64*136];
    __shared__ short Alo[64*136];
    __shared__ float part[64][16];
    const int t = threadIdx.x;
    const int w = t >> 6, lane = t & 63;
    const int m = lane & 15, qd = lane >> 4;
    const int col0 = blockIdx.y * 128;

    f32x4 acc[4][2];
#pragma unroll
    for (int r4 = 0; r4 < 4; ++r4)
#pragma unroll
        for (int j = 0; j < 2; ++j) acc[r4][j] = (f32x4){0,0,0,0};

    for (int kb = 0; kb < K; kb += 128) {
        if (kb) __syncthreads();
#pragma unroll
        for (int i = 0; i < 8; ++i) {
            int r = (t >> 5) + 8*i;
            int c = (t & 31) * 4;
            float4 av = *(const float4*)(A + (size_t)(row0 + r)*K + kb + c);
            short4 hi4, lo4;
            split2(av.x, hi4.x, lo4.x);
            split2(av.y, hi4.y, lo4.y);
            split2(av.z, hi4.z, lo4.z);
            split2(av.w, hi4.w, lo4.w);
            *(short4*)&Ahi[r*136 + c] = hi4;
            *(short4*)&Alo[r*136 + c] = lo4;
        }
        __syncthreads();

#pragma unroll
        for (int ks = 0; ks < 4; ++ks) {
            bf16x8 wh[2], wl[2];
#pragma unroll
            for (int j = 0; j < 2; ++j) {
                size_t wi = (size_t)(col0 + 32*w + 16*j + m)*K + kb + 32*ks + 8*qd;
                wh[j] = *(const bf16x8*)(Whi + wi);
                wl[j] = *(const bf16x8*)(Wlo + wi);
            }
#pragma unroll
            for (int r4 = 0; r4 < 4; ++r4) {
                bf16x8 ah = *(const bf16x8*)&Ahi[(16*r4 + m)*136 + 32*ks + 8*qd];
                bf16x8 al = *(const bf16x8*)&Alo[(16*r4 + m)*136 + 32*ks + 8*qd];
#pragma unroll
                for (int j = 0; j < 2; ++j) {
                    acc[r4][j] = __builtin_amdgcn_mfma_f32_16x16x32_bf16(wh[j], ah, acc[r4][j], 0, 0, 0);
                    acc[r4][j] = __builtin_amdgcn_mfma_f32_16x16x32_bf16(wh[j], al, acc[r4][j], 0, 0, 0);
                    acc[r4][j] = __builtin_amdgcn_mfma_f32_16x16x32_bf16(wl[j], ah, acc[r4][j], 0, 0, 0);
                }
            }
        }
    }

#pragma unroll
    for (int r4 = 0; r4 < 4; ++r4) {
        int row = row0 + 16*r4 + m;
        float dotp = 0.0f;
#pragma unroll
        for (int j = 0; j < 2; ++j) {
            int col = col0 + 32*w + 16*j + 4*qd;
            f32x4 v = acc[r4][j];
            if (EPI == 2 || EPI == 3 || EPI == 7) {
                float4 bv = *(const float4*)(bias + col);
                v[0] += bv.x; v[1] += bv.y; v[2] += bv.z; v[3] += bv.w;
            }
            if (EPI == 2) {
#pragma unroll
                for (int e = 0; e < 4; ++e)
                    v[e] = 0.5f * v[e] * (1.0f + erff(v[e] * 0.70710678118654752f));
            }
            if (EPI == 7) {
#pragma unroll
                for (int e = 0; e < 4; ++e) v[e] = tanhf(v[e]);
            }
            if (EPI == 1 || EPI == 3) {
                float4 rv = *(const float4*)(resid + (size_t)row*N + col);
                v[0] += rv.x; v[1] += rv.y; v[2] += rv.z; v[3] += rv.w;
            }
            if (EPI == 7) {
                float4 uv = *(const float4*)(resid + col);   // uf
                dotp += v[0]*uv.x + v[1]*uv.y + v[2]*uv.z + v[3]*uv.w;
            } else {
                float4 sv = {v[0], v[1], v[2], v[3]};
                *(float4*)(out + (size_t)row*N + col) = sv;
            }
        }
        if (EPI == 7) part[16*r4 + m][4*w + qd] = dotp;
    }
    if (EPI == 7) {
        __syncthreads();
        if (t < 64) {
            float s = 0.0f;
#pragma unroll
            for (int i = 0; i < 16; ++i) s += part[t][i];
            out[row0 + t] = s + cfm[row0 + t];
        }
    }
}

// ---------------------------------------------------------------------------
// Fused QKV GEMM on compact rows, one weight stream per block (grid.y=3):
// sec 0: Q fp32; sec 1: K hi/lo head-major; sec 2: V^T hi/lo.
// ---------------------------------------------------------------------------
__global__ __launch_bounds__(256)
void gemm_qkv_fused(const float* __restrict__ A, const short* __restrict__ Whi,
                    const short* __restrict__ Wlo, const int* __restrict__ kcount,
                    float* __restrict__ qout,
                    short* __restrict__ khi, short* __restrict__ klo,
                    short* __restrict__ vhiT, short* __restrict__ vloT)
{
    const int row0 = blockIdx.x * 64;
    const int bb = row0 >> 11;
    if ((row0 & 2047) >= ((kcount[bb] + 63) & ~63)) return;
    const int sec = blockIdx.y;

    __shared__ short Ahi[64*136];
    __shared__ short Alo[64*136];
    const int t = threadIdx.x;
    const int w = t >> 6, lane = t & 63;
    const int m = lane & 15, qd = lane >> 4;

#pragma unroll
    for (int i = 0; i < 8; ++i) {
        int r = (t >> 5) + 8*i;
        int c = (t & 31) * 4;
        float4 av = *(const float4*)(A + (size_t)(row0 + r)*D_ + c);
        short4 hi4, lo4;
        split2(av.x, hi4.x, lo4.x);
        split2(av.y, hi4.y, lo4.y);
        split2(av.z, hi4.z, lo4.z);
        split2(av.w, hi4.w, lo4.w);
        *(short4*)&Ahi[r*136 + c] = hi4;
        *(short4*)&Alo[r*136 + c] = lo4;
    }
    __syncthreads();

    const short* Wh = Whi + sec*16384;
    const short* Wl = Wlo + sec*16384;
    f32x4 acc[4][2];
#pragma unroll
    for (int r4 = 0; r4 < 4; ++r4)
#pragma unroll
        for (int j = 0; j < 2; ++j) acc[r4][j] = (f32x4){0,0,0,0};

#pragma unroll
    for (int ks = 0; ks < 4; ++ks) {
        bf16x8 wh[2], wl[2];
#pragma unroll
        for (int j = 0; j < 2; ++j) {
            size_t wi = (size_t)(32*w + 16*j + m)*D_ + 32*ks + 8*qd;
            wh[j] = *(const bf16x8*)(Wh + wi);
            wl[j] = *(const bf16x8*)(Wl + wi);
        }
#pragma unroll
        for (int r4 = 0; r4 < 4; ++r4) {
            bf16x8 ah = *(const bf16x8*)&Ahi[(16*r4 + m)*136 + 32*ks + 8*qd];
            bf16x8 al = *(const bf16x8*)&Alo[(16*r4 + m)*136 + 32*ks + 8*qd];
#pragma unroll
            for (int j = 0; j < 2; ++j) {
                acc[r4][j] = __builtin_amdgcn_mfma_f32_16x16x32_bf16(wh[j], ah, acc[r4][j], 0, 0, 0);
                acc[r4][j] = __builtin_amdgcn_mfma_f32_16x16x32_bf16(wh[j], al, acc[r4][j], 0, 0, 0);
                acc[r4][j] = __builtin_amdgcn_mfma_f32_16x16x32_bf16(wl[j], ah, acc[r4][j], 0, 0, 0);
            }
        }
    }

#pragma unroll
    for (int r4 = 0; r4 < 4; ++r4) {
        int row = row0 + 16*r4 + m;
        int l = row & 2047;
#pragma unroll
        for (int j = 0; j < 2; ++j) {
            int col = 32*w + 16*j + 4*qd;
            f32x4 v = acc[r4][j];
            if (sec == 0) {
                float4 sv = {v[0], v[1], v[2], v[3]};
                *(float4*)(qout + (size_t)row*D_ + col) = sv;
            } else if (sec == 1) {
                size_t idx = ((size_t)((bb*4 + w)*2048 + l))*32 + (col & 31);
                short4 hi4, lo4;
                split2(v[0], hi4.x, lo4.x);
                split2(v[1], hi4.y, lo4.y);
                split2(v[2], hi4.z, lo4.z);
                split2(v[3], hi4.w, lo4.w);
                *(short4*)(khi + idx) = hi4;
                *(short4*)(klo + idx) = lo4;
            } else {
                size_t basep = (size_t)(bb*4 + w)*32;
#pragma unroll
                for (int e = 0; e < 4; ++e) {
                    int d = 16*j + 4*qd + e;
                    short hh, ll; split2(v[e], hh, ll);
                    vhiT[(basep + d)*2048 + l] = hh;
                    vloT[(basep + d)*2048 + l] = ll;
                }
            }
        }
    }
}

// ---------------------------------------------------------------------------
// MFMA flash attention over compact rows, depth-1 scalar-register prefetch
// (R11-proven: no dynamic register indexing -> no scratch spill).
// ---------------------------------------------------------------------------
__global__ __launch_bounds__(256)
void attn_mfma_kernel(const float* __restrict__ q,
                      const short* __restrict__ khi, const short* __restrict__ klo,
                      const short* __restrict__ vhiT, const short* __restrict__ vloT,
                      const int* __restrict__ kcount, const float* __restrict__ cfm,
                      float* __restrict__ o)
{
    __shared__ short KhiS[64*32];
    __shared__ short KloS[64*32];
    __shared__ short Vthi[32*72];
    __shared__ short Vtlo[32*72];
    __shared__ short Pshi[4][16*PSTR];
    __shared__ short Pslo[4][16*PSTR];
    __shared__ float kmf[64];
    __shared__ float al_ls[4][16];
    __shared__ float l_ls [4][16];

    const int t    = threadIdx.x;
    const int w    = t >> 6;
    const int lane = t & 63;
    const int m    = lane & 15;
    const int qd   = lane >> 4;
    const int qt = blockIdx.x, h = blockIdx.y, b = blockIdx.z;

    const int Kb = kcount[b];
    if (qt*64 >= Kb) return;
    const int nt = (Kb + 63) >> 6;

    const size_t hd = ((size_t)(b*4 + h))*2048*32;
    const int vd = t >> 3;
    const int vk = (t & 7) * 8;
    const size_t vbase = ((size_t)(b*4 + h)*32 + vd)*2048 + vk;

    const int qrow = qt*64 + 16*w + m;
    const float* qp = q + ((size_t)(b*L_ + qrow))*D_ + h*DK_ + 8*qd;
    float qf[8];
    *(float4*)&qf[0] = *(const float4*)qp;
    *(float4*)&qf[4] = *(const float4*)(qp + 4);
    bf16x8 qhi, qlo;
#pragma unroll
    for (int j = 0; j < 8; ++j) {
        float qs = qf[j] * LOG2E;
        short hs = f2bf(qs);
        qhi[j] = hs;
        qlo[j] = f2bf(qs - bf2f(hs));
    }

    bf16x8 pkh, pkl, pvh, pvl;
    float4 pmask = {0,0,0,0};
    {
        const size_t gk = hd + (size_t)t*8;
        pkh = *(const bf16x8*)(khi + gk);
        pkl = *(const bf16x8*)(klo + gk);
        pvh = *(const bf16x8*)(vhiT + vbase);
        pvl = *(const bf16x8*)(vloT + vbase);
        if (t < 16) pmask = ((const float4*)(cfm + (size_t)b*L_))[t];
    }

    float m_old = -INFINITY, l_run = 0.0f;
    f32x4 o_acc[2] = {{0,0,0,0},{0,0,0,0}};

    for (int kt = 0; kt < nt; ++kt) {
        __syncthreads();
        *(bf16x8*)&KhiS[t*8] = pkh;
        *(bf16x8*)&KloS[t*8] = pkl;
        *(bf16x8*)&Vthi[vd*72 + vk] = pvh;
        *(bf16x8*)&Vtlo[vd*72 + vk] = pvl;
        if (t < 16) ((float4*)kmf)[t] = pmask;
        __syncthreads();
        if (kt + 1 < nt) {
            const size_t gk = hd + (size_t)(kt+1)*64*32 + t*8;
            pkh = *(const bf16x8*)(khi + gk);
            pkl = *(const bf16x8*)(klo + gk);
            pvh = *(const bf16x8*)(vhiT + vbase + (size_t)(kt+1)*64);
            pvl = *(const bf16x8*)(vloT + vbase + (size_t)(kt+1)*64);
            if (t < 16) pmask = ((const float4*)(cfm + (size_t)b*L_ + (size_t)(kt+1)*64))[t];
        }

        f32x4 sf[4];
#pragma unroll
        for (int k4 = 0; k4 < 4; ++k4) {
            bf16x8 ka = *(const bf16x8*)&KhiS[(16*k4 + m)*32 + 8*qd];
            bf16x8 kl = *(const bf16x8*)&KloS[(16*k4 + m)*32 + 8*qd];
            f32x4 c = {0,0,0,0};
            c = __builtin_amdgcn_mfma_f32_16x16x32_bf16(ka, qhi, c, 0, 0, 0);
            c = __builtin_amdgcn_mfma_f32_16x16x32_bf16(ka, qlo, c, 0, 0, 0);
            c = __builtin_amdgcn_mfma_f32_16x16x32_bf16(kl, qhi, c, 0, 0, 0);
            sf[k4] = c;
        }

        float sv[16];
#pragma unroll
        for (int k4 = 0; k4 < 4; ++k4) {
            float4 kmv = *(const float4*)&kmf[16*k4 + 4*qd];
            sv[4*k4+0] = sf[k4][0] + kmv.x;
            sv[4*k4+1] = sf[k4][1] + kmv.y;
            sv[4*k4+2] = sf[k4][2] + kmv.z;
            sv[4*k4+3] = sf[k4][3] + kmv.w;
        }

        float tmax = sv[0];
#pragma unroll
        for (int j = 1; j < 16; ++j) tmax = fmaxf(tmax, sv[j]);
        tmax = fmaxf(tmax, __shfl_xor(tmax, 16));
        tmax = fmaxf(tmax, __shfl_xor(tmax, 32));
        float mnew  = fmaxf(m_old, tmax);
        float alpha = EXP2F(m_old - mnew);
        float psum = 0.0f;
        short pbh[16], pbl[16];
#pragma unroll
        for (int j = 0; j < 16; ++j) {
            float p = EXP2F(sv[j] - mnew);
            psum += p;
            split_trunc(p, pbh[j], pbl[j]);
        }
        psum += __shfl_xor(psum, 16);
        psum += __shfl_xor(psum, 32);
        l_run = l_run * alpha + psum;
        m_old = mnew;

#pragma unroll
        for (int k4 = 0; k4 < 4; ++k4) {
            short4 s4h, s4l;
            s4h.x = pbh[4*k4+0]; s4h.y = pbh[4*k4+1]; s4h.z = pbh[4*k4+2]; s4h.w = pbh[4*k4+3];
            s4l.x = pbl[4*k4+0]; s4l.y = pbl[4*k4+1]; s4l.z = pbl[4*k4+2]; s4l.w = pbl[4*k4+3];
            *(short4*)&Pshi[w][m*PSTR + 16*k4 + 4*qd] = s4h;
            *(short4*)&Pslo[w][m*PSTR + 16*k4 + 4*qd] = s4l;
        }
        if (lane < 16) al_ls[w][lane] = alpha;

        {
            float4 alr = *(const float4*)&al_ls[w][4*qd];
            o_acc[0][0]*=alr.x; o_acc[0][1]*=alr.y; o_acc[0][2]*=alr.z; o_acc[0][3]*=alr.w;
            o_acc[1][0]*=alr.x; o_acc[1][1]*=alr.y; o_acc[1][2]*=alr.z; o_acc[1][3]*=alr.w;
        }
#pragma unroll
        for (int s = 0; s < 2; ++s) {
            bf16x8 pah = *(const bf16x8*)&Pshi[w][m*PSTR + 32*s + 8*qd];
            bf16x8 pal = *(const bf16x8*)&Pslo[w][m*PSTR + 32*s + 8*qd];
#pragma unroll
            for (int tp = 0; tp < 2; ++tp) {
                bf16x8 vh = *(const bf16x8*)&Vthi[(16*tp + m)*72 + 32*s + 8*qd];
                bf16x8 vl = *(const bf16x8*)&Vtlo[(16*tp + m)*72 + 32*s + 8*qd];
                o_acc[tp] = __builtin_amdgcn_mfma_f32_16x16x32_bf16(pah, vh, o_acc[tp], 0, 0, 0);
                o_acc[tp] = __builtin_amdgcn_mfma_f32_16x16x32_bf16(pah, vl, o_acc[tp], 0, 0, 0);
                o_acc[tp] = __builtin_amdgcn_mfma_f32_16x16x32_bf16(pal, vh, o_acc[tp], 0, 0, 0);
            }
        }
    }

    if (lane < 16) l_ls[w][lane] = l_run;
    float4 lr = *(const float4*)&l_ls[w][4*qd];
    float li[4] = {1.0f/lr.x, 1.0f/lr.y, 1.0f/lr.z, 1.0f/lr.w};
#pragma unroll
    for (int tp = 0; tp < 2; ++tp)
#pragma unroll
        for (int r = 0; r < 4; ++r)
            o[((size_t)(b*L_ + qt*64 + 16*w + 4*qd + r))*D_ + h*DK_ + 16*tp + m] =
                o_acc[tp][r] * li[r];
}

// ---------------------------------------------------------------------------
// Pooling
// ---------------------------------------------------------------------------
__global__ __launch_bounds__(256)
void pool_stats_kernel(const float* __restrict__ att, const int* __restrict__ kcount,
                       float* __restrict__ p)
{
    int b = blockIdx.x, t = threadIdx.x;
    int lim = (kcount[b] + 63) & ~63;
    __shared__ float red[4];
    __shared__ float a_s[L_];

    float m = -INFINITY;
    for (int l = t; l < L_; l += 256) {
        float a = (l < lim) ? att[b*L_ + l] : FMINV;
        a_s[l] = a;
        m = fmaxf(m, a);
    }
#pragma unroll
    for (int s = 1; s < 64; s <<= 1) m = fmaxf(m, __shfl_xor(m, s));
    if ((t & 63) == 0) red[t >> 6] = m;
    __syncthreads();
    m = fmaxf(fmaxf(red[0], red[1]), fmaxf(red[2], red[3]));
    __syncthreads();

    float s = 0.0f;
    for (int l = t; l < L_; l += 256) s += __expf(a_s[l] - m);
#pragma unroll
    for (int st = 1; st < 64; st <<= 1) s += __shfl_xor(s, st);
    if ((t & 63) == 0) red[t >> 6] = s;
    __syncthreads();
    s = red[0] + red[1] + red[2] + red[3];
    float inv = 1.0f / s;
    for (int l = t; l < L_; l += 256)
        p[b*L_ + l] = (l < lim) ? __expf(a_s[l] - m) * inv : 0.0f;
}

__global__ __launch_bounds__(128)
void pool_partial_kernel(const float* __restrict__ p, const float* __restrict__ x,
                         float* __restrict__ part)
{
    int c = blockIdx.x, b = blockIdx.y, d = threadIdx.x;
    const float* xb = x + ((size_t)(b*L_ + c*128))*D_ + d;
    const float* pb = p + b*L_ + c*128;
    float acc = 0.0f;
#pragma unroll 4
    for (int i = 0; i < 128; ++i) acc += pb[i] * xb[(size_t)i*D_];
    part[((size_t)b*16 + c)*D_ + d] = acc;
}

// ---------------------------------------------------------------------------
// Demographics MLP
// ---------------------------------------------------------------------------
__global__ __launch_bounds__(256)
void demo_kernel(const float* __restrict__ demog, const float* __restrict__ Wd1,
                 const float* __restrict__ bd1, const float* __restrict__ Wd2,
                 const float* __restrict__ bd2, float* __restrict__ demo_out)
{
    int t = threadIdx.x;
    __shared__ float dsm[B_][DM_];
    __shared__ float hs[B_][2*D_];
    if (t < B_*DM_) dsm[t >> 4][t & 15] = demog[t];
    __syncthreads();
    {
        int col = t;
#pragma unroll
        for (int r = 0; r < B_; ++r) {
            float acc = bd1[col];
#pragma unroll
            for (int kk = 0; kk < DM_; ++kk) acc += dsm[r][kk]*Wd1[kk*(2*D_)+col];
            hs[r][col] = tanhf(acc);
        }
    }
    __syncthreads();
    {
        int c  = t & (D_-1);
        int r0 = t >> 7;
        for (int r = r0; r < B_; r += 2) {
            float acc = bd2[c];
            for (int kk = 0; kk < 2*D_; ++kk) acc += hs[r][kk]*Wd2[kk*D_+c];
            demo_out[r*D_+c] = acc;
        }
    }
}

// ---------------------------------------------------------------------------
// Head
// ---------------------------------------------------------------------------
__global__ __launch_bounds__(256)
void head_kernel(const float* __restrict__ part, const float* __restrict__ demo,
                 const float* __restrict__ Wh, const float* __restrict__ bh,
                 float* __restrict__ out)
{
    int b = blockIdx.x, t = threadIdx.x;
    __shared__ float tss[128];
    if (t < 128) {
        float s = 0.0f;
#pragma unroll
        for (int c = 0; c < 16; ++c) s += part[((size_t)b*16 + c)*D_ + t];
        tss[t] = s;
    }
    __syncthreads();
    if (t >= F_OUT) return;
    float acc = bh[t];
    for (int k2 = 0; k2 < D_; ++k2) acc += tss[k2]         * Wh[k2*F_OUT + t];
    for (int k2 = 0; k2 < D_; ++k2) acc += demo[b*D_ + k2] * Wh[(D_+k2)*F_OUT + t];
    out[b*F_OUT + t] = acc;
}

// ---------------------------------------------------------------------------
extern "C" void kernel_launch(void* const* d_in, const int* in_sizes, int n_in,
                              void* d_out, int out_size, void* d_ws, size_t ws_size,
                              hipStream_t stream)
{
    (void)in_sizes; (void)n_in; (void)out_size; (void)ws_size;
    const float* values       = (const float*)d_in[0];
    const float* times        = (const float*)d_in[1];
    const int*   variables    = (const int*)  d_in[2];
    const int*   input_mask   = (const int*)  d_in[3];
    const float* demographics = (const float*)d_in[4];
    const float* W1t = (const float*)d_in[5];
    const float* b1t = (const float*)d_in[6];
    const float* W2t = (const float*)d_in[7];
    const float* W1v = (const float*)d_in[8];
    const float* b1v = (const float*)d_in[9];
    const float* W2v = (const float*)d_in[10];
    const float* var_table = (const float*)d_in[11];
    const float* Wq  = (const float*)d_in[12];
    const float* Wk  = (const float*)d_in[13];
    const float* Wv  = (const float*)d_in[14];
    const float* Wo  = (const float*)d_in[15];
    const float* W1  = (const float*)d_in[16];
    const float* b1  = (const float*)d_in[17];
    const float* W2  = (const float*)d_in[18];
    const float* b2  = (const float*)d_in[19];
    const float* Wf  = (const float*)d_in[20];
    const float* bfv = (const float*)d_in[21];
    const float* uf  = (const float*)d_in[22];
    const float* Wd1 = (const float*)d_in[23];
    const float* bd1 = (const float*)d_in[24];
    const float* Wd2 = (const float*)d_in[25];
    const float* bd2 = (const float*)d_in[26];
    const float* Wh  = (const float*)d_in[27];
    const float* bhv = (const float*)d_in[28];
    float* out = (float*)d_out;

    float* ws     = (float*)d_ws;
    float* x      = ws;                   // compact rows
    float* qb     = ws + (size_t)SZ_X;
    float* region = ws + (size_t)2*SZ_X;
    short* khi    = (short*)region;
    short* klo    = khi + (size_t)SZ_X;
    short* vhiT   = klo + (size_t)SZ_X;
    short* vloT   = vhiT + (size_t)SZ_X;
    float* hb     = region;               // alias (FFN hidden)
    float* attb   = ws + (size_t)4*SZ_X;  // BL_
    float* attp   = attb + BL_;           // BL_
    float* partb  = attp + BL_;           // B_*16*D_
    float* demob  = partb + B_*16*D_;     // B_*D_
    short* wt_hi  = (short*)(demob + B_*D_);
    short* wt_lo  = wt_hi + (size_t)NL_*WT_TOT;
    short* wfhi   = wt_lo + (size_t)NL_*WT_TOT;
    short* wflo   = wfhi + 16384;
    int*   posb   = (int*)(wflo + 16384);       // BL_
    int*   kcountb= posb + BL_;                 // B_
    float* cfmb   = (float*)(kcountb + B_);     // BL_

    compact_kernel<<<B_, 256, 0, stream>>>(input_mask, posb, kcountb, cfmb);
    embed_kernel<<<BL_, 128, 0, stream>>>(values, times, variables, posb,
                                          W1t, b1t, W2t, W1v, b1v, W2v,
                                          var_table, x);
    xtail_zero_kernel<<<B_, 256, 0, stream>>>(kcountb, x);
    demo_kernel<<<1, 256, 0, stream>>>(demographics, Wd1, bd1, Wd2, bd2, demob);
    split_nk_kernel<<<64, 256, 0, stream>>>(Wf, wfhi, wflo, D_, D_);
    split_all_kernel<<<NL_*512, 256, 0, stream>>>(Wq, Wk, Wv, Wo, W1, W2, wt_hi, wt_lo);

    for (int i = 0; i < NL_; ++i) {
        short* whL = wt_hi + (size_t)i*WT_TOT;
        short* wlL = wt_lo + (size_t)i*WT_TOT;
        gemm_qkv_fused<<<dim3(BL_/64, 3), 256, 0, stream>>>(x, whL, wlL, kcountb,
            qb, khi, klo, vhiT, vloT);
        attn_mfma_kernel<<<dim3(L_/64, H_, B_), 256, 0, stream>>>(qb, khi, klo, vhiT, vloT,
                                                                  kcountb, cfmb, qb);
        gemm_mfma<1><<<dim3(BL_/64, 1), 256, 0, stream>>>(qb, whL+WT_O, wlL+WT_O,
            nullptr, x, x, nullptr, kcountb, D_, D_);
        gemm_mfma<2><<<dim3(BL_/64, 2), 256, 0, stream>>>(x, whL+WT_1, wlL+WT_1,
            b1 + i*DFF_, nullptr, hb, nullptr, kcountb, DFF_, D_);
        gemm_mfma<3><<<dim3(BL_/64, 1), 256, 0, stream>>>(hb, whL+WT_2, wlL+WT_2,
            b2 + i*D_, x, x, nullptr, kcountb, D_, DFF_);
    }

    // fused fusion-attention on compact rows: att = tanh(x@Wf+bf).uf + cfm
    gemm_mfma<7><<<dim3(BL_/64, 1), 256, 0, stream>>>(x, wfhi, wflo,
        bfv, uf, attb, cfmb, kcountb, D_, D_);
    pool_stats_kernel<<<B_, 256, 0, stream>>>(attb, kcountb, attp);
    pool_partial_kernel<<<dim3(16, B_), 128, 0, stream>>>(attp, x, partb);
    head_kernel<<<B_, 256, 0, stream>>>(partb, demob, Wh, bhv, out);
}

// Round 15
// 836.182 us; speedup vs baseline: 2.5038x; 1.0162x over previous
//
#include <hip/hip_runtime.h>
#include <hip/hip_bf16.h>
#include <math.h>

#define B_   16
#define L_   2048
#define D_   128
#define H_   4
#define NL_  4
#define DK_  32
#define DFF_ 256
#define INTD_ 11
#define F_OUT 129
#define DM_  16
#define FMINV (-3.402823466e38f)
#define LOG2E 1.4426950408889634f

#define BL_  (B_*L_)      // 32768
#define SZ_X (BL_*D_)     // 4194304 floats

#define PSTR 72           // attn P-scratch stride

#define WT_Q 0
#define WT_K 16384
#define WT_V 32768
#define WT_O 49152
#define WT_1 65536
#define WT_2 98304
#define WT_TOT 131072

typedef __attribute__((ext_vector_type(8))) short bf16x8;
typedef __attribute__((ext_vector_type(4))) float f32x4;

#if __has_builtin(__builtin_amdgcn_exp2f)
#define EXP2F(x) __builtin_amdgcn_exp2f(x)
#else
#define EXP2F(x) __expf(0.69314718055994531f*(x))
#endif

static __device__ __forceinline__ short f2bf(float x) {
    union { __hip_bfloat16 h; short s; } u;
    u.h = __float2bfloat16(x);
    return u.s;
}
static __device__ __forceinline__ float bf2f(short s) {
    union { __hip_bfloat16 h; short t; } u;
    u.t = s;
    return __bfloat162float(u.h);
}
static __device__ __forceinline__ void split2(float v, short& h, short& l) {
    h = f2bf(v); l = f2bf(v - bf2f(h));
}
static __device__ __forceinline__ void split_trunc(float v, short& h, short& l) {
    unsigned u = __float_as_uint(v);
    h = (short)(u >> 16);
    float r = v - __uint_as_float(u & 0xffff0000u);
    l = (short)(__float_as_uint(r) >> 16);
}

// ---------------------------------------------------------------------------
// Mask compaction: pos[b,l] = compact index or -1; kcount[b]; cfm[b,j]=0/FMIN.
// ---------------------------------------------------------------------------
__global__ __launch_bounds__(256)
void compact_kernel(const int* __restrict__ mask, int* __restrict__ pos,
                    int* __restrict__ kcount, float* __restrict__ cfm)
{
    int b = blockIdx.x, t = threadIdx.x;
    int lane = t & 63, w = t >> 6;
    __shared__ int wsum[4];
    __shared__ int tot_s;
    int mv[8], loc[8], s = 0;
#pragma unroll
    for (int i = 0; i < 8; ++i) {
        mv[i] = mask[b*L_ + t*8 + i];
        loc[i] = s;
        s += mv[i];
    }
    int v = s;
#pragma unroll
    for (int d = 1; d < 64; d <<= 1) {
        int y = __shfl_up(v, d);
        if (lane >= d) v += y;
    }
    int excl = v - s;
    if (lane == 63) wsum[w] = v;
    __syncthreads();
    int wbase = 0;
    for (int i = 0; i < w; ++i) wbase += wsum[i];
    int base = wbase + excl;
#pragma unroll
    for (int i = 0; i < 8; ++i)
        pos[b*L_ + t*8 + i] = mv[i] ? (base + loc[i]) : -1;
    if (t == 255) { kcount[b] = base + s; tot_s = base + s; }
    __syncthreads();
    int tot = tot_s;
    for (int l = t; l < L_; l += 256) cfm[b*L_ + l] = (l < tot) ? 0.0f : FMINV;
}

// ---------------------------------------------------------------------------
// Embedding with compaction
// ---------------------------------------------------------------------------
__global__ __launch_bounds__(128)
void embed_kernel(const float* __restrict__ values, const float* __restrict__ times,
                  const int* __restrict__ variables, const int* __restrict__ pos,
                  const float* __restrict__ W1t, const float* __restrict__ b1t,
                  const float* __restrict__ W2t,
                  const float* __restrict__ W1v, const float* __restrict__ b1v,
                  const float* __restrict__ W2v,
                  const float* __restrict__ var_table, float* __restrict__ x)
{
    int bl = blockIdx.x;
    int p  = pos[bl];
    if (p < 0) return;
    int t  = threadIdx.x;
    __shared__ float th[INTD_], vh[INTD_];
    if (t < INTD_)                th[t]    = tanhf(times[bl]  * W1t[t]    + b1t[t]);
    if (t >= 64 && t < 64+INTD_)  vh[t-64] = tanhf(values[bl] * W1v[t-64] + b1v[t-64]);
    __syncthreads();
    int var = variables[bl];
    float acc = var_table[var*D_ + t];
#pragma unroll
    for (int i = 0; i < INTD_; ++i)
        acc += th[i]*W2t[i*D_ + t] + vh[i]*W2v[i*D_ + t];
    x[((size_t)((bl >> 11)*2048 + p))*D_ + t] = acc;
}

// zero compact x tail rows [Kb, ceil64(Kb)) once
__global__ __launch_bounds__(256)
void xtail_zero_kernel(const int* __restrict__ kcount, float* __restrict__ x)
{
    int b = blockIdx.x, t = threadIdx.x;
    int Kb = kcount[b];
    int end = (Kb + 63) & ~63;
    int tot = (end - Kb) * D_;
    for (int i = t; i < tot; i += 256)
        x[((size_t)(b*2048 + Kb))*D_ + i] = 0.0f;
}

// ---------------------------------------------------------------------------
// Weight pre-splits
// ---------------------------------------------------------------------------
__global__ __launch_bounds__(256)
void split_all_kernel(const float* __restrict__ Wq, const float* __restrict__ Wk,
                      const float* __restrict__ Wv, const float* __restrict__ Wo,
                      const float* __restrict__ W1, const float* __restrict__ W2,
                      short* __restrict__ hi, short* __restrict__ lo)
{
    int gidx = blockIdx.x*256 + threadIdx.x;
    int layer = gidx >> 17;
    int idx   = gidx & 131071;
    float v;
    if (idx < 49152) {
        int which = idx >> 14;
        int r = idx & 16383;
        int col = r >> 7, k = r & 127;
        int h = col >> 5, e = col & 31;
        const float* src = ((which == 0) ? Wq : (which == 1) ? Wk : Wv)
                           + (size_t)layer*H_*D_*DK_;
        v = src[(h*D_ + k)*DK_ + e];
    } else if (idx < 65536) {
        int r = idx - 49152;
        int col = r >> 7, k = r & 127;
        v = Wo[(size_t)layer*D_*D_ + k*D_ + col];
    } else if (idx < 98304) {
        int r = idx - 65536;
        int col = r >> 7, k = r & 127;
        v = W1[(size_t)layer*D_*DFF_ + k*DFF_ + col];
    } else {
        int r = idx - 98304;
        int col = r >> 8, k = r & 255;
        v = W2[(size_t)layer*DFF_*D_ + k*D_ + col];
    }
    short h2, l2; split2(v, h2, l2);
    hi[gidx] = h2; lo[gidx] = l2;
}

__global__ __launch_bounds__(256)
void split_nk_kernel(const float* __restrict__ W, short* __restrict__ hi,
                     short* __restrict__ lo, int N, int K)
{
    int idx = blockIdx.x*256 + threadIdx.x;
    int col = idx / K, k = idx - col*K;
    float v = W[k*N + col];
    short h2, l2; split2(v, h2, l2);
    hi[idx] = h2; lo[idx] = l2;
}

// ---------------------------------------------------------------------------
// MFMA GEMM on COMPACT rows (early-exit past ceil64(Kb)). 64-row blocks.
// EPI: 2=+bias,gelu 3=+bias,+resid 7=fusion att dot (+cfm)
// ---------------------------------------------------------------------------
template<int EPI>
__global__ __launch_bounds__(256)
void gemm_mfma(const float* __restrict__ A, const short* __restrict__ Whi,
               const short* __restrict__ Wlo, const float* __restrict__ bias,
               const float* __restrict__ resid, float* __restrict__ out,
               const float* __restrict__ cfm, const int* __restrict__ kcount,
               int N, int K)
{
    const int row0 = blockIdx.x * 64;
    const int bb = row0 >> 11;
    if ((row0 & 2047) >= ((kcount[bb] + 63) & ~63)) return;

    __shared__ short Ahi[64*136];
    __shared__ short Alo[64*136];
    __shared__ float part[64][16];
    const int t = threadIdx.x;
    const int w = t >> 6, lane = t & 63;
    const int m = lane & 15, qd = lane >> 4;
    const int col0 = blockIdx.y * 128;

    f32x4 acc[4][2];
#pragma unroll
    for (int r4 = 0; r4 < 4; ++r4)
#pragma unroll
        for (int j = 0; j < 2; ++j) acc[r4][j] = (f32x4){0,0,0,0};

    for (int kb = 0; kb < K; kb += 128) {
        if (kb) __syncthreads();
#pragma unroll
        for (int i = 0; i < 8; ++i) {
            int r = (t >> 5) + 8*i;
            int c = (t & 31) * 4;
            float4 av = *(const float4*)(A + (size_t)(row0 + r)*K + kb + c);
            short4 hi4, lo4;
            split2(av.x, hi4.x, lo4.x);
            split2(av.y, hi4.y, lo4.y);
            split2(av.z, hi4.z, lo4.z);
            split2(av.w, hi4.w, lo4.w);
            *(short4*)&Ahi[r*136 + c] = hi4;
            *(short4*)&Alo[r*136 + c] = lo4;
        }
        __syncthreads();

#pragma unroll
        for (int ks = 0; ks < 4; ++ks) {
            bf16x8 wh[2], wl[2];
#pragma unroll
            for (int j = 0; j < 2; ++j) {
                size_t wi = (size_t)(col0 + 32*w + 16*j + m)*K + kb + 32*ks + 8*qd;
                wh[j] = *(const bf16x8*)(Whi + wi);
                wl[j] = *(const bf16x8*)(Wlo + wi);
            }
#pragma unroll
            for (int r4 = 0; r4 < 4; ++r4) {
                bf16x8 ah = *(const bf16x8*)&Ahi[(16*r4 + m)*136 + 32*ks + 8*qd];
                bf16x8 al = *(const bf16x8*)&Alo[(16*r4 + m)*136 + 32*ks + 8*qd];
#pragma unroll
                for (int j = 0; j < 2; ++j) {
                    acc[r4][j] = __builtin_amdgcn_mfma_f32_16x16x32_bf16(wh[j], ah, acc[r4][j], 0, 0, 0);
                    acc[r4][j] = __builtin_amdgcn_mfma_f32_16x16x32_bf16(wh[j], al, acc[r4][j], 0, 0, 0);
                    acc[r4][j] = __builtin_amdgcn_mfma_f32_16x16x32_bf16(wl[j], ah, acc[r4][j], 0, 0, 0);
                }
            }
        }
    }

#pragma unroll
    for (int r4 = 0; r4 < 4; ++r4) {
        int row = row0 + 16*r4 + m;
        float dotp = 0.0f;
#pragma unroll
        for (int j = 0; j < 2; ++j) {
            int col = col0 + 32*w + 16*j + 4*qd;
            f32x4 v = acc[r4][j];
            if (EPI == 2 || EPI == 3 || EPI == 7) {
                float4 bv = *(const float4*)(bias + col);
                v[0] += bv.x; v[1] += bv.y; v[2] += bv.z; v[3] += bv.w;
            }
            if (EPI == 2) {
#pragma unroll
                for (int e = 0; e < 4; ++e)
                    v[e] = 0.5f * v[e] * (1.0f + erff(v[e] * 0.70710678118654752f));
            }
            if (EPI == 7) {
#pragma unroll
                for (int e = 0; e < 4; ++e) v[e] = tanhf(v[e]);
            }
            if (EPI == 3) {
                float4 rv = *(const float4*)(resid + (size_t)row*N + col);
                v[0] += rv.x; v[1] += rv.y; v[2] += rv.z; v[3] += rv.w;
            }
            if (EPI == 7) {
                float4 uv = *(const float4*)(resid + col);   // uf
                dotp += v[0]*uv.x + v[1]*uv.y + v[2]*uv.z + v[3]*uv.w;
            } else {
                float4 sv = {v[0], v[1], v[2], v[3]};
                *(float4*)(out + (size_t)row*N + col) = sv;
            }
        }
        if (EPI == 7) part[16*r4 + m][4*w + qd] = dotp;
    }
    if (EPI == 7) {
        __syncthreads();
        if (t < 64) {
            float s = 0.0f;
#pragma unroll
            for (int i = 0; i < 16; ++i) s += part[t][i];
            out[row0 + t] = s + cfm[row0 + t];
        }
    }
}

// ---------------------------------------------------------------------------
// Fused QKV GEMM on compact rows, one weight stream per block (grid.y=3):
// sec 0: Q fp32; sec 1: K hi/lo head-major; sec 2: V^T hi/lo.
// ---------------------------------------------------------------------------
__global__ __launch_bounds__(256)
void gemm_qkv_fused(const float* __restrict__ A, const short* __restrict__ Whi,
                    const short* __restrict__ Wlo, const int* __restrict__ kcount,
                    float* __restrict__ qout,
                    short* __restrict__ khi, short* __restrict__ klo,
                    short* __restrict__ vhiT, short* __restrict__ vloT)
{
    const int row0 = blockIdx.x * 64;
    const int bb = row0 >> 11;
    if ((row0 & 2047) >= ((kcount[bb] + 63) & ~63)) return;
    const int sec = blockIdx.y;

    __shared__ short Ahi[64*136];
    __shared__ short Alo[64*136];
    const int t = threadIdx.x;
    const int w = t >> 6, lane = t & 63;
    const int m = lane & 15, qd = lane >> 4;

#pragma unroll
    for (int i = 0; i < 8; ++i) {
        int r = (t >> 5) + 8*i;
        int c = (t & 31) * 4;
        float4 av = *(const float4*)(A + (size_t)(row0 + r)*D_ + c);
        short4 hi4, lo4;
        split2(av.x, hi4.x, lo4.x);
        split2(av.y, hi4.y, lo4.y);
        split2(av.z, hi4.z, lo4.z);
        split2(av.w, hi4.w, lo4.w);
        *(short4*)&Ahi[r*136 + c] = hi4;
        *(short4*)&Alo[r*136 + c] = lo4;
    }
    __syncthreads();

    const short* Wh = Whi + sec*16384;
    const short* Wl = Wlo + sec*16384;
    f32x4 acc[4][2];
#pragma unroll
    for (int r4 = 0; r4 < 4; ++r4)
#pragma unroll
        for (int j = 0; j < 2; ++j) acc[r4][j] = (f32x4){0,0,0,0};

#pragma unroll
    for (int ks = 0; ks < 4; ++ks) {
        bf16x8 wh[2], wl[2];
#pragma unroll
        for (int j = 0; j < 2; ++j) {
            size_t wi = (size_t)(32*w + 16*j + m)*D_ + 32*ks + 8*qd;
            wh[j] = *(const bf16x8*)(Wh + wi);
            wl[j] = *(const bf16x8*)(Wl + wi);
        }
#pragma unroll
        for (int r4 = 0; r4 < 4; ++r4) {
            bf16x8 ah = *(const bf16x8*)&Ahi[(16*r4 + m)*136 + 32*ks + 8*qd];
            bf16x8 al = *(const bf16x8*)&Alo[(16*r4 + m)*136 + 32*ks + 8*qd];
#pragma unroll
            for (int j = 0; j < 2; ++j) {
                acc[r4][j] = __builtin_amdgcn_mfma_f32_16x16x32_bf16(wh[j], ah, acc[r4][j], 0, 0, 0);
                acc[r4][j] = __builtin_amdgcn_mfma_f32_16x16x32_bf16(wh[j], al, acc[r4][j], 0, 0, 0);
                acc[r4][j] = __builtin_amdgcn_mfma_f32_16x16x32_bf16(wl[j], ah, acc[r4][j], 0, 0, 0);
            }
        }
    }

#pragma unroll
    for (int r4 = 0; r4 < 4; ++r4) {
        int row = row0 + 16*r4 + m;
        int l = row & 2047;
#pragma unroll
        for (int j = 0; j < 2; ++j) {
            int col = 32*w + 16*j + 4*qd;
            f32x4 v = acc[r4][j];
            if (sec == 0) {
                float4 sv = {v[0], v[1], v[2], v[3]};
                *(float4*)(qout + (size_t)row*D_ + col) = sv;
            } else if (sec == 1) {
                size_t idx = ((size_t)((bb*4 + w)*2048 + l))*32 + (col & 31);
                short4 hi4, lo4;
                split2(v[0], hi4.x, lo4.x);
                split2(v[1], hi4.y, lo4.y);
                split2(v[2], hi4.z, lo4.z);
                split2(v[3], hi4.w, lo4.w);
                *(short4*)(khi + idx) = hi4;
                *(short4*)(klo + idx) = lo4;
            } else {
                size_t basep = (size_t)(bb*4 + w)*32;
#pragma unroll
                for (int e = 0; e < 4; ++e) {
                    int d = 16*j + 4*qd + e;
                    short hh, ll; split2(v[e], hh, ll);
                    vhiT[(basep + d)*2048 + l] = hh;
                    vloT[(basep + d)*2048 + l] = ll;
                }
            }
        }
    }
}

// ---------------------------------------------------------------------------
// SPLIT-K MFMA flash attention: blockIdx.y encodes (h, half); each block does
// half the key tiles with online softmax, writing UNNORMALIZED O partial +
// per-row (m, l) to workspace. Merge happens in gemm_wo_merge (exact).
// ---------------------------------------------------------------------------
__global__ __launch_bounds__(256)
void attn_mfma_kernel(const float* __restrict__ q,
                      const short* __restrict__ khi, const short* __restrict__ klo,
                      const short* __restrict__ vhiT, const short* __restrict__ vloT,
                      const int* __restrict__ kcount, const float* __restrict__ cfm,
                      float* __restrict__ opart, float* __restrict__ mlm,
                      float* __restrict__ mll)
{
    __shared__ short KhiS[64*32];
    __shared__ short KloS[64*32];
    __shared__ short Vthi[32*72];
    __shared__ short Vtlo[32*72];
    __shared__ short Pshi[4][16*PSTR];
    __shared__ short Pslo[4][16*PSTR];
    __shared__ float kmf[64];
    __shared__ float al_ls[4][16];

    const int t    = threadIdx.x;
    const int w    = t >> 6;
    const int lane = t & 63;
    const int m    = lane & 15;
    const int qd   = lane >> 4;
    const int qt = blockIdx.x, b = blockIdx.z;
    const int h = blockIdx.y & 3, half = blockIdx.y >> 2;

    const int Kb = kcount[b];
    if (qt*64 >= Kb) return;
    const int nt = (Kb + 63) >> 6;
    const int ntH = (nt + 1) >> 1;
    const int kt0 = half * ntH;
    const int kt1 = (kt0 + ntH < nt) ? (kt0 + ntH) : nt;
    const size_t mlbase = (((size_t)(b*4 + h))*2 + half)*2048;

    if (kt0 >= kt1) {                     // empty half (only if nt==1)
        if (lane < 16) {
            mlm[mlbase + qt*64 + 16*w + lane] = FMINV;
            mll[mlbase + qt*64 + 16*w + lane] = 0.0f;
        }
        return;
    }

    const size_t hd = ((size_t)(b*4 + h))*2048*32;
    const int vd = t >> 3;
    const int vk = (t & 7) * 8;
    const size_t vbase = ((size_t)(b*4 + h)*32 + vd)*2048 + vk;

    const int qrow = qt*64 + 16*w + m;
    const float* qp = q + ((size_t)(b*L_ + qrow))*D_ + h*DK_ + 8*qd;
    float qf[8];
    *(float4*)&qf[0] = *(const float4*)qp;
    *(float4*)&qf[4] = *(const float4*)(qp + 4);
    bf16x8 qhi, qlo;
#pragma unroll
    for (int j = 0; j < 8; ++j) {
        float qs = qf[j] * LOG2E;
        short hs = f2bf(qs);
        qhi[j] = hs;
        qlo[j] = f2bf(qs - bf2f(hs));
    }

    bf16x8 pkh, pkl, pvh, pvl;
    float4 pmask = {0,0,0,0};
    {
        const size_t gk = hd + (size_t)kt0*64*32 + t*8;
        pkh = *(const bf16x8*)(khi + gk);
        pkl = *(const bf16x8*)(klo + gk);
        pvh = *(const bf16x8*)(vhiT + vbase + (size_t)kt0*64);
        pvl = *(const bf16x8*)(vloT + vbase + (size_t)kt0*64);
        if (t < 16) pmask = ((const float4*)(cfm + (size_t)b*L_ + (size_t)kt0*64))[t];
    }

    float m_old = -INFINITY, l_run = 0.0f;
    f32x4 o_acc[2] = {{0,0,0,0},{0,0,0,0}};

    for (int kt = kt0; kt < kt1; ++kt) {
        __syncthreads();
        *(bf16x8*)&KhiS[t*8] = pkh;
        *(bf16x8*)&KloS[t*8] = pkl;
        *(bf16x8*)&Vthi[vd*72 + vk] = pvh;
        *(bf16x8*)&Vtlo[vd*72 + vk] = pvl;
        if (t < 16) ((float4*)kmf)[t] = pmask;
        __syncthreads();
        if (kt + 1 < kt1) {
            const size_t gk = hd + (size_t)(kt+1)*64*32 + t*8;
            pkh = *(const bf16x8*)(khi + gk);
            pkl = *(const bf16x8*)(klo + gk);
            pvh = *(const bf16x8*)(vhiT + vbase + (size_t)(kt+1)*64);
            pvl = *(const bf16x8*)(vloT + vbase + (size_t)(kt+1)*64);
            if (t < 16) pmask = ((const float4*)(cfm + (size_t)b*L_ + (size_t)(kt+1)*64))[t];
        }

        f32x4 sf[4];
#pragma unroll
        for (int k4 = 0; k4 < 4; ++k4) {
            bf16x8 ka = *(const bf16x8*)&KhiS[(16*k4 + m)*32 + 8*qd];
            bf16x8 kl = *(const bf16x8*)&KloS[(16*k4 + m)*32 + 8*qd];
            f32x4 c = {0,0,0,0};
            c = __builtin_amdgcn_mfma_f32_16x16x32_bf16(ka, qhi, c, 0, 0, 0);
            c = __builtin_amdgcn_mfma_f32_16x16x32_bf16(ka, qlo, c, 0, 0, 0);
            c = __builtin_amdgcn_mfma_f32_16x16x32_bf16(kl, qhi, c, 0, 0, 0);
            sf[k4] = c;
        }

        float sv[16];
#pragma unroll
        for (int k4 = 0; k4 < 4; ++k4) {
            float4 kmv = *(const float4*)&kmf[16*k4 + 4*qd];
            sv[4*k4+0] = sf[k4][0] + kmv.x;
            sv[4*k4+1] = sf[k4][1] + kmv.y;
            sv[4*k4+2] = sf[k4][2] + kmv.z;
            sv[4*k4+3] = sf[k4][3] + kmv.w;
        }

        float tmax = sv[0];
#pragma unroll
        for (int j = 1; j < 16; ++j) tmax = fmaxf(tmax, sv[j]);
        tmax = fmaxf(tmax, __shfl_xor(tmax, 16));
        tmax = fmaxf(tmax, __shfl_xor(tmax, 32));
        float mnew  = fmaxf(m_old, tmax);
        float alpha = EXP2F(m_old - mnew);
        float psum = 0.0f;
        short pbh[16], pbl[16];
#pragma unroll
        for (int j = 0; j < 16; ++j) {
            float p = EXP2F(sv[j] - mnew);
            psum += p;
            split_trunc(p, pbh[j], pbl[j]);
        }
        psum += __shfl_xor(psum, 16);
        psum += __shfl_xor(psum, 32);
        l_run = l_run * alpha + psum;
        m_old = mnew;

#pragma unroll
        for (int k4 = 0; k4 < 4; ++k4) {
            short4 s4h, s4l;
            s4h.x = pbh[4*k4+0]; s4h.y = pbh[4*k4+1]; s4h.z = pbh[4*k4+2]; s4h.w = pbh[4*k4+3];
            s4l.x = pbl[4*k4+0]; s4l.y = pbl[4*k4+1]; s4l.z = pbl[4*k4+2]; s4l.w = pbl[4*k4+3];
            *(short4*)&Pshi[w][m*PSTR + 16*k4 + 4*qd] = s4h;
            *(short4*)&Pslo[w][m*PSTR + 16*k4 + 4*qd] = s4l;
        }
        if (lane < 16) al_ls[w][lane] = alpha;

        {
            float4 alr = *(const float4*)&al_ls[w][4*qd];
            o_acc[0][0]*=alr.x; o_acc[0][1]*=alr.y; o_acc[0][2]*=alr.z; o_acc[0][3]*=alr.w;
            o_acc[1][0]*=alr.x; o_acc[1][1]*=alr.y; o_acc[1][2]*=alr.z; o_acc[1][3]*=alr.w;
        }
#pragma unroll
        for (int s = 0; s < 2; ++s) {
            bf16x8 pah = *(const bf16x8*)&Pshi[w][m*PSTR + 32*s + 8*qd];
            bf16x8 pal = *(const bf16x8*)&Pslo[w][m*PSTR + 32*s + 8*qd];
#pragma unroll
            for (int tp = 0; tp < 2; ++tp) {
                bf16x8 vh = *(const bf16x8*)&Vthi[(16*tp + m)*72 + 32*s + 8*qd];
                bf16x8 vl = *(const bf16x8*)&Vtlo[(16*tp + m)*72 + 32*s + 8*qd];
                o_acc[tp] = __builtin_amdgcn_mfma_f32_16x16x32_bf16(pah, vh, o_acc[tp], 0, 0, 0);
                o_acc[tp] = __builtin_amdgcn_mfma_f32_16x16x32_bf16(pah, vl, o_acc[tp], 0, 0, 0);
                o_acc[tp] = __builtin_amdgcn_mfma_f32_16x16x32_bf16(pal, vh, o_acc[tp], 0, 0, 0);
            }
        }
    }

    if (lane < 16) {
        mlm[mlbase + qt*64 + 16*w + lane] = m_old;
        mll[mlbase + qt*64 + 16*w + lane] = l_run;
    }
    float* ob = opart + (size_t)half*SZ_X;
#pragma unroll
    for (int tp = 0; tp < 2; ++tp)
#pragma unroll
        for (int r = 0; r < 4; ++r)
            ob[((size_t)(b*L_ + qt*64 + 16*w + 4*qd + r))*D_ + h*DK_ + 16*tp + m] =
                o_acc[tp][r];
}

// ---------------------------------------------------------------------------
// Wo GEMM with fused split-K merge in the A-staging:
//   o = (o0*2^(m0-M) + o1*2^(m1-M)) / (l0*2^(m0-M) + l1*2^(m1-M)),  M=max.
// Then x = o @ Wo + x (N=K=128).
// ---------------------------------------------------------------------------
__global__ __launch_bounds__(256)
void gemm_wo_merge(const float* __restrict__ opart, const float* __restrict__ mlm,
                   const float* __restrict__ mll,
                   const short* __restrict__ Whi, const short* __restrict__ Wlo,
                   const int* __restrict__ kcount, float* __restrict__ x)
{
    const int row0 = blockIdx.x * 64;
    const int bb = row0 >> 11;
    if ((row0 & 2047) >= ((kcount[bb] + 63) & ~63)) return;

    __shared__ short Ahi[64*136];
    __shared__ short Alo[64*136];
    const int t = threadIdx.x;
    const int w = t >> 6, lane = t & 63;
    const int m = lane & 15, qd = lane >> 4;

#pragma unroll
    for (int i = 0; i < 8; ++i) {
        int r = (t >> 5) + 8*i;
        int c = (t & 31) * 4;
        int row = row0 + r;
        int l = row & 2047;
        int h = c >> 5;
        size_t i0 = (((size_t)(bb*4 + h))*2 + 0)*2048 + l;
        size_t i1 = i0 + 2048;
        float m0 = mlm[i0], m1 = mlm[i1];
        float l0 = mll[i0], l1 = mll[i1];
        float M  = fmaxf(m0, m1);
        float w0 = EXP2F(m0 - M), w1 = EXP2F(m1 - M);
        float inv = 1.0f / (l0*w0 + l1*w1);
        float s0 = w0 * inv, s1 = w1 * inv;
        float4 o0 = *(const float4*)(opart + (size_t)row*D_ + c);
        float4 o1 = *(const float4*)(opart + (size_t)(BL_ + row)*D_ + c);
        float4 av;
        av.x = s0*o0.x + s1*o1.x;
        av.y = s0*o0.y + s1*o1.y;
        av.z = s0*o0.z + s1*o1.z;
        av.w = s0*o0.w + s1*o1.w;
        short4 hi4, lo4;
        split2(av.x, hi4.x, lo4.x);
        split2(av.y, hi4.y, lo4.y);
        split2(av.z, hi4.z, lo4.z);
        split2(av.w, hi4.w, lo4.w);
        *(short4*)&Ahi[r*136 + c] = hi4;
        *(short4*)&Alo[r*136 + c] = lo4;
    }
    __syncthreads();

    f32x4 acc[4][2];
#pragma unroll
    for (int r4 = 0; r4 < 4; ++r4)
#pragma unroll
        for (int j = 0; j < 2; ++j) acc[r4][j] = (f32x4){0,0,0,0};

#pragma unroll
    for (int ks = 0; ks < 4; ++ks) {
        bf16x8 wh[2], wl[2];
#pragma unroll
        for (int j = 0; j < 2; ++j) {
            size_t wi = (size_t)(32*w + 16*j + m)*D_ + 32*ks + 8*qd;
            wh[j] = *(const bf16x8*)(Whi + wi);
            wl[j] = *(const bf16x8*)(Wlo + wi);
        }
#pragma unroll
        for (int r4 = 0; r4 < 4; ++r4) {
            bf16x8 ah = *(const bf16x8*)&Ahi[(16*r4 + m)*136 + 32*ks + 8*qd];
            bf16x8 al = *(const bf16x8*)&Alo[(16*r4 + m)*136 + 32*ks + 8*qd];
#pragma unroll
            for (int j = 0; j < 2; ++j) {
                acc[r4][j] = __builtin_amdgcn_mfma_f32_16x16x32_bf16(wh[j], ah, acc[r4][j], 0, 0, 0);
                acc[r4][j] = __builtin_amdgcn_mfma_f32_16x16x32_bf16(wh[j], al, acc[r4][j], 0, 0, 0);
                acc[r4][j] = __builtin_amdgcn_mfma_f32_16x16x32_bf16(wl[j], ah, acc[r4][j], 0, 0, 0);
            }
        }
    }

#pragma unroll
    for (int r4 = 0; r4 < 4; ++r4) {
        int row = row0 + 16*r4 + m;
#pragma unroll
        for (int j = 0; j < 2; ++j) {
            int col = 32*w + 16*j + 4*qd;
            f32x4 v = acc[r4][j];
            float4 rv = *(const float4*)(x + (size_t)row*D_ + col);
            float4 sv = {v[0]+rv.x, v[1]+rv.y, v[2]+rv.z, v[3]+rv.w};
            *(float4*)(x + (size_t)row*D_ + col) = sv;
        }
    }
}

// ---------------------------------------------------------------------------
// Pooling
// ---------------------------------------------------------------------------
__global__ __launch_bounds__(256)
void pool_stats_kernel(const float* __restrict__ att, const int* __restrict__ kcount,
                       float* __restrict__ p)
{
    int b = blockIdx.x, t = threadIdx.x;
    int lim = (kcount[b] + 63) & ~63;
    __shared__ float red[4];
    __shared__ float a_s[L_];

    float m = -INFINITY;
    for (int l = t; l < L_; l += 256) {
        float a = (l < lim) ? att[b*L_ + l] : FMINV;
        a_s[l] = a;
        m = fmaxf(m, a);
    }
#pragma unroll
    for (int s = 1; s < 64; s <<= 1) m = fmaxf(m, __shfl_xor(m, s));
    if ((t & 63) == 0) red[t >> 6] = m;
    __syncthreads();
    m = fmaxf(fmaxf(red[0], red[1]), fmaxf(red[2], red[3]));
    __syncthreads();

    float s = 0.0f;
    for (int l = t; l < L_; l += 256) s += __expf(a_s[l] - m);
#pragma unroll
    for (int st = 1; st < 64; st <<= 1) s += __shfl_xor(s, st);
    if ((t & 63) == 0) red[t >> 6] = s;
    __syncthreads();
    s = red[0] + red[1] + red[2] + red[3];
    float inv = 1.0f / s;
    for (int l = t; l < L_; l += 256)
        p[b*L_ + l] = (l < lim) ? __expf(a_s[l] - m) * inv : 0.0f;
}

__global__ __launch_bounds__(128)
void pool_partial_kernel(const float* __restrict__ p, const float* __restrict__ x,
                         float* __restrict__ part)
{
    int c = blockIdx.x, b = blockIdx.y, d = threadIdx.x;
    const float* xb = x + ((size_t)(b*L_ + c*128))*D_ + d;
    const float* pb = p + b*L_ + c*128;
    float acc = 0.0f;
#pragma unroll 4
    for (int i = 0; i < 128; ++i) acc += pb[i] * xb[(size_t)i*D_];
    part[((size_t)b*16 + c)*D_ + d] = acc;
}

// ---------------------------------------------------------------------------
// Demographics MLP
// ---------------------------------------------------------------------------
__global__ __launch_bounds__(256)
void demo_kernel(const float* __restrict__ demog, const float* __restrict__ Wd1,
                 const float* __restrict__ bd1, const float* __restrict__ Wd2,
                 const float* __restrict__ bd2, float* __restrict__ demo_out)
{
    int t = threadIdx.x;
    __shared__ float dsm[B_][DM_];
    __shared__ float hs[B_][2*D_];
    if (t < B_*DM_) dsm[t >> 4][t & 15] = demog[t];
    __syncthreads();
    {
        int col = t;
#pragma unroll
        for (int r = 0; r < B_; ++r) {
            float acc = bd1[col];
#pragma unroll
            for (int kk = 0; kk < DM_; ++kk) acc += dsm[r][kk]*Wd1[kk*(2*D_)+col];
            hs[r][col] = tanhf(acc);
        }
    }
    __syncthreads();
    {
        int c  = t & (D_-1);
        int r0 = t >> 7;
        for (int r = r0; r < B_; r += 2) {
            float acc = bd2[c];
            for (int kk = 0; kk < 2*D_; ++kk) acc += hs[r][kk]*Wd2[kk*D_+c];
            demo_out[r*D_+c] = acc;
        }
    }
}

// ---------------------------------------------------------------------------
// Head
// ---------------------------------------------------------------------------
__global__ __launch_bounds__(256)
void head_kernel(const float* __restrict__ part, const float* __restrict__ demo,
                 const float* __restrict__ Wh, const float* __restrict__ bh,
                 float* __restrict__ out)
{
    int b = blockIdx.x, t = threadIdx.x;
    __shared__ float tss[128];
    if (t < 128) {
        float s = 0.0f;
#pragma unroll
        for (int c = 0; c < 16; ++c) s += part[((size_t)b*16 + c)*D_ + t];
        tss[t] = s;
    }
    __syncthreads();
    if (t >= F_OUT) return;
    float acc = bh[t];
    for (int k2 = 0; k2 < D_; ++k2) acc += tss[k2]         * Wh[k2*F_OUT + t];
    for (int k2 = 0; k2 < D_; ++k2) acc += demo[b*D_ + k2] * Wh[(D_+k2)*F_OUT + t];
    out[b*F_OUT + t] = acc;
}

// ---------------------------------------------------------------------------
extern "C" void kernel_launch(void* const* d_in, const int* in_sizes, int n_in,
                              void* d_out, int out_size, void* d_ws, size_t ws_size,
                              hipStream_t stream)
{
    (void)in_sizes; (void)n_in; (void)out_size; (void)ws_size;
    const float* values       = (const float*)d_in[0];
    const float* times        = (const float*)d_in[1];
    const int*   variables    = (const int*)  d_in[2];
    const int*   input_mask   = (const int*)  d_in[3];
    const float* demographics = (const float*)d_in[4];
    const float* W1t = (const float*)d_in[5];
    const float* b1t = (const float*)d_in[6];
    const float* W2t = (const float*)d_in[7];
    const float* W1v = (const float*)d_in[8];
    const float* b1v = (const float*)d_in[9];
    const float* W2v = (const float*)d_in[10];
    const float* var_table = (const float*)d_in[11];
    const float* Wq  = (const float*)d_in[12];
    const float* Wk  = (const float*)d_in[13];
    const float* Wv  = (const float*)d_in[14];
    const float* Wo  = (const float*)d_in[15];
    const float* W1  = (const float*)d_in[16];
    const float* b1  = (const float*)d_in[17];
    const float* W2  = (const float*)d_in[18];
    const float* b2  = (const float*)d_in[19];
    const float* Wf  = (const float*)d_in[20];
    const float* bfv = (const float*)d_in[21];
    const float* uf  = (const float*)d_in[22];
    const float* Wd1 = (const float*)d_in[23];
    const float* bd1 = (const float*)d_in[24];
    const float* Wd2 = (const float*)d_in[25];
    const float* bd2 = (const float*)d_in[26];
    const float* Wh  = (const float*)d_in[27];
    const float* bhv = (const float*)d_in[28];
    float* out = (float*)d_out;

    float* ws     = (float*)d_ws;
    float* x      = ws;                   // compact rows
    float* qb     = ws + (size_t)SZ_X;
    float* region = ws + (size_t)2*SZ_X;
    short* khi    = (short*)region;
    short* klo    = khi + (size_t)SZ_X;
    short* vhiT   = klo + (size_t)SZ_X;
    short* vloT   = vhiT + (size_t)SZ_X;
    float* hb     = region;               // alias (FFN hidden)
    float* attb   = ws + (size_t)4*SZ_X;  // BL_
    float* attp   = attb + BL_;           // BL_
    float* partb  = attp + BL_;           // B_*16*D_
    float* demob  = partb + B_*16*D_;     // B_*D_
    short* wt_hi  = (short*)(demob + B_*D_);
    short* wt_lo  = wt_hi + (size_t)NL_*WT_TOT;
    short* wfhi   = wt_lo + (size_t)NL_*WT_TOT;
    short* wflo   = wfhi + 16384;
    int*   posb   = (int*)(wflo + 16384);       // BL_
    int*   kcountb= posb + BL_;                 // B_
    float* cfmb   = (float*)(kcountb + B_);     // BL_
    float* opart  = cfmb + BL_;                 // 2*SZ_X (split-K O partials)
    float* mlm    = opart + (size_t)2*SZ_X;     // B_*H_*2*2048
    float* mll    = mlm + (size_t)B_*H_*2*2048; // B_*H_*2*2048

    compact_kernel<<<B_, 256, 0, stream>>>(input_mask, posb, kcountb, cfmb);
    embed_kernel<<<BL_, 128, 0, stream>>>(values, times, variables, posb,
                                          W1t, b1t, W2t, W1v, b1v, W2v,
                                          var_table, x);
    xtail_zero_kernel<<<B_, 256, 0, stream>>>(kcountb, x);
    demo_kernel<<<1, 256, 0, stream>>>(demographics, Wd1, bd1, Wd2, bd2, demob);
    split_nk_kernel<<<64, 256, 0, stream>>>(Wf, wfhi, wflo, D_, D_);
    split_all_kernel<<<NL_*512, 256, 0, stream>>>(Wq, Wk, Wv, Wo, W1, W2, wt_hi, wt_lo);

    for (int i = 0; i < NL_; ++i) {
        short* whL = wt_hi + (size_t)i*WT_TOT;
        short* wlL = wt_lo + (size_t)i*WT_TOT;
        gemm_qkv_fused<<<dim3(BL_/64, 3), 256, 0, stream>>>(x, whL, wlL, kcountb,
            qb, khi, klo, vhiT, vloT);
        attn_mfma_kernel<<<dim3(L_/64, H_*2, B_), 256, 0, stream>>>(qb, khi, klo,
            vhiT, vloT, kcountb, cfmb, opart, mlm, mll);
        gemm_wo_merge<<<dim3(BL_/64, 1), 256, 0, stream>>>(opart, mlm, mll,
            whL+WT_O, wlL+WT_O, kcountb, x);
        gemm_mfma<2><<<dim3(BL_/64, 2), 256, 0, stream>>>(x, whL+WT_1, wlL+WT_1,
            b1 + i*DFF_, nullptr, hb, nullptr, kcountb, DFF_, D_);
        gemm_mfma<3><<<dim3(BL_/64, 1), 256, 0, stream>>>(hb, whL+WT_2, wlL+WT_2,
            b2 + i*D_, x, x, nullptr, kcountb, D_, DFF_);
    }

    // fused fusion-attention on compact rows: att = tanh(x@Wf+bf).uf + cfm
    gemm_mfma<7><<<dim3(BL_/64, 1), 256, 0, stream>>>(x, wfhi, wflo,
        bfv, uf, attb, cfmb, kcountb, D_, D_);
    pool_stats_kernel<<<B_, 256, 0, stream>>>(attb, kcountb, attp);
    pool_partial_kernel<<<dim3(16, B_), 128, 0, stream>>>(attp, x, partb);
    head_kernel<<<B_, 256, 0, stream>>>(partb, demob, Wh, bhv, out);
}

// Round 16
// 789.600 us; speedup vs baseline: 2.6515x; 1.0590x over previous
//
#include <hip/hip_runtime.h>
#include <hip/hip_bf16.h>
#include <math.h>

#define B_   16
#define L_   2048
#define D_   128
#define H_   4
#define NL_  4
#define DK_  32
#define DFF_ 256
#define INTD_ 11
#define F_OUT 129
#define DM_  16
#define FMINV (-3.402823466e38f)
#define LOG2E 1.4426950408889634f

#define BL_  (B_*L_)      // 32768
#define SZ_X (BL_*D_)     // 4194304 floats

#define PSTR 72

#define WT_Q 0
#define WT_K 16384
#define WT_V 32768
#define WT_O 49152
#define WT_1 65536
#define WT_2 98304
#define WT_TOT 131072

typedef __attribute__((ext_vector_type(8))) short bf16x8;
typedef __attribute__((ext_vector_type(4))) float f32x4;

#if __has_builtin(__builtin_amdgcn_exp2f)
#define EXP2F(x) __builtin_amdgcn_exp2f(x)
#else
#define EXP2F(x) __expf(0.69314718055994531f*(x))
#endif

static __device__ __forceinline__ short f2bf(float x) {
    union { __hip_bfloat16 h; short s; } u;
    u.h = __float2bfloat16(x);
    return u.s;
}
static __device__ __forceinline__ float bf2f(short s) {
    union { __hip_bfloat16 h; short t; } u;
    u.t = s;
    return __bfloat162float(u.h);
}
static __device__ __forceinline__ void split2(float v, short& h, short& l) {
    h = f2bf(v); l = f2bf(v - bf2f(h));
}
static __device__ __forceinline__ void split_trunc(float v, short& h, short& l) {
    unsigned u = __float_as_uint(v);
    h = (short)(u >> 16);
    float r = v - __uint_as_float(u & 0xffff0000u);
    l = (short)(__float_as_uint(r) >> 16);
}

// ---------------------------------------------------------------------------
// Mask compaction + x tail-zero: pos, kcount, cfm; zeroes x rows [Kb,ceil64).
// ---------------------------------------------------------------------------
__global__ __launch_bounds__(256)
void compact_kernel(const int* __restrict__ mask, int* __restrict__ pos,
                    int* __restrict__ kcount, float* __restrict__ cfm,
                    float* __restrict__ x)
{
    int b = blockIdx.x, t = threadIdx.x;
    int lane = t & 63, w = t >> 6;
    __shared__ int wsum[4];
    __shared__ int tot_s;
    int mv[8], loc[8], s = 0;
#pragma unroll
    for (int i = 0; i < 8; ++i) {
        mv[i] = mask[b*L_ + t*8 + i];
        loc[i] = s;
        s += mv[i];
    }
    int v = s;
#pragma unroll
    for (int d = 1; d < 64; d <<= 1) {
        int y = __shfl_up(v, d);
        if (lane >= d) v += y;
    }
    int excl = v - s;
    if (lane == 63) wsum[w] = v;
    __syncthreads();
    int wbase = 0;
    for (int i = 0; i < w; ++i) wbase += wsum[i];
    int base = wbase + excl;
#pragma unroll
    for (int i = 0; i < 8; ++i)
        pos[b*L_ + t*8 + i] = mv[i] ? (base + loc[i]) : -1;
    if (t == 255) { kcount[b] = base + s; tot_s = base + s; }
    __syncthreads();
    int tot = tot_s;
    for (int l = t; l < L_; l += 256) cfm[b*L_ + l] = (l < tot) ? 0.0f : FMINV;
    int end = (tot + 63) & ~63;
    int nz = (end - tot) * D_;
    for (int i = t; i < nz; i += 256)
        x[((size_t)(b*2048 + tot))*D_ + i] = 0.0f;
}

// ---------------------------------------------------------------------------
// Embedding with compaction
// ---------------------------------------------------------------------------
__global__ __launch_bounds__(128)
void embed_kernel(const float* __restrict__ values, const float* __restrict__ times,
                  const int* __restrict__ variables, const int* __restrict__ pos,
                  const float* __restrict__ W1t, const float* __restrict__ b1t,
                  const float* __restrict__ W2t,
                  const float* __restrict__ W1v, const float* __restrict__ b1v,
                  const float* __restrict__ W2v,
                  const float* __restrict__ var_table, float* __restrict__ x)
{
    int bl = blockIdx.x;
    int p  = pos[bl];
    if (p < 0) return;
    int t  = threadIdx.x;
    __shared__ float th[INTD_], vh[INTD_];
    if (t < INTD_)                th[t]    = tanhf(times[bl]  * W1t[t]    + b1t[t]);
    if (t >= 64 && t < 64+INTD_)  vh[t-64] = tanhf(values[bl] * W1v[t-64] + b1v[t-64]);
    __syncthreads();
    int var = variables[bl];
    float acc = var_table[var*D_ + t];
#pragma unroll
    for (int i = 0; i < INTD_; ++i)
        acc += th[i]*W2t[i*D_ + t] + vh[i]*W2v[i*D_ + t];
    x[((size_t)((bl >> 11)*2048 + p))*D_ + t] = acc;
}

// ---------------------------------------------------------------------------
// Weight pre-split: all 4 layers + Wf appended at offset NL_*WT_TOT.
// ---------------------------------------------------------------------------
__global__ __launch_bounds__(256)
void split_all_kernel(const float* __restrict__ Wq, const float* __restrict__ Wk,
                      const float* __restrict__ Wv, const float* __restrict__ Wo,
                      const float* __restrict__ W1, const float* __restrict__ W2,
                      const float* __restrict__ Wf,
                      short* __restrict__ hi, short* __restrict__ lo)
{
    int gidx = blockIdx.x*256 + threadIdx.x;
    float v;
    if (gidx < NL_*131072) {
        int layer = gidx >> 17;
        int idx   = gidx & 131071;
        if (idx < 49152) {
            int which = idx >> 14;
            int r = idx & 16383;
            int col = r >> 7, k = r & 127;
            int h = col >> 5, e = col & 31;
            const float* src = ((which == 0) ? Wq : (which == 1) ? Wk : Wv)
                               + (size_t)layer*H_*D_*DK_;
            v = src[(h*D_ + k)*DK_ + e];
        } else if (idx < 65536) {
            int r = idx - 49152;
            int col = r >> 7, k = r & 127;
            v = Wo[(size_t)layer*D_*D_ + k*D_ + col];
        } else if (idx < 98304) {
            int r = idx - 65536;
            int col = r >> 7, k = r & 127;
            v = W1[(size_t)layer*D_*DFF_ + k*DFF_ + col];
        } else {
            int r = idx - 98304;
            int col = r >> 8, k = r & 255;
            v = W2[(size_t)layer*DFF_*D_ + k*D_ + col];
        }
    } else {
        int r = gidx - NL_*131072;      // Wf: 16384 elems, [col][K]
        int col = r >> 7, k = r & 127;
        v = Wf[k*D_ + col];
    }
    short h2, l2; split2(v, h2, l2);
    hi[gidx] = h2; lo[gidx] = l2;
}

// ---------------------------------------------------------------------------
// Fused QKV GEMM (layer 0 only), one weight stream per block (grid.y=3).
// ---------------------------------------------------------------------------
__global__ __launch_bounds__(256)
void gemm_qkv_fused(const float* __restrict__ A, const short* __restrict__ Whi,
                    const short* __restrict__ Wlo, const int* __restrict__ kcount,
                    float* __restrict__ qout,
                    short* __restrict__ khi, short* __restrict__ klo,
                    short* __restrict__ vhiT, short* __restrict__ vloT)
{
    const int row0 = blockIdx.x * 64;
    const int bb = row0 >> 11;
    if ((row0 & 2047) >= ((kcount[bb] + 63) & ~63)) return;
    const int sec = blockIdx.y;

    __shared__ short Ahi[64*136];
    __shared__ short Alo[64*136];
    const int t = threadIdx.x;
    const int w = t >> 6, lane = t & 63;
    const int m = lane & 15, qd = lane >> 4;

#pragma unroll
    for (int i = 0; i < 8; ++i) {
        int r = (t >> 5) + 8*i;
        int c = (t & 31) * 4;
        float4 av = *(const float4*)(A + (size_t)(row0 + r)*D_ + c);
        short4 hi4, lo4;
        split2(av.x, hi4.x, lo4.x);
        split2(av.y, hi4.y, lo4.y);
        split2(av.z, hi4.z, lo4.z);
        split2(av.w, hi4.w, lo4.w);
        *(short4*)&Ahi[r*136 + c] = hi4;
        *(short4*)&Alo[r*136 + c] = lo4;
    }
    __syncthreads();

    const short* Wh = Whi + sec*16384;
    const short* Wl = Wlo + sec*16384;
    f32x4 acc[4][2];
#pragma unroll
    for (int r4 = 0; r4 < 4; ++r4)
#pragma unroll
        for (int j = 0; j < 2; ++j) acc[r4][j] = (f32x4){0,0,0,0};

#pragma unroll
    for (int ks = 0; ks < 4; ++ks) {
        bf16x8 wh[2], wl[2];
#pragma unroll
        for (int j = 0; j < 2; ++j) {
            size_t wi = (size_t)(32*w + 16*j + m)*D_ + 32*ks + 8*qd;
            wh[j] = *(const bf16x8*)(Wh + wi);
            wl[j] = *(const bf16x8*)(Wl + wi);
        }
#pragma unroll
        for (int r4 = 0; r4 < 4; ++r4) {
            bf16x8 ah = *(const bf16x8*)&Ahi[(16*r4 + m)*136 + 32*ks + 8*qd];
            bf16x8 al = *(const bf16x8*)&Alo[(16*r4 + m)*136 + 32*ks + 8*qd];
#pragma unroll
            for (int j = 0; j < 2; ++j) {
                acc[r4][j] = __builtin_amdgcn_mfma_f32_16x16x32_bf16(wh[j], ah, acc[r4][j], 0, 0, 0);
                acc[r4][j] = __builtin_amdgcn_mfma_f32_16x16x32_bf16(wh[j], al, acc[r4][j], 0, 0, 0);
                acc[r4][j] = __builtin_amdgcn_mfma_f32_16x16x32_bf16(wl[j], ah, acc[r4][j], 0, 0, 0);
            }
        }
    }

#pragma unroll
    for (int r4 = 0; r4 < 4; ++r4) {
        int row = row0 + 16*r4 + m;
        int l = row & 2047;
#pragma unroll
        for (int j = 0; j < 2; ++j) {
            int col = 32*w + 16*j + 4*qd;
            f32x4 v = acc[r4][j];
            if (sec == 0) {
                float4 sv = {v[0], v[1], v[2], v[3]};
                *(float4*)(qout + (size_t)row*D_ + col) = sv;
            } else if (sec == 1) {
                size_t idx = ((size_t)((bb*4 + w)*2048 + l))*32 + (col & 31);
                short4 hi4, lo4;
                split2(v[0], hi4.x, lo4.x);
                split2(v[1], hi4.y, lo4.y);
                split2(v[2], hi4.z, lo4.z);
                split2(v[3], hi4.w, lo4.w);
                *(short4*)(khi + idx) = hi4;
                *(short4*)(klo + idx) = lo4;
            } else {
                size_t basep = (size_t)(bb*4 + w)*32;
#pragma unroll
                for (int e = 0; e < 4; ++e) {
                    int d = 16*j + 4*qd + e;
                    short hh, ll; split2(v[e], hh, ll);
                    vhiT[(basep + d)*2048 + l] = hh;
                    vloT[(basep + d)*2048 + l] = ll;
                }
            }
        }
    }
}

// ---------------------------------------------------------------------------
// SPLIT-K MFMA flash attention (unchanged from R15).
// ---------------------------------------------------------------------------
__global__ __launch_bounds__(256)
void attn_mfma_kernel(const float* __restrict__ q,
                      const short* __restrict__ khi, const short* __restrict__ klo,
                      const short* __restrict__ vhiT, const short* __restrict__ vloT,
                      const int* __restrict__ kcount, const float* __restrict__ cfm,
                      float* __restrict__ opart, float* __restrict__ mlm,
                      float* __restrict__ mll)
{
    __shared__ short KhiS[64*32];
    __shared__ short KloS[64*32];
    __shared__ short Vthi[32*72];
    __shared__ short Vtlo[32*72];
    __shared__ short Pshi[4][16*PSTR];
    __shared__ short Pslo[4][16*PSTR];
    __shared__ float kmf[64];
    __shared__ float al_ls[4][16];

    const int t    = threadIdx.x;
    const int w    = t >> 6;
    const int lane = t & 63;
    const int m    = lane & 15;
    const int qd   = lane >> 4;
    const int qt = blockIdx.x, b = blockIdx.z;
    const int h = blockIdx.y & 3, half = blockIdx.y >> 2;

    const int Kb = kcount[b];
    if (qt*64 >= Kb) return;
    const int nt = (Kb + 63) >> 6;
    const int ntH = (nt + 1) >> 1;
    const int kt0 = half * ntH;
    const int kt1 = (kt0 + ntH < nt) ? (kt0 + ntH) : nt;
    const size_t mlbase = (((size_t)(b*4 + h))*2 + half)*2048;

    if (kt0 >= kt1) {
        if (lane < 16) {
            mlm[mlbase + qt*64 + 16*w + lane] = FMINV;
            mll[mlbase + qt*64 + 16*w + lane] = 0.0f;
        }
        return;
    }

    const size_t hd = ((size_t)(b*4 + h))*2048*32;
    const int vd = t >> 3;
    const int vk = (t & 7) * 8;
    const size_t vbase = ((size_t)(b*4 + h)*32 + vd)*2048 + vk;

    const int qrow = qt*64 + 16*w + m;
    const float* qp = q + ((size_t)(b*L_ + qrow))*D_ + h*DK_ + 8*qd;
    float qf[8];
    *(float4*)&qf[0] = *(const float4*)qp;
    *(float4*)&qf[4] = *(const float4*)(qp + 4);
    bf16x8 qhi, qlo;
#pragma unroll
    for (int j = 0; j < 8; ++j) {
        float qs = qf[j] * LOG2E;
        short hs = f2bf(qs);
        qhi[j] = hs;
        qlo[j] = f2bf(qs - bf2f(hs));
    }

    bf16x8 pkh, pkl, pvh, pvl;
    float4 pmask = {0,0,0,0};
    {
        const size_t gk = hd + (size_t)kt0*64*32 + t*8;
        pkh = *(const bf16x8*)(khi + gk);
        pkl = *(const bf16x8*)(klo + gk);
        pvh = *(const bf16x8*)(vhiT + vbase + (size_t)kt0*64);
        pvl = *(const bf16x8*)(vloT + vbase + (size_t)kt0*64);
        if (t < 16) pmask = ((const float4*)(cfm + (size_t)b*L_ + (size_t)kt0*64))[t];
    }

    float m_old = -INFINITY, l_run = 0.0f;
    f32x4 o_acc[2] = {{0,0,0,0},{0,0,0,0}};

    for (int kt = kt0; kt < kt1; ++kt) {
        __syncthreads();
        *(bf16x8*)&KhiS[t*8] = pkh;
        *(bf16x8*)&KloS[t*8] = pkl;
        *(bf16x8*)&Vthi[vd*72 + vk] = pvh;
        *(bf16x8*)&Vtlo[vd*72 + vk] = pvl;
        if (t < 16) ((float4*)kmf)[t] = pmask;
        __syncthreads();
        if (kt + 1 < kt1) {
            const size_t gk = hd + (size_t)(kt+1)*64*32 + t*8;
            pkh = *(const bf16x8*)(khi + gk);
            pkl = *(const bf16x8*)(klo + gk);
            pvh = *(const bf16x8*)(vhiT + vbase + (size_t)(kt+1)*64);
            pvl = *(const bf16x8*)(vloT + vbase + (size_t)(kt+1)*64);
            if (t < 16) pmask = ((const float4*)(cfm + (size_t)b*L_ + (size_t)(kt+1)*64))[t];
        }

        f32x4 sf[4];
#pragma unroll
        for (int k4 = 0; k4 < 4; ++k4) {
            bf16x8 ka = *(const bf16x8*)&KhiS[(16*k4 + m)*32 + 8*qd];
            bf16x8 kl = *(const bf16x8*)&KloS[(16*k4 + m)*32 + 8*qd];
            f32x4 c = {0,0,0,0};
            c = __builtin_amdgcn_mfma_f32_16x16x32_bf16(ka, qhi, c, 0, 0, 0);
            c = __builtin_amdgcn_mfma_f32_16x16x32_bf16(ka, qlo, c, 0, 0, 0);
            c = __builtin_amdgcn_mfma_f32_16x16x32_bf16(kl, qhi, c, 0, 0, 0);
            sf[k4] = c;
        }

        float sv[16];
#pragma unroll
        for (int k4 = 0; k4 < 4; ++k4) {
            float4 kmv = *(const float4*)&kmf[16*k4 + 4*qd];
            sv[4*k4+0] = sf[k4][0] + kmv.x;
            sv[4*k4+1] = sf[k4][1] + kmv.y;
            sv[4*k4+2] = sf[k4][2] + kmv.z;
            sv[4*k4+3] = sf[k4][3] + kmv.w;
        }

        float tmax = sv[0];
#pragma unroll
        for (int j = 1; j < 16; ++j) tmax = fmaxf(tmax, sv[j]);
        tmax = fmaxf(tmax, __shfl_xor(tmax, 16));
        tmax = fmaxf(tmax, __shfl_xor(tmax, 32));
        float mnew  = fmaxf(m_old, tmax);
        float alpha = EXP2F(m_old - mnew);
        float psum = 0.0f;
        short pbh[16], pbl[16];
#pragma unroll
        for (int j = 0; j < 16; ++j) {
            float p = EXP2F(sv[j] - mnew);
            psum += p;
            split_trunc(p, pbh[j], pbl[j]);
        }
        psum += __shfl_xor(psum, 16);
        psum += __shfl_xor(psum, 32);
        l_run = l_run * alpha + psum;
        m_old = mnew;

#pragma unroll
        for (int k4 = 0; k4 < 4; ++k4) {
            short4 s4h, s4l;
            s4h.x = pbh[4*k4+0]; s4h.y = pbh[4*k4+1]; s4h.z = pbh[4*k4+2]; s4h.w = pbh[4*k4+3];
            s4l.x = pbl[4*k4+0]; s4l.y = pbl[4*k4+1]; s4l.z = pbl[4*k4+2]; s4l.w = pbl[4*k4+3];
            *(short4*)&Pshi[w][m*PSTR + 16*k4 + 4*qd] = s4h;
            *(short4*)&Pslo[w][m*PSTR + 16*k4 + 4*qd] = s4l;
        }
        if (lane < 16) al_ls[w][lane] = alpha;

        {
            float4 alr = *(const float4*)&al_ls[w][4*qd];
            o_acc[0][0]*=alr.x; o_acc[0][1]*=alr.y; o_acc[0][2]*=alr.z; o_acc[0][3]*=alr.w;
            o_acc[1][0]*=alr.x; o_acc[1][1]*=alr.y; o_acc[1][2]*=alr.z; o_acc[1][3]*=alr.w;
        }
#pragma unroll
        for (int s = 0; s < 2; ++s) {
            bf16x8 pah = *(const bf16x8*)&Pshi[w][m*PSTR + 32*s + 8*qd];
            bf16x8 pal = *(const bf16x8*)&Pslo[w][m*PSTR + 32*s + 8*qd];
#pragma unroll
            for (int tp = 0; tp < 2; ++tp) {
                bf16x8 vh = *(const bf16x8*)&Vthi[(16*tp + m)*72 + 32*s + 8*qd];
                bf16x8 vl = *(const bf16x8*)&Vtlo[(16*tp + m)*72 + 32*s + 8*qd];
                o_acc[tp] = __builtin_amdgcn_mfma_f32_16x16x32_bf16(pah, vh, o_acc[tp], 0, 0, 0);
                o_acc[tp] = __builtin_amdgcn_mfma_f32_16x16x32_bf16(pah, vl, o_acc[tp], 0, 0, 0);
                o_acc[tp] = __builtin_amdgcn_mfma_f32_16x16x32_bf16(pal, vh, o_acc[tp], 0, 0, 0);
            }
        }
    }

    if (lane < 16) {
        mlm[mlbase + qt*64 + 16*w + lane] = m_old;
        mll[mlbase + qt*64 + 16*w + lane] = l_run;
    }
    float* ob = opart + (size_t)half*SZ_X;
#pragma unroll
    for (int tp = 0; tp < 2; ++tp)
#pragma unroll
        for (int r = 0; r < 4; ++r)
            ob[((size_t)(b*L_ + qt*64 + 16*w + 4*qd + r))*D_ + h*DK_ + 16*tp + m] =
                o_acc[tp][r];
}

// ---------------------------------------------------------------------------
// FUSED: split-K merge + Wo GEMM + resid (writes x) + restage + FFN1 + GELU
// ---------------------------------------------------------------------------
__global__ __launch_bounds__(256)
void wo_ffn1_kernel(const float* __restrict__ opart, const float* __restrict__ mlm,
                    const float* __restrict__ mll,
                    const short* __restrict__ WhiO, const short* __restrict__ WloO,
                    const short* __restrict__ Whi1, const short* __restrict__ Wlo1,
                    const float* __restrict__ b1,
                    const int* __restrict__ kcount, float* __restrict__ x,
                    float* __restrict__ hb)
{
    const int row0 = blockIdx.x * 64;
    const int bb = row0 >> 11;
    if ((row0 & 2047) >= ((kcount[bb] + 63) & ~63)) return;

    __shared__ short Ahi[64*136];
    __shared__ short Alo[64*136];
    const int t = threadIdx.x;
    const int w = t >> 6, lane = t & 63;
    const int m = lane & 15, qd = lane >> 4;

    // ---- stage merged O hi/lo ----
#pragma unroll
    for (int i = 0; i < 8; ++i) {
        int r = (t >> 5) + 8*i;
        int c = (t & 31) * 4;
        int row = row0 + r;
        int l = row & 2047;
        int h = c >> 5;
        size_t i0 = (((size_t)(bb*4 + h))*2 + 0)*2048 + l;
        size_t i1 = i0 + 2048;
        float m0 = mlm[i0], m1 = mlm[i1];
        float l0 = mll[i0], l1 = mll[i1];
        float M  = fmaxf(m0, m1);
        float w0 = EXP2F(m0 - M), w1 = EXP2F(m1 - M);
        float inv = 1.0f / (l0*w0 + l1*w1);
        float s0 = w0 * inv, s1 = w1 * inv;
        float4 o0 = *(const float4*)(opart + (size_t)row*D_ + c);
        float4 o1 = *(const float4*)(opart + (size_t)(BL_ + row)*D_ + c);
        float4 av;
        av.x = s0*o0.x + s1*o1.x;
        av.y = s0*o0.y + s1*o1.y;
        av.z = s0*o0.z + s1*o1.z;
        av.w = s0*o0.w + s1*o1.w;
        short4 hi4, lo4;
        split2(av.x, hi4.x, lo4.x);
        split2(av.y, hi4.y, lo4.y);
        split2(av.z, hi4.z, lo4.z);
        split2(av.w, hi4.w, lo4.w);
        *(short4*)&Ahi[r*136 + c] = hi4;
        *(short4*)&Alo[r*136 + c] = lo4;
    }
    __syncthreads();

    // ---- Wo matmul ----
    f32x4 acc[4][2];
#pragma unroll
    for (int r4 = 0; r4 < 4; ++r4)
#pragma unroll
        for (int j = 0; j < 2; ++j) acc[r4][j] = (f32x4){0,0,0,0};
#pragma unroll
    for (int ks = 0; ks < 4; ++ks) {
        bf16x8 wh[2], wl[2];
#pragma unroll
        for (int j = 0; j < 2; ++j) {
            size_t wi = (size_t)(32*w + 16*j + m)*D_ + 32*ks + 8*qd;
            wh[j] = *(const bf16x8*)(WhiO + wi);
            wl[j] = *(const bf16x8*)(WloO + wi);
        }
#pragma unroll
        for (int r4 = 0; r4 < 4; ++r4) {
            bf16x8 ah = *(const bf16x8*)&Ahi[(16*r4 + m)*136 + 32*ks + 8*qd];
            bf16x8 al = *(const bf16x8*)&Alo[(16*r4 + m)*136 + 32*ks + 8*qd];
#pragma unroll
            for (int j = 0; j < 2; ++j) {
                acc[r4][j] = __builtin_amdgcn_mfma_f32_16x16x32_bf16(wh[j], ah, acc[r4][j], 0, 0, 0);
                acc[r4][j] = __builtin_amdgcn_mfma_f32_16x16x32_bf16(wh[j], al, acc[r4][j], 0, 0, 0);
                acc[r4][j] = __builtin_amdgcn_mfma_f32_16x16x32_bf16(wl[j], ah, acc[r4][j], 0, 0, 0);
            }
        }
    }

    // ---- epilogue: xnew = acc + x; write x; keep in regs ----
#pragma unroll
    for (int r4 = 0; r4 < 4; ++r4) {
        int row = row0 + 16*r4 + m;
#pragma unroll
        for (int j = 0; j < 2; ++j) {
            int col = 32*w + 16*j + 4*qd;
            float4 rv = *(const float4*)(x + (size_t)row*D_ + col);
            acc[r4][j][0] += rv.x; acc[r4][j][1] += rv.y;
            acc[r4][j][2] += rv.z; acc[r4][j][3] += rv.w;
            float4 sv = {acc[r4][j][0], acc[r4][j][1], acc[r4][j][2], acc[r4][j][3]};
            *(float4*)(x + (size_t)row*D_ + col) = sv;
        }
    }
    __syncthreads();          // all waves done reading old staging

    // ---- restage xnew hi/lo ----
#pragma unroll
    for (int r4 = 0; r4 < 4; ++r4) {
#pragma unroll
        for (int j = 0; j < 2; ++j) {
            int col = 32*w + 16*j + 4*qd;
            short4 hi4, lo4;
            split2(acc[r4][j][0], hi4.x, lo4.x);
            split2(acc[r4][j][1], hi4.y, lo4.y);
            split2(acc[r4][j][2], hi4.z, lo4.z);
            split2(acc[r4][j][3], hi4.w, lo4.w);
            *(short4*)&Ahi[(16*r4 + m)*136 + col] = hi4;
            *(short4*)&Alo[(16*r4 + m)*136 + col] = lo4;
        }
    }
    __syncthreads();

    // ---- FFN1: wave w -> cols 64w + 16jj + {m|4qd}, 256 total ----
    f32x4 a2[4][4];
#pragma unroll
    for (int r4 = 0; r4 < 4; ++r4)
#pragma unroll
        for (int jj = 0; jj < 4; ++jj) a2[r4][jj] = (f32x4){0,0,0,0};
#pragma unroll
    for (int ks = 0; ks < 4; ++ks) {
        bf16x8 wh[4], wl[4];
#pragma unroll
        for (int jj = 0; jj < 4; ++jj) {
            size_t wi = (size_t)(64*w + 16*jj + m)*D_ + 32*ks + 8*qd;
            wh[jj] = *(const bf16x8*)(Whi1 + wi);
            wl[jj] = *(const bf16x8*)(Wlo1 + wi);
        }
#pragma unroll
        for (int r4 = 0; r4 < 4; ++r4) {
            bf16x8 ah = *(const bf16x8*)&Ahi[(16*r4 + m)*136 + 32*ks + 8*qd];
            bf16x8 al = *(const bf16x8*)&Alo[(16*r4 + m)*136 + 32*ks + 8*qd];
#pragma unroll
            for (int jj = 0; jj < 4; ++jj) {
                a2[r4][jj] = __builtin_amdgcn_mfma_f32_16x16x32_bf16(wh[jj], ah, a2[r4][jj], 0, 0, 0);
                a2[r4][jj] = __builtin_amdgcn_mfma_f32_16x16x32_bf16(wh[jj], al, a2[r4][jj], 0, 0, 0);
                a2[r4][jj] = __builtin_amdgcn_mfma_f32_16x16x32_bf16(wl[jj], ah, a2[r4][jj], 0, 0, 0);
            }
        }
    }

#pragma unroll
    for (int r4 = 0; r4 < 4; ++r4) {
        int row = row0 + 16*r4 + m;
#pragma unroll
        for (int jj = 0; jj < 4; ++jj) {
            int col = 64*w + 16*jj + 4*qd;
            f32x4 v = a2[r4][jj];
            float4 bv = *(const float4*)(b1 + col);
            v[0] += bv.x; v[1] += bv.y; v[2] += bv.z; v[3] += bv.w;
#pragma unroll
            for (int e = 0; e < 4; ++e)
                v[e] = 0.5f * v[e] * (1.0f + erff(v[e] * 0.70710678118654752f));
            float4 sv = {v[0], v[1], v[2], v[3]};
            *(float4*)(hb + (size_t)row*DFF_ + col) = sv;
        }
    }
}

// ---------------------------------------------------------------------------
// FUSED: FFN2 (+b2, +resid, writes x) + restage + [TAIL=0: next-layer QKV]
//                                               [TAIL=1: fusion att dot]
// ---------------------------------------------------------------------------
template<int TAIL>
__global__ __launch_bounds__(256)
void ffn2_next_kernel(const float* __restrict__ hb,
                      const short* __restrict__ Whi2, const short* __restrict__ Wlo2,
                      const float* __restrict__ b2,
                      const short* __restrict__ WhiN, const short* __restrict__ WloN,
                      const float* __restrict__ bfv, const float* __restrict__ uf,
                      const float* __restrict__ cfm,
                      const int* __restrict__ kcount, float* __restrict__ x,
                      float* __restrict__ qout,
                      short* __restrict__ khi, short* __restrict__ klo,
                      short* __restrict__ vhiT, short* __restrict__ vloT,
                      float* __restrict__ attb)
{
    const int row0 = blockIdx.x * 64;
    const int bb = row0 >> 11;
    if ((row0 & 2047) >= ((kcount[bb] + 63) & ~63)) return;

    __shared__ short Ahi[64*136];
    __shared__ short Alo[64*136];
    __shared__ float part[64][16];
    const int t = threadIdx.x;
    const int w = t >> 6, lane = t & 63;
    const int m = lane & 15, qd = lane >> 4;

    // ---- FFN2: K=256, two staging phases ----
    f32x4 acc[4][2];
#pragma unroll
    for (int r4 = 0; r4 < 4; ++r4)
#pragma unroll
        for (int j = 0; j < 2; ++j) acc[r4][j] = (f32x4){0,0,0,0};

    for (int kb = 0; kb < DFF_; kb += 128) {
        if (kb) __syncthreads();
#pragma unroll
        for (int i = 0; i < 8; ++i) {
            int r = (t >> 5) + 8*i;
            int c = (t & 31) * 4;
            float4 av = *(const float4*)(hb + (size_t)(row0 + r)*DFF_ + kb + c);
            short4 hi4, lo4;
            split2(av.x, hi4.x, lo4.x);
            split2(av.y, hi4.y, lo4.y);
            split2(av.z, hi4.z, lo4.z);
            split2(av.w, hi4.w, lo4.w);
            *(short4*)&Ahi[r*136 + c] = hi4;
            *(short4*)&Alo[r*136 + c] = lo4;
        }
        __syncthreads();

#pragma unroll
        for (int ks = 0; ks < 4; ++ks) {
            bf16x8 wh[2], wl[2];
#pragma unroll
            for (int j = 0; j < 2; ++j) {
                size_t wi = (size_t)(32*w + 16*j + m)*DFF_ + kb + 32*ks + 8*qd;
                wh[j] = *(const bf16x8*)(Whi2 + wi);
                wl[j] = *(const bf16x8*)(Wlo2 + wi);
            }
#pragma unroll
            for (int r4 = 0; r4 < 4; ++r4) {
                bf16x8 ah = *(const bf16x8*)&Ahi[(16*r4 + m)*136 + 32*ks + 8*qd];
                bf16x8 al = *(const bf16x8*)&Alo[(16*r4 + m)*136 + 32*ks + 8*qd];
#pragma unroll
                for (int j = 0; j < 2; ++j) {
                    acc[r4][j] = __builtin_amdgcn_mfma_f32_16x16x32_bf16(wh[j], ah, acc[r4][j], 0, 0, 0);
                    acc[r4][j] = __builtin_amdgcn_mfma_f32_16x16x32_bf16(wh[j], al, acc[r4][j], 0, 0, 0);
                    acc[r4][j] = __builtin_amdgcn_mfma_f32_16x16x32_bf16(wl[j], ah, acc[r4][j], 0, 0, 0);
                }
            }
        }
    }

    // ---- epilogue: xnew = acc + b2 + x; write x; keep in regs ----
#pragma unroll
    for (int r4 = 0; r4 < 4; ++r4) {
        int row = row0 + 16*r4 + m;
#pragma unroll
        for (int j = 0; j < 2; ++j) {
            int col = 32*w + 16*j + 4*qd;
            float4 bv = *(const float4*)(b2 + col);
            float4 rv = *(const float4*)(x + (size_t)row*D_ + col);
            acc[r4][j][0] += bv.x + rv.x; acc[r4][j][1] += bv.y + rv.y;
            acc[r4][j][2] += bv.z + rv.z; acc[r4][j][3] += bv.w + rv.w;
            float4 sv = {acc[r4][j][0], acc[r4][j][1], acc[r4][j][2], acc[r4][j][3]};
            *(float4*)(x + (size_t)row*D_ + col) = sv;
        }
    }
    __syncthreads();

    // ---- restage xnew hi/lo ----
#pragma unroll
    for (int r4 = 0; r4 < 4; ++r4) {
#pragma unroll
        for (int j = 0; j < 2; ++j) {
            int col = 32*w + 16*j + 4*qd;
            short4 hi4, lo4;
            split2(acc[r4][j][0], hi4.x, lo4.x);
            split2(acc[r4][j][1], hi4.y, lo4.y);
            split2(acc[r4][j][2], hi4.z, lo4.z);
            split2(acc[r4][j][3], hi4.w, lo4.w);
            *(short4*)&Ahi[(16*r4 + m)*136 + col] = hi4;
            *(short4*)&Alo[(16*r4 + m)*136 + col] = lo4;
        }
    }
    __syncthreads();

    if (TAIL == 0) {
        // ---- next layer QKV (3 streams serial) ----
#pragma unroll
        for (int sec = 0; sec < 3; ++sec) {
            const short* Wh = WhiN + sec*16384;
            const short* Wl = WloN + sec*16384;
            f32x4 a3[4][2];
#pragma unroll
            for (int r4 = 0; r4 < 4; ++r4)
#pragma unroll
                for (int j = 0; j < 2; ++j) a3[r4][j] = (f32x4){0,0,0,0};
#pragma unroll
            for (int ks = 0; ks < 4; ++ks) {
                bf16x8 wh[2], wl[2];
#pragma unroll
                for (int j = 0; j < 2; ++j) {
                    size_t wi = (size_t)(32*w + 16*j + m)*D_ + 32*ks + 8*qd;
                    wh[j] = *(const bf16x8*)(Wh + wi);
                    wl[j] = *(const bf16x8*)(Wl + wi);
                }
#pragma unroll
                for (int r4 = 0; r4 < 4; ++r4) {
                    bf16x8 ah = *(const bf16x8*)&Ahi[(16*r4 + m)*136 + 32*ks + 8*qd];
                    bf16x8 al = *(const bf16x8*)&Alo[(16*r4 + m)*136 + 32*ks + 8*qd];
#pragma unroll
                    for (int j = 0; j < 2; ++j) {
                        a3[r4][j] = __builtin_amdgcn_mfma_f32_16x16x32_bf16(wh[j], ah, a3[r4][j], 0, 0, 0);
                        a3[r4][j] = __builtin_amdgcn_mfma_f32_16x16x32_bf16(wh[j], al, a3[r4][j], 0, 0, 0);
                        a3[r4][j] = __builtin_amdgcn_mfma_f32_16x16x32_bf16(wl[j], ah, a3[r4][j], 0, 0, 0);
                    }
                }
            }
#pragma unroll
            for (int r4 = 0; r4 < 4; ++r4) {
                int row = row0 + 16*r4 + m;
                int l = row & 2047;
#pragma unroll
                for (int j = 0; j < 2; ++j) {
                    int col = 32*w + 16*j + 4*qd;
                    f32x4 v = a3[r4][j];
                    if (sec == 0) {
                        float4 sv = {v[0], v[1], v[2], v[3]};
                        *(float4*)(qout + (size_t)row*D_ + col) = sv;
                    } else if (sec == 1) {
                        size_t idx = ((size_t)((bb*4 + w)*2048 + l))*32 + (col & 31);
                        short4 hi4, lo4;
                        split2(v[0], hi4.x, lo4.x);
                        split2(v[1], hi4.y, lo4.y);
                        split2(v[2], hi4.z, lo4.z);
                        split2(v[3], hi4.w, lo4.w);
                        *(short4*)(khi + idx) = hi4;
                        *(short4*)(klo + idx) = lo4;
                    } else {
                        size_t basep = (size_t)(bb*4 + w)*32;
#pragma unroll
                        for (int e = 0; e < 4; ++e) {
                            int d = 16*j + 4*qd + e;
                            short hh, ll; split2(v[e], hh, ll);
                            vhiT[(basep + d)*2048 + l] = hh;
                            vloT[(basep + d)*2048 + l] = ll;
                        }
                    }
                }
            }
        }
    } else {
        // ---- fusion attention: att = tanh(x@Wf+bf).uf + cfm ----
        f32x4 a3[4][2];
#pragma unroll
        for (int r4 = 0; r4 < 4; ++r4)
#pragma unroll
            for (int j = 0; j < 2; ++j) a3[r4][j] = (f32x4){0,0,0,0};
#pragma unroll
        for (int ks = 0; ks < 4; ++ks) {
            bf16x8 wh[2], wl[2];
#pragma unroll
            for (int j = 0; j < 2; ++j) {
                size_t wi = (size_t)(32*w + 16*j + m)*D_ + 32*ks + 8*qd;
                wh[j] = *(const bf16x8*)(WhiN + wi);
                wl[j] = *(const bf16x8*)(WloN + wi);
            }
#pragma unroll
            for (int r4 = 0; r4 < 4; ++r4) {
                bf16x8 ah = *(const bf16x8*)&Ahi[(16*r4 + m)*136 + 32*ks + 8*qd];
                bf16x8 al = *(const bf16x8*)&Alo[(16*r4 + m)*136 + 32*ks + 8*qd];
#pragma unroll
                for (int j = 0; j < 2; ++j) {
                    a3[r4][j] = __builtin_amdgcn_mfma_f32_16x16x32_bf16(wh[j], ah, a3[r4][j], 0, 0, 0);
                    a3[r4][j] = __builtin_amdgcn_mfma_f32_16x16x32_bf16(wh[j], al, a3[r4][j], 0, 0, 0);
                    a3[r4][j] = __builtin_amdgcn_mfma_f32_16x16x32_bf16(wl[j], ah, a3[r4][j], 0, 0, 0);
                }
            }
        }
#pragma unroll
        for (int r4 = 0; r4 < 4; ++r4) {
            float dotp = 0.0f;
#pragma unroll
            for (int j = 0; j < 2; ++j) {
                int col = 32*w + 16*j + 4*qd;
                f32x4 v = a3[r4][j];
                float4 bv = *(const float4*)(bfv + col);
                v[0] += bv.x; v[1] += bv.y; v[2] += bv.z; v[3] += bv.w;
#pragma unroll
                for (int e = 0; e < 4; ++e) v[e] = tanhf(v[e]);
                float4 uv = *(const float4*)(uf + col);
                dotp += v[0]*uv.x + v[1]*uv.y + v[2]*uv.z + v[3]*uv.w;
            }
            part[16*r4 + m][4*w + qd] = dotp;
        }
        __syncthreads();
        if (t < 64) {
            float s = 0.0f;
#pragma unroll
            for (int i = 0; i < 16; ++i) s += part[t][i];
            attb[row0 + t] = s + cfm[row0 + t];
        }
    }
}

// ---------------------------------------------------------------------------
// Pooling
// ---------------------------------------------------------------------------
__global__ __launch_bounds__(256)
void pool_stats_kernel(const float* __restrict__ att, const int* __restrict__ kcount,
                       float* __restrict__ p)
{
    int b = blockIdx.x, t = threadIdx.x;
    int lim = (kcount[b] + 63) & ~63;
    __shared__ float red[4];
    __shared__ float a_s[L_];

    float m = -INFINITY;
    for (int l = t; l < L_; l += 256) {
        float a = (l < lim) ? att[b*L_ + l] : FMINV;
        a_s[l] = a;
        m = fmaxf(m, a);
    }
#pragma unroll
    for (int s = 1; s < 64; s <<= 1) m = fmaxf(m, __shfl_xor(m, s));
    if ((t & 63) == 0) red[t >> 6] = m;
    __syncthreads();
    m = fmaxf(fmaxf(red[0], red[1]), fmaxf(red[2], red[3]));
    __syncthreads();

    float s = 0.0f;
    for (int l = t; l < L_; l += 256) s += __expf(a_s[l] - m);
#pragma unroll
    for (int st = 1; st < 64; st <<= 1) s += __shfl_xor(s, st);
    if ((t & 63) == 0) red[t >> 6] = s;
    __syncthreads();
    s = red[0] + red[1] + red[2] + red[3];
    float inv = 1.0f / s;
    for (int l = t; l < L_; l += 256)
        p[b*L_ + l] = (l < lim) ? __expf(a_s[l] - m) * inv : 0.0f;
}

__global__ __launch_bounds__(128)
void pool_partial_kernel(const float* __restrict__ p, const float* __restrict__ x,
                         float* __restrict__ part)
{
    int c = blockIdx.x, b = blockIdx.y, d = threadIdx.x;
    const float* xb = x + ((size_t)(b*L_ + c*128))*D_ + d;
    const float* pb = p + b*L_ + c*128;
    float acc = 0.0f;
#pragma unroll 4
    for (int i = 0; i < 128; ++i) acc += pb[i] * xb[(size_t)i*D_];
    part[((size_t)b*16 + c)*D_ + d] = acc;
}

// ---------------------------------------------------------------------------
// Head (+inline demographics MLP for row b)
// ---------------------------------------------------------------------------
__global__ __launch_bounds__(256)
void head_kernel(const float* __restrict__ part, const float* __restrict__ demog,
                 const float* __restrict__ Wd1, const float* __restrict__ bd1,
                 const float* __restrict__ Wd2, const float* __restrict__ bd2,
                 const float* __restrict__ Wh, const float* __restrict__ bh,
                 float* __restrict__ out)
{
    int b = blockIdx.x, t = threadIdx.x;
    __shared__ float tss[128];
    __shared__ float hs1[256];
    __shared__ float dems[128];
    if (t < 128) {
        float s = 0.0f;
#pragma unroll
        for (int c = 0; c < 16; ++c) s += part[((size_t)b*16 + c)*D_ + t];
        tss[t] = s;
    }
    {
        float a = bd1[t];
#pragma unroll
        for (int kk = 0; kk < DM_; ++kk) a += demog[b*DM_ + kk] * Wd1[kk*(2*D_) + t];
        hs1[t] = tanhf(a);
    }
    __syncthreads();
    if (t < 128) {
        float a = bd2[t];
        for (int kk = 0; kk < 2*D_; ++kk) a += hs1[kk] * Wd2[kk*D_ + t];
        dems[t] = a;
    }
    __syncthreads();
    if (t >= F_OUT) return;
    float acc = bh[t];
    for (int k2 = 0; k2 < D_; ++k2) acc += tss[k2]  * Wh[k2*F_OUT + t];
    for (int k2 = 0; k2 < D_; ++k2) acc += dems[k2] * Wh[(D_+k2)*F_OUT + t];
    out[b*F_OUT + t] = acc;
}

// ---------------------------------------------------------------------------
extern "C" void kernel_launch(void* const* d_in, const int* in_sizes, int n_in,
                              void* d_out, int out_size, void* d_ws, size_t ws_size,
                              hipStream_t stream)
{
    (void)in_sizes; (void)n_in; (void)out_size; (void)ws_size;
    const float* values       = (const float*)d_in[0];
    const float* times        = (const float*)d_in[1];
    const int*   variables    = (const int*)  d_in[2];
    const int*   input_mask   = (const int*)  d_in[3];
    const float* demographics = (const float*)d_in[4];
    const float* W1t = (const float*)d_in[5];
    const float* b1t = (const float*)d_in[6];
    const float* W2t = (const float*)d_in[7];
    const float* W1v = (const float*)d_in[8];
    const float* b1v = (const float*)d_in[9];
    const float* W2v = (const float*)d_in[10];
    const float* var_table = (const float*)d_in[11];
    const float* Wq  = (const float*)d_in[12];
    const float* Wk  = (const float*)d_in[13];
    const float* Wv  = (const float*)d_in[14];
    const float* Wo  = (const float*)d_in[15];
    const float* W1  = (const float*)d_in[16];
    const float* b1  = (const float*)d_in[17];
    const float* W2  = (const float*)d_in[18];
    const float* b2  = (const float*)d_in[19];
    const float* Wf  = (const float*)d_in[20];
    const float* bfv = (const float*)d_in[21];
    const float* uf  = (const float*)d_in[22];
    const float* Wd1 = (const float*)d_in[23];
    const float* bd1 = (const float*)d_in[24];
    const float* Wd2 = (const float*)d_in[25];
    const float* bd2 = (const float*)d_in[26];
    const float* Wh  = (const float*)d_in[27];
    const float* bhv = (const float*)d_in[28];
    float* out = (float*)d_out;

    float* ws     = (float*)d_ws;
    float* x      = ws;                   // compact rows
    float* qb     = ws + (size_t)SZ_X;
    float* region = ws + (size_t)2*SZ_X;
    short* khi    = (short*)region;
    short* klo    = khi + (size_t)SZ_X;
    short* vhiT   = klo + (size_t)SZ_X;
    short* vloT   = vhiT + (size_t)SZ_X;
    float* attb   = ws + (size_t)4*SZ_X;  // BL_
    float* attp   = attb + BL_;           // BL_
    float* partb  = attp + BL_;           // B_*16*D_
    short* wt_hi  = (short*)(partb + B_*16*D_);  // NL_*WT_TOT + 16384 shorts
    short* wt_lo  = wt_hi + ((size_t)NL_*WT_TOT + 16384);
    int*   posb   = (int*)(wt_lo + ((size_t)NL_*WT_TOT + 16384));
    int*   kcountb= posb + BL_;
    float* cfmb   = (float*)(kcountb + B_ + 3);  // keep 16B-ish alignment
    float* opart  = cfmb + BL_;                  // 2*SZ_X
    float* mlm    = opart + (size_t)2*SZ_X;      // B_*H_*2*2048
    float* mll    = mlm + (size_t)B_*H_*2*2048;
    float* hb     = mll + (size_t)B_*H_*2*2048;  // 2*SZ_X (dedicated, no alias)
    short* wfhi   = wt_hi + (size_t)NL_*WT_TOT;
    short* wflo   = wt_lo + (size_t)NL_*WT_TOT;

    compact_kernel<<<B_, 256, 0, stream>>>(input_mask, posb, kcountb, cfmb, x);
    embed_kernel<<<BL_, 128, 0, stream>>>(values, times, variables, posb,
                                          W1t, b1t, W2t, W1v, b1v, W2v,
                                          var_table, x);
    split_all_kernel<<<(NL_*131072 + 16384)/256, 256, 0, stream>>>(
        Wq, Wk, Wv, Wo, W1, W2, Wf, wt_hi, wt_lo);

    gemm_qkv_fused<<<dim3(BL_/64, 3), 256, 0, stream>>>(x,
        wt_hi + 0*WT_TOT, wt_lo + 0*WT_TOT, kcountb, qb, khi, klo, vhiT, vloT);

    for (int i = 0; i < NL_; ++i) {
        short* whL = wt_hi + (size_t)i*WT_TOT;
        short* wlL = wt_lo + (size_t)i*WT_TOT;
        attn_mfma_kernel<<<dim3(L_/64, H_*2, B_), 256, 0, stream>>>(qb, khi, klo,
            vhiT, vloT, kcountb, cfmb, opart, mlm, mll);
        wo_ffn1_kernel<<<BL_/64, 256, 0, stream>>>(opart, mlm, mll,
            whL+WT_O, wlL+WT_O, whL+WT_1, wlL+WT_1, b1 + i*DFF_,
            kcountb, x, hb);
        if (i < NL_ - 1) {
            short* whN = wt_hi + (size_t)(i+1)*WT_TOT;
            short* wlN = wt_lo + (size_t)(i+1)*WT_TOT;
            ffn2_next_kernel<0><<<BL_/64, 256, 0, stream>>>(hb,
                whL+WT_2, wlL+WT_2, b2 + i*D_, whN, wlN,
                nullptr, nullptr, nullptr, kcountb, x,
                qb, khi, klo, vhiT, vloT, nullptr);
        } else {
            ffn2_next_kernel<1><<<BL_/64, 256, 0, stream>>>(hb,
                whL+WT_2, wlL+WT_2, b2 + i*D_, wfhi, wflo,
                bfv, uf, cfmb, kcountb, x,
                nullptr, nullptr, nullptr, nullptr, nullptr, attb);
        }
    }

    pool_stats_kernel<<<B_, 256, 0, stream>>>(attb, kcountb, attp);
    pool_partial_kernel<<<dim3(16, B_), 128, 0, stream>>>(attp, x, partb);
    head_kernel<<<B_, 256, 0, stream>>>(partb, demographics, Wd1, bd1, Wd2, bd2,
                                        Wh, bhv, out);
}

// Round 17
// 789.573 us; speedup vs baseline: 2.6516x; 1.0000x over previous
//
#include <hip/hip_runtime.h>
#include <hip/hip_bf16.h>
#include <math.h>

#define B_   16
#define L_   2048
#define D_   128
#define H_   4
#define NL_  4
#define DK_  32
#define DFF_ 256
#define INTD_ 11
#define F_OUT 129
#define DM_  16
#define FMINV (-3.402823466e38f)
#define LOG2E 1.4426950408889634f

#define BL_  (B_*L_)      // 32768
#define SZ_X (BL_*D_)     // 4194304 floats

#define PSTR 68           // single-buffered P scratch: 64 keys + pad, 8B-aligned rows

#define WT_Q 0
#define WT_K 16384
#define WT_V 32768
#define WT_O 49152
#define WT_1 65536
#define WT_2 98304
#define WT_TOT 131072

typedef __attribute__((ext_vector_type(8))) short bf16x8;
typedef __attribute__((ext_vector_type(4))) float f32x4;

#if __has_builtin(__builtin_amdgcn_exp2f)
#define EXP2F(x) __builtin_amdgcn_exp2f(x)
#else
#define EXP2F(x) __expf(0.69314718055994531f*(x))
#endif

static __device__ __forceinline__ short f2bf(float x) {
    union { __hip_bfloat16 h; short s; } u;
    u.h = __float2bfloat16(x);
    return u.s;
}
static __device__ __forceinline__ float bf2f(short s) {
    union { __hip_bfloat16 h; short t; } u;
    u.t = s;
    return __bfloat162float(u.h);
}
static __device__ __forceinline__ void split2(float v, short& h, short& l) {
    h = f2bf(v); l = f2bf(v - bf2f(h));
}
static __device__ __forceinline__ void split_trunc(float v, short& h, short& l) {
    unsigned u = __float_as_uint(v);
    h = (short)(u >> 16);
    float r = v - __uint_as_float(u & 0xffff0000u);
    l = (short)(__float_as_uint(r) >> 16);
}

// ---------------------------------------------------------------------------
// Mask compaction + x tail-zero: pos, kcount, cfm; zeroes x rows [Kb,ceil64).
// ---------------------------------------------------------------------------
__global__ __launch_bounds__(256)
void compact_kernel(const int* __restrict__ mask, int* __restrict__ pos,
                    int* __restrict__ kcount, float* __restrict__ cfm,
                    float* __restrict__ x)
{
    int b = blockIdx.x, t = threadIdx.x;
    int lane = t & 63, w = t >> 6;
    __shared__ int wsum[4];
    __shared__ int tot_s;
    int mv[8], loc[8], s = 0;
#pragma unroll
    for (int i = 0; i < 8; ++i) {
        mv[i] = mask[b*L_ + t*8 + i];
        loc[i] = s;
        s += mv[i];
    }
    int v = s;
#pragma unroll
    for (int d = 1; d < 64; d <<= 1) {
        int y = __shfl_up(v, d);
        if (lane >= d) v += y;
    }
    int excl = v - s;
    if (lane == 63) wsum[w] = v;
    __syncthreads();
    int wbase = 0;
    for (int i = 0; i < w; ++i) wbase += wsum[i];
    int base = wbase + excl;
#pragma unroll
    for (int i = 0; i < 8; ++i)
        pos[b*L_ + t*8 + i] = mv[i] ? (base + loc[i]) : -1;
    if (t == 255) { kcount[b] = base + s; tot_s = base + s; }
    __syncthreads();
    int tot = tot_s;
    for (int l = t; l < L_; l += 256) cfm[b*L_ + l] = (l < tot) ? 0.0f : FMINV;
    int end = (tot + 63) & ~63;
    int nz = (end - tot) * D_;
    for (int i = t; i < nz; i += 256)
        x[((size_t)(b*2048 + tot))*D_ + i] = 0.0f;
}

// ---------------------------------------------------------------------------
// Embedding with compaction
// ---------------------------------------------------------------------------
__global__ __launch_bounds__(128)
void embed_kernel(const float* __restrict__ values, const float* __restrict__ times,
                  const int* __restrict__ variables, const int* __restrict__ pos,
                  const float* __restrict__ W1t, const float* __restrict__ b1t,
                  const float* __restrict__ W2t,
                  const float* __restrict__ W1v, const float* __restrict__ b1v,
                  const float* __restrict__ W2v,
                  const float* __restrict__ var_table, float* __restrict__ x)
{
    int bl = blockIdx.x;
    int p  = pos[bl];
    if (p < 0) return;
    int t  = threadIdx.x;
    __shared__ float th[INTD_], vh[INTD_];
    if (t < INTD_)                th[t]    = tanhf(times[bl]  * W1t[t]    + b1t[t]);
    if (t >= 64 && t < 64+INTD_)  vh[t-64] = tanhf(values[bl] * W1v[t-64] + b1v[t-64]);
    __syncthreads();
    int var = variables[bl];
    float acc = var_table[var*D_ + t];
#pragma unroll
    for (int i = 0; i < INTD_; ++i)
        acc += th[i]*W2t[i*D_ + t] + vh[i]*W2v[i*D_ + t];
    x[((size_t)((bl >> 11)*2048 + p))*D_ + t] = acc;
}

// ---------------------------------------------------------------------------
// Weight pre-split: all 4 layers + Wf appended at offset NL_*WT_TOT.
// ---------------------------------------------------------------------------
__global__ __launch_bounds__(256)
void split_all_kernel(const float* __restrict__ Wq, const float* __restrict__ Wk,
                      const float* __restrict__ Wv, const float* __restrict__ Wo,
                      const float* __restrict__ W1, const float* __restrict__ W2,
                      const float* __restrict__ Wf,
                      short* __restrict__ hi, short* __restrict__ lo)
{
    int gidx = blockIdx.x*256 + threadIdx.x;
    float v;
    if (gidx < NL_*131072) {
        int layer = gidx >> 17;
        int idx   = gidx & 131071;
        if (idx < 49152) {
            int which = idx >> 14;
            int r = idx & 16383;
            int col = r >> 7, k = r & 127;
            int h = col >> 5, e = col & 31;
            const float* src = ((which == 0) ? Wq : (which == 1) ? Wk : Wv)
                               + (size_t)layer*H_*D_*DK_;
            v = src[(h*D_ + k)*DK_ + e];
        } else if (idx < 65536) {
            int r = idx - 49152;
            int col = r >> 7, k = r & 127;
            v = Wo[(size_t)layer*D_*D_ + k*D_ + col];
        } else if (idx < 98304) {
            int r = idx - 65536;
            int col = r >> 7, k = r & 127;
            v = W1[(size_t)layer*D_*DFF_ + k*DFF_ + col];
        } else {
            int r = idx - 98304;
            int col = r >> 8, k = r & 255;
            v = W2[(size_t)layer*DFF_*D_ + k*D_ + col];
        }
    } else {
        int r = gidx - NL_*131072;      // Wf: 16384 elems, [col][K]
        int col = r >> 7, k = r & 127;
        v = Wf[k*D_ + col];
    }
    short h2, l2; split2(v, h2, l2);
    hi[gidx] = h2; lo[gidx] = l2;
}

// ---------------------------------------------------------------------------
// Fused QKV GEMM (layer 0 only), one weight stream per block (grid.y=3).
// ---------------------------------------------------------------------------
__global__ __launch_bounds__(256)
void gemm_qkv_fused(const float* __restrict__ A, const short* __restrict__ Whi,
                    const short* __restrict__ Wlo, const int* __restrict__ kcount,
                    float* __restrict__ qout,
                    short* __restrict__ khi, short* __restrict__ klo,
                    short* __restrict__ vhiT, short* __restrict__ vloT)
{
    const int row0 = blockIdx.x * 64;
    const int bb = row0 >> 11;
    if ((row0 & 2047) >= ((kcount[bb] + 63) & ~63)) return;
    const int sec = blockIdx.y;

    __shared__ short Ahi[64*136];
    __shared__ short Alo[64*136];
    const int t = threadIdx.x;
    const int w = t >> 6, lane = t & 63;
    const int m = lane & 15, qd = lane >> 4;

#pragma unroll
    for (int i = 0; i < 8; ++i) {
        int r = (t >> 5) + 8*i;
        int c = (t & 31) * 4;
        float4 av = *(const float4*)(A + (size_t)(row0 + r)*D_ + c);
        short4 hi4, lo4;
        split2(av.x, hi4.x, lo4.x);
        split2(av.y, hi4.y, lo4.y);
        split2(av.z, hi4.z, lo4.z);
        split2(av.w, hi4.w, lo4.w);
        *(short4*)&Ahi[r*136 + c] = hi4;
        *(short4*)&Alo[r*136 + c] = lo4;
    }
    __syncthreads();

    const short* Wh = Whi + sec*16384;
    const short* Wl = Wlo + sec*16384;
    f32x4 acc[4][2];
#pragma unroll
    for (int r4 = 0; r4 < 4; ++r4)
#pragma unroll
        for (int j = 0; j < 2; ++j) acc[r4][j] = (f32x4){0,0,0,0};

#pragma unroll
    for (int ks = 0; ks < 4; ++ks) {
        bf16x8 wh[2], wl[2];
#pragma unroll
        for (int j = 0; j < 2; ++j) {
            size_t wi = (size_t)(32*w + 16*j + m)*D_ + 32*ks + 8*qd;
            wh[j] = *(const bf16x8*)(Wh + wi);
            wl[j] = *(const bf16x8*)(Wl + wi);
        }
#pragma unroll
        for (int r4 = 0; r4 < 4; ++r4) {
            bf16x8 ah = *(const bf16x8*)&Ahi[(16*r4 + m)*136 + 32*ks + 8*qd];
            bf16x8 al = *(const bf16x8*)&Alo[(16*r4 + m)*136 + 32*ks + 8*qd];
#pragma unroll
            for (int j = 0; j < 2; ++j) {
                acc[r4][j] = __builtin_amdgcn_mfma_f32_16x16x32_bf16(wh[j], ah, acc[r4][j], 0, 0, 0);
                acc[r4][j] = __builtin_amdgcn_mfma_f32_16x16x32_bf16(wh[j], al, acc[r4][j], 0, 0, 0);
                acc[r4][j] = __builtin_amdgcn_mfma_f32_16x16x32_bf16(wl[j], ah, acc[r4][j], 0, 0, 0);
            }
        }
    }

#pragma unroll
    for (int r4 = 0; r4 < 4; ++r4) {
        int row = row0 + 16*r4 + m;
        int l = row & 2047;
#pragma unroll
        for (int j = 0; j < 2; ++j) {
            int col = 32*w + 16*j + 4*qd;
            f32x4 v = acc[r4][j];
            if (sec == 0) {
                float4 sv = {v[0], v[1], v[2], v[3]};
                *(float4*)(qout + (size_t)row*D_ + col) = sv;
            } else if (sec == 1) {
                size_t idx = ((size_t)((bb*4 + w)*2048 + l))*32 + (col & 31);
                short4 hi4, lo4;
                split2(v[0], hi4.x, lo4.x);
                split2(v[1], hi4.y, lo4.y);
                split2(v[2], hi4.z, lo4.z);
                split2(v[3], hi4.w, lo4.w);
                *(short4*)(khi + idx) = hi4;
                *(short4*)(klo + idx) = lo4;
            } else {
                size_t basep = (size_t)(bb*4 + w)*32;
#pragma unroll
                for (int e = 0; e < 4; ++e) {
                    int d = 16*j + 4*qd + e;
                    short hh, ll; split2(v[e], hh, ll);
                    vhiT[(basep + d)*2048 + l] = hh;
                    vloT[(basep + d)*2048 + l] = ll;
                }
            }
        }
    }
}

// ---------------------------------------------------------------------------
// SPLIT-K MFMA flash attention, SINGLE-BUFFERED P (two-pass PV):
// write Phi -> Phi·Vhi + Phi·Vlo -> overwrite with Plo -> Plo·Vhi.
// P scratch is wave-private; DS ops within a wave are in-order (WAR-safe).
// LDS 36.3 -> 26.0 KB => 6 blocks/CU (was 4).
// ---------------------------------------------------------------------------
__global__ __launch_bounds__(256)
void attn_mfma_kernel(const float* __restrict__ q,
                      const short* __restrict__ khi, const short* __restrict__ klo,
                      const short* __restrict__ vhiT, const short* __restrict__ vloT,
                      const int* __restrict__ kcount, const float* __restrict__ cfm,
                      float* __restrict__ opart, float* __restrict__ mlm,
                      float* __restrict__ mll)
{
    __shared__ short KhiS[64*32];
    __shared__ short KloS[64*32];
    __shared__ short Vthi[32*72];
    __shared__ short Vtlo[32*72];
    __shared__ short Ps[4][16*PSTR];
    __shared__ float kmf[64];
    __shared__ float al_ls[4][16];

    const int t    = threadIdx.x;
    const int w    = t >> 6;
    const int lane = t & 63;
    const int m    = lane & 15;
    const int qd   = lane >> 4;
    const int qt = blockIdx.x, b = blockIdx.z;
    const int h = blockIdx.y & 3, half = blockIdx.y >> 2;

    const int Kb = kcount[b];
    if (qt*64 >= Kb) return;
    const int nt = (Kb + 63) >> 6;
    const int ntH = (nt + 1) >> 1;
    const int kt0 = half * ntH;
    const int kt1 = (kt0 + ntH < nt) ? (kt0 + ntH) : nt;
    const size_t mlbase = (((size_t)(b*4 + h))*2 + half)*2048;

    if (kt0 >= kt1) {
        if (lane < 16) {
            mlm[mlbase + qt*64 + 16*w + lane] = FMINV;
            mll[mlbase + qt*64 + 16*w + lane] = 0.0f;
        }
        return;
    }

    const size_t hd = ((size_t)(b*4 + h))*2048*32;
    const int vd = t >> 3;
    const int vk = (t & 7) * 8;
    const size_t vbase = ((size_t)(b*4 + h)*32 + vd)*2048 + vk;

    const int qrow = qt*64 + 16*w + m;
    const float* qp = q + ((size_t)(b*L_ + qrow))*D_ + h*DK_ + 8*qd;
    float qf[8];
    *(float4*)&qf[0] = *(const float4*)qp;
    *(float4*)&qf[4] = *(const float4*)(qp + 4);
    bf16x8 qhi, qlo;
#pragma unroll
    for (int j = 0; j < 8; ++j) {
        float qs = qf[j] * LOG2E;
        short hs = f2bf(qs);
        qhi[j] = hs;
        qlo[j] = f2bf(qs - bf2f(hs));
    }

    bf16x8 pkh, pkl, pvh, pvl;
    float4 pmask = {0,0,0,0};
    {
        const size_t gk = hd + (size_t)kt0*64*32 + t*8;
        pkh = *(const bf16x8*)(khi + gk);
        pkl = *(const bf16x8*)(klo + gk);
        pvh = *(const bf16x8*)(vhiT + vbase + (size_t)kt0*64);
        pvl = *(const bf16x8*)(vloT + vbase + (size_t)kt0*64);
        if (t < 16) pmask = ((const float4*)(cfm + (size_t)b*L_ + (size_t)kt0*64))[t];
    }

    float m_old = -INFINITY, l_run = 0.0f;
    f32x4 o_acc[2] = {{0,0,0,0},{0,0,0,0}};

    for (int kt = kt0; kt < kt1; ++kt) {
        __syncthreads();
        *(bf16x8*)&KhiS[t*8] = pkh;
        *(bf16x8*)&KloS[t*8] = pkl;
        *(bf16x8*)&Vthi[vd*72 + vk] = pvh;
        *(bf16x8*)&Vtlo[vd*72 + vk] = pvl;
        if (t < 16) ((float4*)kmf)[t] = pmask;
        __syncthreads();
        if (kt + 1 < kt1) {
            const size_t gk = hd + (size_t)(kt+1)*64*32 + t*8;
            pkh = *(const bf16x8*)(khi + gk);
            pkl = *(const bf16x8*)(klo + gk);
            pvh = *(const bf16x8*)(vhiT + vbase + (size_t)(kt+1)*64);
            pvl = *(const bf16x8*)(vloT + vbase + (size_t)(kt+1)*64);
            if (t < 16) pmask = ((const float4*)(cfm + (size_t)b*L_ + (size_t)(kt+1)*64))[t];
        }

        f32x4 sf[4];
#pragma unroll
        for (int k4 = 0; k4 < 4; ++k4) {
            bf16x8 ka = *(const bf16x8*)&KhiS[(16*k4 + m)*32 + 8*qd];
            bf16x8 kl = *(const bf16x8*)&KloS[(16*k4 + m)*32 + 8*qd];
            f32x4 c = {0,0,0,0};
            c = __builtin_amdgcn_mfma_f32_16x16x32_bf16(ka, qhi, c, 0, 0, 0);
            c = __builtin_amdgcn_mfma_f32_16x16x32_bf16(ka, qlo, c, 0, 0, 0);
            c = __builtin_amdgcn_mfma_f32_16x16x32_bf16(kl, qhi, c, 0, 0, 0);
            sf[k4] = c;
        }

        float sv[16];
#pragma unroll
        for (int k4 = 0; k4 < 4; ++k4) {
            float4 kmv = *(const float4*)&kmf[16*k4 + 4*qd];
            sv[4*k4+0] = sf[k4][0] + kmv.x;
            sv[4*k4+1] = sf[k4][1] + kmv.y;
            sv[4*k4+2] = sf[k4][2] + kmv.z;
            sv[4*k4+3] = sf[k4][3] + kmv.w;
        }

        float tmax = sv[0];
#pragma unroll
        for (int j = 1; j < 16; ++j) tmax = fmaxf(tmax, sv[j]);
        tmax = fmaxf(tmax, __shfl_xor(tmax, 16));
        tmax = fmaxf(tmax, __shfl_xor(tmax, 32));
        float mnew  = fmaxf(m_old, tmax);
        float alpha = EXP2F(m_old - mnew);
        float psum = 0.0f;
        short pbh[16], pbl[16];
#pragma unroll
        for (int j = 0; j < 16; ++j) {
            float p = EXP2F(sv[j] - mnew);
            psum += p;
            split_trunc(p, pbh[j], pbl[j]);
        }
        psum += __shfl_xor(psum, 16);
        psum += __shfl_xor(psum, 32);
        l_run = l_run * alpha + psum;
        m_old = mnew;

        // ---- write Phi ----
#pragma unroll
        for (int k4 = 0; k4 < 4; ++k4) {
            short4 s4h;
            s4h.x = pbh[4*k4+0]; s4h.y = pbh[4*k4+1]; s4h.z = pbh[4*k4+2]; s4h.w = pbh[4*k4+3];
            *(short4*)&Ps[w][m*PSTR + 16*k4 + 4*qd] = s4h;
        }
        if (lane < 16) al_ls[w][lane] = alpha;

        // ---- O rescale ----
        {
            float4 alr = *(const float4*)&al_ls[w][4*qd];
            o_acc[0][0]*=alr.x; o_acc[0][1]*=alr.y; o_acc[0][2]*=alr.z; o_acc[0][3]*=alr.w;
            o_acc[1][0]*=alr.x; o_acc[1][1]*=alr.y; o_acc[1][2]*=alr.z; o_acc[1][3]*=alr.w;
        }
        // ---- pass 1: Phi·Vhi + Phi·Vlo ----
#pragma unroll
        for (int s = 0; s < 2; ++s) {
            bf16x8 pah = *(const bf16x8*)&Ps[w][m*PSTR + 32*s + 8*qd];
#pragma unroll
            for (int tp = 0; tp < 2; ++tp) {
                bf16x8 vh = *(const bf16x8*)&Vthi[(16*tp + m)*72 + 32*s + 8*qd];
                bf16x8 vl = *(const bf16x8*)&Vtlo[(16*tp + m)*72 + 32*s + 8*qd];
                o_acc[tp] = __builtin_amdgcn_mfma_f32_16x16x32_bf16(pah, vh, o_acc[tp], 0, 0, 0);
                o_acc[tp] = __builtin_amdgcn_mfma_f32_16x16x32_bf16(pah, vl, o_acc[tp], 0, 0, 0);
            }
        }
        // ---- overwrite with Plo (wave-private, in-order DS => WAR-safe) ----
#pragma unroll
        for (int k4 = 0; k4 < 4; ++k4) {
            short4 s4l;
            s4l.x = pbl[4*k4+0]; s4l.y = pbl[4*k4+1]; s4l.z = pbl[4*k4+2]; s4l.w = pbl[4*k4+3];
            *(short4*)&Ps[w][m*PSTR + 16*k4 + 4*qd] = s4l;
        }
        // ---- pass 2: Plo·Vhi ----
#pragma unroll
        for (int s = 0; s < 2; ++s) {
            bf16x8 pal = *(const bf16x8*)&Ps[w][m*PSTR + 32*s + 8*qd];
#pragma unroll
            for (int tp = 0; tp < 2; ++tp) {
                bf16x8 vh = *(const bf16x8*)&Vthi[(16*tp + m)*72 + 32*s + 8*qd];
                o_acc[tp] = __builtin_amdgcn_mfma_f32_16x16x32_bf16(pal, vh, o_acc[tp], 0, 0, 0);
            }
        }
    }

    if (lane < 16) {
        mlm[mlbase + qt*64 + 16*w + lane] = m_old;
        mll[mlbase + qt*64 + 16*w + lane] = l_run;
    }
    float* ob = opart + (size_t)half*SZ_X;
#pragma unroll
    for (int tp = 0; tp < 2; ++tp)
#pragma unroll
        for (int r = 0; r < 4; ++r)
            ob[((size_t)(b*L_ + qt*64 + 16*w + 4*qd + r))*D_ + h*DK_ + 16*tp + m] =
                o_acc[tp][r];
}

// ---------------------------------------------------------------------------
// FUSED: split-K merge + Wo GEMM + resid (writes x) + restage + FFN1 + GELU
// ---------------------------------------------------------------------------
__global__ __launch_bounds__(256)
void wo_ffn1_kernel(const float* __restrict__ opart, const float* __restrict__ mlm,
                    const float* __restrict__ mll,
                    const short* __restrict__ WhiO, const short* __restrict__ WloO,
                    const short* __restrict__ Whi1, const short* __restrict__ Wlo1,
                    const float* __restrict__ b1,
                    const int* __restrict__ kcount, float* __restrict__ x,
                    float* __restrict__ hb)
{
    const int row0 = blockIdx.x * 64;
    const int bb = row0 >> 11;
    if ((row0 & 2047) >= ((kcount[bb] + 63) & ~63)) return;

    __shared__ short Ahi[64*136];
    __shared__ short Alo[64*136];
    const int t = threadIdx.x;
    const int w = t >> 6, lane = t & 63;
    const int m = lane & 15, qd = lane >> 4;

    // ---- stage merged O hi/lo ----
#pragma unroll
    for (int i = 0; i < 8; ++i) {
        int r = (t >> 5) + 8*i;
        int c = (t & 31) * 4;
        int row = row0 + r;
        int l = row & 2047;
        int h = c >> 5;
        size_t i0 = (((size_t)(bb*4 + h))*2 + 0)*2048 + l;
        size_t i1 = i0 + 2048;
        float m0 = mlm[i0], m1 = mlm[i1];
        float l0 = mll[i0], l1 = mll[i1];
        float M  = fmaxf(m0, m1);
        float w0 = EXP2F(m0 - M), w1 = EXP2F(m1 - M);
        float inv = 1.0f / (l0*w0 + l1*w1);
        float s0 = w0 * inv, s1 = w1 * inv;
        float4 o0 = *(const float4*)(opart + (size_t)row*D_ + c);
        float4 o1 = *(const float4*)(opart + (size_t)(BL_ + row)*D_ + c);
        float4 av;
        av.x = s0*o0.x + s1*o1.x;
        av.y = s0*o0.y + s1*o1.y;
        av.z = s0*o0.z + s1*o1.z;
        av.w = s0*o0.w + s1*o1.w;
        short4 hi4, lo4;
        split2(av.x, hi4.x, lo4.x);
        split2(av.y, hi4.y, lo4.y);
        split2(av.z, hi4.z, lo4.z);
        split2(av.w, hi4.w, lo4.w);
        *(short4*)&Ahi[r*136 + c] = hi4;
        *(short4*)&Alo[r*136 + c] = lo4;
    }
    __syncthreads();

    // ---- Wo matmul ----
    f32x4 acc[4][2];
#pragma unroll
    for (int r4 = 0; r4 < 4; ++r4)
#pragma unroll
        for (int j = 0; j < 2; ++j) acc[r4][j] = (f32x4){0,0,0,0};
#pragma unroll
    for (int ks = 0; ks < 4; ++ks) {
        bf16x8 wh[2], wl[2];
#pragma unroll
        for (int j = 0; j < 2; ++j) {
            size_t wi = (size_t)(32*w + 16*j + m)*D_ + 32*ks + 8*qd;
            wh[j] = *(const bf16x8*)(WhiO + wi);
            wl[j] = *(const bf16x8*)(WloO + wi);
        }
#pragma unroll
        for (int r4 = 0; r4 < 4; ++r4) {
            bf16x8 ah = *(const bf16x8*)&Ahi[(16*r4 + m)*136 + 32*ks + 8*qd];
            bf16x8 al = *(const bf16x8*)&Alo[(16*r4 + m)*136 + 32*ks + 8*qd];
#pragma unroll
            for (int j = 0; j < 2; ++j) {
                acc[r4][j] = __builtin_amdgcn_mfma_f32_16x16x32_bf16(wh[j], ah, acc[r4][j], 0, 0, 0);
                acc[r4][j] = __builtin_amdgcn_mfma_f32_16x16x32_bf16(wh[j], al, acc[r4][j], 0, 0, 0);
                acc[r4][j] = __builtin_amdgcn_mfma_f32_16x16x32_bf16(wl[j], ah, acc[r4][j], 0, 0, 0);
            }
        }
    }

    // ---- epilogue: xnew = acc + x; write x; keep in regs ----
#pragma unroll
    for (int r4 = 0; r4 < 4; ++r4) {
        int row = row0 + 16*r4 + m;
#pragma unroll
        for (int j = 0; j < 2; ++j) {
            int col = 32*w + 16*j + 4*qd;
            float4 rv = *(const float4*)(x + (size_t)row*D_ + col);
            acc[r4][j][0] += rv.x; acc[r4][j][1] += rv.y;
            acc[r4][j][2] += rv.z; acc[r4][j][3] += rv.w;
            float4 sv = {acc[r4][j][0], acc[r4][j][1], acc[r4][j][2], acc[r4][j][3]};
            *(float4*)(x + (size_t)row*D_ + col) = sv;
        }
    }
    __syncthreads();

    // ---- restage xnew hi/lo ----
#pragma unroll
    for (int r4 = 0; r4 < 4; ++r4) {
#pragma unroll
        for (int j = 0; j < 2; ++j) {
            int col = 32*w + 16*j + 4*qd;
            short4 hi4, lo4;
            split2(acc[r4][j][0], hi4.x, lo4.x);
            split2(acc[r4][j][1], hi4.y, lo4.y);
            split2(acc[r4][j][2], hi4.z, lo4.z);
            split2(acc[r4][j][3], hi4.w, lo4.w);
            *(short4*)&Ahi[(16*r4 + m)*136 + col] = hi4;
            *(short4*)&Alo[(16*r4 + m)*136 + col] = lo4;
        }
    }
    __syncthreads();

    // ---- FFN1 ----
    f32x4 a2[4][4];
#pragma unroll
    for (int r4 = 0; r4 < 4; ++r4)
#pragma unroll
        for (int jj = 0; jj < 4; ++jj) a2[r4][jj] = (f32x4){0,0,0,0};
#pragma unroll
    for (int ks = 0; ks < 4; ++ks) {
        bf16x8 wh[4], wl[4];
#pragma unroll
        for (int jj = 0; jj < 4; ++jj) {
            size_t wi = (size_t)(64*w + 16*jj + m)*D_ + 32*ks + 8*qd;
            wh[jj] = *(const bf16x8*)(Whi1 + wi);
            wl[jj] = *(const bf16x8*)(Wlo1 + wi);
        }
#pragma unroll
        for (int r4 = 0; r4 < 4; ++r4) {
            bf16x8 ah = *(const bf16x8*)&Ahi[(16*r4 + m)*136 + 32*ks + 8*qd];
            bf16x8 al = *(const bf16x8*)&Alo[(16*r4 + m)*136 + 32*ks + 8*qd];
#pragma unroll
            for (int jj = 0; jj < 4; ++jj) {
                a2[r4][jj] = __builtin_amdgcn_mfma_f32_16x16x32_bf16(wh[jj], ah, a2[r4][jj], 0, 0, 0);
                a2[r4][jj] = __builtin_amdgcn_mfma_f32_16x16x32_bf16(wh[jj], al, a2[r4][jj], 0, 0, 0);
                a2[r4][jj] = __builtin_amdgcn_mfma_f32_16x16x32_bf16(wl[jj], ah, a2[r4][jj], 0, 0, 0);
            }
        }
    }

#pragma unroll
    for (int r4 = 0; r4 < 4; ++r4) {
        int row = row0 + 16*r4 + m;
#pragma unroll
        for (int jj = 0; jj < 4; ++jj) {
            int col = 64*w + 16*jj + 4*qd;
            f32x4 v = a2[r4][jj];
            float4 bv = *(const float4*)(b1 + col);
            v[0] += bv.x; v[1] += bv.y; v[2] += bv.z; v[3] += bv.w;
#pragma unroll
            for (int e = 0; e < 4; ++e)
                v[e] = 0.5f * v[e] * (1.0f + erff(v[e] * 0.70710678118654752f));
            float4 sv = {v[0], v[1], v[2], v[3]};
            *(float4*)(hb + (size_t)row*DFF_ + col) = sv;
        }
    }
}

// ---------------------------------------------------------------------------
// FUSED: FFN2 (+b2, +resid, writes x) + restage + [TAIL=0: next-layer QKV]
//                                               [TAIL=1: fusion att dot]
// ---------------------------------------------------------------------------
template<int TAIL>
__global__ __launch_bounds__(256)
void ffn2_next_kernel(const float* __restrict__ hb,
                      const short* __restrict__ Whi2, const short* __restrict__ Wlo2,
                      const float* __restrict__ b2,
                      const short* __restrict__ WhiN, const short* __restrict__ WloN,
                      const float* __restrict__ bfv, const float* __restrict__ uf,
                      const float* __restrict__ cfm,
                      const int* __restrict__ kcount, float* __restrict__ x,
                      float* __restrict__ qout,
                      short* __restrict__ khi, short* __restrict__ klo,
                      short* __restrict__ vhiT, short* __restrict__ vloT,
                      float* __restrict__ attb)
{
    const int row0 = blockIdx.x * 64;
    const int bb = row0 >> 11;
    if ((row0 & 2047) >= ((kcount[bb] + 63) & ~63)) return;

    __shared__ short Ahi[64*136];
    __shared__ short Alo[64*136];
    __shared__ float part[64][16];
    const int t = threadIdx.x;
    const int w = t >> 6, lane = t & 63;
    const int m = lane & 15, qd = lane >> 4;

    // ---- FFN2: K=256, two staging phases ----
    f32x4 acc[4][2];
#pragma unroll
    for (int r4 = 0; r4 < 4; ++r4)
#pragma unroll
        for (int j = 0; j < 2; ++j) acc[r4][j] = (f32x4){0,0,0,0};

    for (int kb = 0; kb < DFF_; kb += 128) {
        if (kb) __syncthreads();
#pragma unroll
        for (int i = 0; i < 8; ++i) {
            int r = (t >> 5) + 8*i;
            int c = (t & 31) * 4;
            float4 av = *(const float4*)(hb + (size_t)(row0 + r)*DFF_ + kb + c);
            short4 hi4, lo4;
            split2(av.x, hi4.x, lo4.x);
            split2(av.y, hi4.y, lo4.y);
            split2(av.z, hi4.z, lo4.z);
            split2(av.w, hi4.w, lo4.w);
            *(short4*)&Ahi[r*136 + c] = hi4;
            *(short4*)&Alo[r*136 + c] = lo4;
        }
        __syncthreads();

#pragma unroll
        for (int ks = 0; ks < 4; ++ks) {
            bf16x8 wh[2], wl[2];
#pragma unroll
            for (int j = 0; j < 2; ++j) {
                size_t wi = (size_t)(32*w + 16*j + m)*DFF_ + kb + 32*ks + 8*qd;
                wh[j] = *(const bf16x8*)(Whi2 + wi);
                wl[j] = *(const bf16x8*)(Wlo2 + wi);
            }
#pragma unroll
            for (int r4 = 0; r4 < 4; ++r4) {
                bf16x8 ah = *(const bf16x8*)&Ahi[(16*r4 + m)*136 + 32*ks + 8*qd];
                bf16x8 al = *(const bf16x8*)&Alo[(16*r4 + m)*136 + 32*ks + 8*qd];
#pragma unroll
                for (int j = 0; j < 2; ++j) {
                    acc[r4][j] = __builtin_amdgcn_mfma_f32_16x16x32_bf16(wh[j], ah, acc[r4][j], 0, 0, 0);
                    acc[r4][j] = __builtin_amdgcn_mfma_f32_16x16x32_bf16(wh[j], al, acc[r4][j], 0, 0, 0);
                    acc[r4][j] = __builtin_amdgcn_mfma_f32_16x16x32_bf16(wl[j], ah, acc[r4][j], 0, 0, 0);
                }
            }
        }
    }

    // ---- epilogue: xnew = acc + b2 + x; write x; keep in regs ----
#pragma unroll
    for (int r4 = 0; r4 < 4; ++r4) {
        int row = row0 + 16*r4 + m;
#pragma unroll
        for (int j = 0; j < 2; ++j) {
            int col = 32*w + 16*j + 4*qd;
            float4 bv = *(const float4*)(b2 + col);
            float4 rv = *(const float4*)(x + (size_t)row*D_ + col);
            acc[r4][j][0] += bv.x + rv.x; acc[r4][j][1] += bv.y + rv.y;
            acc[r4][j][2] += bv.z + rv.z; acc[r4][j][3] += bv.w + rv.w;
            float4 sv = {acc[r4][j][0], acc[r4][j][1], acc[r4][j][2], acc[r4][j][3]};
            *(float4*)(x + (size_t)row*D_ + col) = sv;
        }
    }
    __syncthreads();

    // ---- restage xnew hi/lo ----
#pragma unroll
    for (int r4 = 0; r4 < 4; ++r4) {
#pragma unroll
        for (int j = 0; j < 2; ++j) {
            int col = 32*w + 16*j + 4*qd;
            short4 hi4, lo4;
            split2(acc[r4][j][0], hi4.x, lo4.x);
            split2(acc[r4][j][1], hi4.y, lo4.y);
            split2(acc[r4][j][2], hi4.z, lo4.z);
            split2(acc[r4][j][3], hi4.w, lo4.w);
            *(short4*)&Ahi[(16*r4 + m)*136 + col] = hi4;
            *(short4*)&Alo[(16*r4 + m)*136 + col] = lo4;
        }
    }
    __syncthreads();

    if (TAIL == 0) {
#pragma unroll
        for (int sec = 0; sec < 3; ++sec) {
            const short* Wh = WhiN + sec*16384;
            const short* Wl = WloN + sec*16384;
            f32x4 a3[4][2];
#pragma unroll
            for (int r4 = 0; r4 < 4; ++r4)
#pragma unroll
                for (int j = 0; j < 2; ++j) a3[r4][j] = (f32x4){0,0,0,0};
#pragma unroll
            for (int ks = 0; ks < 4; ++ks) {
                bf16x8 wh[2], wl[2];
#pragma unroll
                for (int j = 0; j < 2; ++j) {
                    size_t wi = (size_t)(32*w + 16*j + m)*D_ + 32*ks + 8*qd;
                    wh[j] = *(const bf16x8*)(Wh + wi);
                    wl[j] = *(const bf16x8*)(Wl + wi);
                }
#pragma unroll
                for (int r4 = 0; r4 < 4; ++r4) {
                    bf16x8 ah = *(const bf16x8*)&Ahi[(16*r4 + m)*136 + 32*ks + 8*qd];
                    bf16x8 al = *(const bf16x8*)&Alo[(16*r4 + m)*136 + 32*ks + 8*qd];
#pragma unroll
                    for (int j = 0; j < 2; ++j) {
                        a3[r4][j] = __builtin_amdgcn_mfma_f32_16x16x32_bf16(wh[j], ah, a3[r4][j], 0, 0, 0);
                        a3[r4][j] = __builtin_amdgcn_mfma_f32_16x16x32_bf16(wh[j], al, a3[r4][j], 0, 0, 0);
                        a3[r4][j] = __builtin_amdgcn_mfma_f32_16x16x32_bf16(wl[j], ah, a3[r4][j], 0, 0, 0);
                    }
                }
            }
#pragma unroll
            for (int r4 = 0; r4 < 4; ++r4) {
                int row = row0 + 16*r4 + m;
                int l = row & 2047;
#pragma unroll
                for (int j = 0; j < 2; ++j) {
                    int col = 32*w + 16*j + 4*qd;
                    f32x4 v = a3[r4][j];
                    if (sec == 0) {
                        float4 sv = {v[0], v[1], v[2], v[3]};
                        *(float4*)(qout + (size_t)row*D_ + col) = sv;
                    } else if (sec == 1) {
                        size_t idx = ((size_t)((bb*4 + w)*2048 + l))*32 + (col & 31);
                        short4 hi4, lo4;
                        split2(v[0], hi4.x, lo4.x);
                        split2(v[1], hi4.y, lo4.y);
                        split2(v[2], hi4.z, lo4.z);
                        split2(v[3], hi4.w, lo4.w);
                        *(short4*)(khi + idx) = hi4;
                        *(short4*)(klo + idx) = lo4;
                    } else {
                        size_t basep = (size_t)(bb*4 + w)*32;
#pragma unroll
                        for (int e = 0; e < 4; ++e) {
                            int d = 16*j + 4*qd + e;
                            short hh, ll; split2(v[e], hh, ll);
                            vhiT[(basep + d)*2048 + l] = hh;
                            vloT[(basep + d)*2048 + l] = ll;
                        }
                    }
                }
            }
        }
    } else {
        f32x4 a3[4][2];
#pragma unroll
        for (int r4 = 0; r4 < 4; ++r4)
#pragma unroll
            for (int j = 0; j < 2; ++j) a3[r4][j] = (f32x4){0,0,0,0};
#pragma unroll
        for (int ks = 0; ks < 4; ++ks) {
            bf16x8 wh[2], wl[2];
#pragma unroll
            for (int j = 0; j < 2; ++j) {
                size_t wi = (size_t)(32*w + 16*j + m)*D_ + 32*ks + 8*qd;
                wh[j] = *(const bf16x8*)(WhiN + wi);
                wl[j] = *(const bf16x8*)(WloN + wi);
            }
#pragma unroll
            for (int r4 = 0; r4 < 4; ++r4) {
                bf16x8 ah = *(const bf16x8*)&Ahi[(16*r4 + m)*136 + 32*ks + 8*qd];
                bf16x8 al = *(const bf16x8*)&Alo[(16*r4 + m)*136 + 32*ks + 8*qd];
#pragma unroll
                for (int j = 0; j < 2; ++j) {
                    a3[r4][j] = __builtin_amdgcn_mfma_f32_16x16x32_bf16(wh[j], ah, a3[r4][j], 0, 0, 0);
                    a3[r4][j] = __builtin_amdgcn_mfma_f32_16x16x32_bf16(wh[j], al, a3[r4][j], 0, 0, 0);
                    a3[r4][j] = __builtin_amdgcn_mfma_f32_16x16x32_bf16(wl[j], ah, a3[r4][j], 0, 0, 0);
                }
            }
        }
#pragma unroll
        for (int r4 = 0; r4 < 4; ++r4) {
            float dotp = 0.0f;
#pragma unroll
            for (int j = 0; j < 2; ++j) {
                int col = 32*w + 16*j + 4*qd;
                f32x4 v = a3[r4][j];
                float4 bv = *(const float4*)(bfv + col);
                v[0] += bv.x; v[1] += bv.y; v[2] += bv.z; v[3] += bv.w;
#pragma unroll
                for (int e = 0; e < 4; ++e) v[e] = tanhf(v[e]);
                float4 uv = *(const float4*)(uf + col);
                dotp += v[0]*uv.x + v[1]*uv.y + v[2]*uv.z + v[3]*uv.w;
            }
            part[16*r4 + m][4*w + qd] = dotp;
        }
        __syncthreads();
        if (t < 64) {
            float s = 0.0f;
#pragma unroll
            for (int i = 0; i < 16; ++i) s += part[t][i];
            attb[row0 + t] = s + cfm[row0 + t];
        }
    }
}

// ---------------------------------------------------------------------------
// Pooling
// ---------------------------------------------------------------------------
__global__ __launch_bounds__(256)
void pool_stats_kernel(const float* __restrict__ att, const int* __restrict__ kcount,
                       float* __restrict__ p)
{
    int b = blockIdx.x, t = threadIdx.x;
    int lim = (kcount[b] + 63) & ~63;
    __shared__ float red[4];
    __shared__ float a_s[L_];

    float m = -INFINITY;
    for (int l = t; l < L_; l += 256) {
        float a = (l < lim) ? att[b*L_ + l] : FMINV;
        a_s[l] = a;
        m = fmaxf(m, a);
    }
#pragma unroll
    for (int s = 1; s < 64; s <<= 1) m = fmaxf(m, __shfl_xor(m, s));
    if ((t & 63) == 0) red[t >> 6] = m;
    __syncthreads();
    m = fmaxf(fmaxf(red[0], red[1]), fmaxf(red[2], red[3]));
    __syncthreads();

    float s = 0.0f;
    for (int l = t; l < L_; l += 256) s += __expf(a_s[l] - m);
#pragma unroll
    for (int st = 1; st < 64; st <<= 1) s += __shfl_xor(s, st);
    if ((t & 63) == 0) red[t >> 6] = s;
    __syncthreads();
    s = red[0] + red[1] + red[2] + red[3];
    float inv = 1.0f / s;
    for (int l = t; l < L_; l += 256)
        p[b*L_ + l] = (l < lim) ? __expf(a_s[l] - m) * inv : 0.0f;
}

__global__ __launch_bounds__(128)
void pool_partial_kernel(const float* __restrict__ p, const float* __restrict__ x,
                         float* __restrict__ part)
{
    int c = blockIdx.x, b = blockIdx.y, d = threadIdx.x;
    const float* xb = x + ((size_t)(b*L_ + c*128))*D_ + d;
    const float* pb = p + b*L_ + c*128;
    float acc = 0.0f;
#pragma unroll 4
    for (int i = 0; i < 128; ++i) acc += pb[i] * xb[(size_t)i*D_];
    part[((size_t)b*16 + c)*D_ + d] = acc;
}

// ---------------------------------------------------------------------------
// Head (+inline demographics MLP for row b)
// ---------------------------------------------------------------------------
__global__ __launch_bounds__(256)
void head_kernel(const float* __restrict__ part, const float* __restrict__ demog,
                 const float* __restrict__ Wd1, const float* __restrict__ bd1,
                 const float* __restrict__ Wd2, const float* __restrict__ bd2,
                 const float* __restrict__ Wh, const float* __restrict__ bh,
                 float* __restrict__ out)
{
    int b = blockIdx.x, t = threadIdx.x;
    __shared__ float tss[128];
    __shared__ float hs1[256];
    __shared__ float dems[128];
    if (t < 128) {
        float s = 0.0f;
#pragma unroll
        for (int c = 0; c < 16; ++c) s += part[((size_t)b*16 + c)*D_ + t];
        tss[t] = s;
    }
    {
        float a = bd1[t];
#pragma unroll
        for (int kk = 0; kk < DM_; ++kk) a += demog[b*DM_ + kk] * Wd1[kk*(2*D_) + t];
        hs1[t] = tanhf(a);
    }
    __syncthreads();
    if (t < 128) {
        float a = bd2[t];
        for (int kk = 0; kk < 2*D_; ++kk) a += hs1[kk] * Wd2[kk*D_ + t];
        dems[t] = a;
    }
    __syncthreads();
    if (t >= F_OUT) return;
    float acc = bh[t];
    for (int k2 = 0; k2 < D_; ++k2) acc += tss[k2]  * Wh[k2*F_OUT + t];
    for (int k2 = 0; k2 < D_; ++k2) acc += dems[k2] * Wh[(D_+k2)*F_OUT + t];
    out[b*F_OUT + t] = acc;
}

// ---------------------------------------------------------------------------
extern "C" void kernel_launch(void* const* d_in, const int* in_sizes, int n_in,
                              void* d_out, int out_size, void* d_ws, size_t ws_size,
                              hipStream_t stream)
{
    (void)in_sizes; (void)n_in; (void)out_size; (void)ws_size;
    const float* values       = (const float*)d_in[0];
    const float* times        = (const float*)d_in[1];
    const int*   variables    = (const int*)  d_in[2];
    const int*   input_mask   = (const int*)  d_in[3];
    const float* demographics = (const float*)d_in[4];
    const float* W1t = (const float*)d_in[5];
    const float* b1t = (const float*)d_in[6];
    const float* W2t = (const float*)d_in[7];
    const float* W1v = (const float*)d_in[8];
    const float* b1v = (const float*)d_in[9];
    const float* W2v = (const float*)d_in[10];
    const float* var_table = (const float*)d_in[11];
    const float* Wq  = (const float*)d_in[12];
    const float* Wk  = (const float*)d_in[13];
    const float* Wv  = (const float*)d_in[14];
    const float* Wo  = (const float*)d_in[15];
    const float* W1  = (const float*)d_in[16];
    const float* b1  = (const float*)d_in[17];
    const float* W2  = (const float*)d_in[18];
    const float* b2  = (const float*)d_in[19];
    const float* Wf  = (const float*)d_in[20];
    const float* bfv = (const float*)d_in[21];
    const float* uf  = (const float*)d_in[22];
    const float* Wd1 = (const float*)d_in[23];
    const float* bd1 = (const float*)d_in[24];
    const float* Wd2 = (const float*)d_in[25];
    const float* bd2 = (const float*)d_in[26];
    const float* Wh  = (const float*)d_in[27];
    const float* bhv = (const float*)d_in[28];
    float* out = (float*)d_out;

    float* ws     = (float*)d_ws;
    float* x      = ws;                   // compact rows
    float* qb     = ws + (size_t)SZ_X;
    float* region = ws + (size_t)2*SZ_X;
    short* khi    = (short*)region;
    short* klo    = khi + (size_t)SZ_X;
    short* vhiT   = klo + (size_t)SZ_X;
    short* vloT   = vhiT + (size_t)SZ_X;
    float* attb   = ws + (size_t)4*SZ_X;  // BL_
    float* attp   = attb + BL_;           // BL_
    float* partb  = attp + BL_;           // B_*16*D_
    short* wt_hi  = (short*)(partb + B_*16*D_);  // NL_*WT_TOT + 16384 shorts
    short* wt_lo  = wt_hi + ((size_t)NL_*WT_TOT + 16384);
    int*   posb   = (int*)(wt_lo + ((size_t)NL_*WT_TOT + 16384));
    int*   kcountb= posb + BL_;
    float* cfmb   = (float*)(kcountb + B_ + 3);
    float* opart  = cfmb + BL_;                  // 2*SZ_X
    float* mlm    = opart + (size_t)2*SZ_X;      // B_*H_*2*2048
    float* mll    = mlm + (size_t)B_*H_*2*2048;
    float* hb     = mll + (size_t)B_*H_*2*2048;  // 2*SZ_X (dedicated)
    short* wfhi   = wt_hi + (size_t)NL_*WT_TOT;
    short* wflo   = wt_lo + (size_t)NL_*WT_TOT;

    compact_kernel<<<B_, 256, 0, stream>>>(input_mask, posb, kcountb, cfmb, x);
    embed_kernel<<<BL_, 128, 0, stream>>>(values, times, variables, posb,
                                          W1t, b1t, W2t, W1v, b1v, W2v,
                                          var_table, x);
    split_all_kernel<<<(NL_*131072 + 16384)/256, 256, 0, stream>>>(
        Wq, Wk, Wv, Wo, W1, W2, Wf, wt_hi, wt_lo);

    gemm_qkv_fused<<<dim3(BL_/64, 3), 256, 0, stream>>>(x,
        wt_hi + 0*WT_TOT, wt_lo + 0*WT_TOT, kcountb, qb, khi, klo, vhiT, vloT);

    for (int i = 0; i < NL_; ++i) {
        short* whL = wt_hi + (size_t)i*WT_TOT;
        short* wlL = wt_lo + (size_t)i*WT_TOT;
        attn_mfma_kernel<<<dim3(L_/64, H_*2, B_), 256, 0, stream>>>(qb, khi, klo,
            vhiT, vloT, kcountb, cfmb, opart, mlm, mll);
        wo_ffn1_kernel<<<BL_/64, 256, 0, stream>>>(opart, mlm, mll,
            whL+WT_O, wlL+WT_O, whL+WT_1, wlL+WT_1, b1 + i*DFF_,
            kcountb, x, hb);
        if (i < NL_ - 1) {
            short* whN = wt_hi + (size_t)(i+1)*WT_TOT;
            short* wlN = wt_lo + (size_t)(i+1)*WT_TOT;
            ffn2_next_kernel<0><<<BL_/64, 256, 0, stream>>>(hb,
                whL+WT_2, wlL+WT_2, b2 + i*D_, whN, wlN,
                nullptr, nullptr, nullptr, kcountb, x,
                qb, khi, klo, vhiT, vloT, nullptr);
        } else {
            ffn2_next_kernel<1><<<BL_/64, 256, 0, stream>>>(hb,
                whL+WT_2, wlL+WT_2, b2 + i*D_, wfhi, wflo,
                bfv, uf, cfmb, kcountb, x,
                nullptr, nullptr, nullptr, nullptr, nullptr, attb);
        }
    }

    pool_stats_kernel<<<B_, 256, 0, stream>>>(attb, kcountb, attp);
    pool_partial_kernel<<<dim3(16, B_), 128, 0, stream>>>(attp, x, partb);
    head_kernel<<<B_, 256, 0, stream>>>(partb, demographics, Wd1, bd1, Wd2, bd2,
                                        Wh, bhv, out);
}